// Round 3
// baseline (2791.335 us; speedup 1.0000x reference)
//
#include <hip/hip_runtime.h>
#include <hip/hip_bf16.h>

#define G_ 256
#define K_ 16
#define L_ 3
#define H_ 3
#define F_ 64
#define EMB_ 200
#define HID_ 256
#define N_ (G_*K_)          // 4096 nodes
#define E_ (G_*K_*(K_-1))   // 61440 edges

__device__ __forceinline__ float selu_f(float x) {
  const float scale = 1.0507009873554804934193349852946f;
  const float alpha = 1.6732632423543772848170429916717f;
  return scale * (x > 0.f ? x : alpha * expm1f(x));
}

// fea[n, 0:63] = elem_fea_in[n,:] @ W_init + b_init ; fea[n,63] = w[n]
__global__ __launch_bounds__(64) void init_embed(
    const float* __restrict__ fea_in, const float* __restrict__ W,
    const float* __restrict__ b, const float* __restrict__ wts,
    float* __restrict__ fea) {
  __shared__ float row[EMB_];
  int n = blockIdx.x;
  int j = threadIdx.x;               // 0..63
  for (int k = j; k < EMB_; k += 64) row[k] = fea_in[(size_t)n*EMB_ + k];
  __syncthreads();
  if (j < F_-1) {
    float s = b[j];
    for (int k = 0; k < EMB_; ++k) s = fmaf(row[k], W[k*(F_-1) + j], s);
    fea[(size_t)n*F_ + j] = s;
  } else {
    fea[(size_t)n*F_ + (F_-1)] = wts[n];
  }
}

// ---------------------------------------------------------------------------
// Fused gate path: gate[m0+r] = selu(A[r,:] @ W1 + b1) . W2 + b2
// A rows gathered from fea (GATHER: concat fea[self], fea[nbr], KD=128;
// else fea row directly, KD=64). 64 rows per block, 256 threads.
// ---------------------------------------------------------------------------
template<int KD, bool GATHER>
__global__ __launch_bounds__(256) void fused_gate(
    const float* __restrict__ fea, const int* __restrict__ self_idx,
    const int* __restrict__ nbr_idx,
    const float* __restrict__ W1,   // [KD, HID]
    const float* __restrict__ b1,   // [HID]
    const float* __restrict__ W2,   // [HID]
    const float* __restrict__ b2p,  // [1]
    float* __restrict__ gate) {
  __shared__ float AsT[KD][68];   // transposed A tile: AsT[k][row]
  __shared__ float Ws[16][68];
  __shared__ float red[64][17];
  int tid = threadIdx.x;
  int m0 = blockIdx.x * 64;
  for (int idx = tid; idx < 64*KD; idx += 256) {
    int r = idx / KD, c = idx - r*KD;
    float v;
    if (GATHER) {
      int node = (c < F_) ? self_idx[m0+r] : nbr_idx[m0+r];
      v = fea[node*F_ + (c & (F_-1))];
    } else {
      v = fea[(size_t)(m0+r)*KD + c];
    }
    AsT[c][r] = v;
  }
  __syncthreads();
  int tr = tid >> 4, tc = tid & 15;
  float partial[4] = {0.f, 0.f, 0.f, 0.f};
  for (int cch = 0; cch < HID_/64; ++cch) {
    float acc[4][4] = {};
    for (int k0 = 0; k0 < KD; k0 += 16) {
      int wr = tid >> 6, wc = tid & 63;
      #pragma unroll
      for (int rr = 0; rr < 4; ++rr)
        Ws[wr + rr*4][wc] = W1[(size_t)(k0 + wr + rr*4)*HID_ + cch*64 + wc];
      __syncthreads();
      #pragma unroll
      for (int kk = 0; kk < 16; ++kk) {
        float a[4], b[4];
        #pragma unroll
        for (int i = 0; i < 4; ++i) a[i] = AsT[k0+kk][tr*4+i];
        #pragma unroll
        for (int j = 0; j < 4; ++j) b[j] = Ws[kk][tc*4+j];
        #pragma unroll
        for (int i = 0; i < 4; ++i)
          #pragma unroll
          for (int j = 0; j < 4; ++j) acc[i][j] = fmaf(a[i], b[j], acc[i][j]);
      }
      __syncthreads();
    }
    #pragma unroll
    for (int j = 0; j < 4; ++j) {
      int n = cch*64 + tc*4 + j;
      float w2 = W2[n];
      float bb = b1[n];
      #pragma unroll
      for (int i = 0; i < 4; ++i)
        partial[i] = fmaf(selu_f(acc[i][j] + bb), w2, partial[i]);
    }
  }
  #pragma unroll
  for (int i = 0; i < 4; ++i) red[tr*4+i][tc] = partial[i];
  __syncthreads();
  if (tid < 64) {
    float s = 0.f;
    #pragma unroll
    for (int t = 0; t < 16; ++t) s += red[tid][t];
    gate[m0 + tid] = s + *b2p;
  }
}

// ---------------------------------------------------------------------------
// Fused message path: msg[m0+r,:] = selu(A[r,:] @ W1 + b1) @ W2 + b2
// Two chained 64x64 tile-GEMMs per hid chunk, hid never hits global memory.
// ---------------------------------------------------------------------------
template<int KD, bool GATHER>
__global__ __launch_bounds__(256) void fused_msg(
    const float* __restrict__ fea, const int* __restrict__ self_idx,
    const int* __restrict__ nbr_idx,
    const float* __restrict__ W1,   // [KD, HID]
    const float* __restrict__ b1,   // [HID]
    const float* __restrict__ W2,   // [HID, F]
    const float* __restrict__ b2,   // [F]
    float* __restrict__ msg) {
  __shared__ float AsT[KD][68];
  __shared__ float HsT[64][68];   // selu'd hid chunk, transposed: HsT[n][row]
  __shared__ float Ws[16][68];
  int tid = threadIdx.x;
  int m0 = blockIdx.x * 64;
  for (int idx = tid; idx < 64*KD; idx += 256) {
    int r = idx / KD, c = idx - r*KD;
    float v;
    if (GATHER) {
      int node = (c < F_) ? self_idx[m0+r] : nbr_idx[m0+r];
      v = fea[node*F_ + (c & (F_-1))];
    } else {
      v = fea[(size_t)(m0+r)*KD + c];
    }
    AsT[c][r] = v;
  }
  __syncthreads();
  int tr = tid >> 4, tc = tid & 15;
  float accM[4][4] = {};
  for (int cch = 0; cch < HID_/64; ++cch) {
    float accH[4][4] = {};
    for (int k0 = 0; k0 < KD; k0 += 16) {
      int wr = tid >> 6, wc = tid & 63;
      #pragma unroll
      for (int rr = 0; rr < 4; ++rr)
        Ws[wr + rr*4][wc] = W1[(size_t)(k0 + wr + rr*4)*HID_ + cch*64 + wc];
      __syncthreads();
      #pragma unroll
      for (int kk = 0; kk < 16; ++kk) {
        float a[4], b[4];
        #pragma unroll
        for (int i = 0; i < 4; ++i) a[i] = AsT[k0+kk][tr*4+i];
        #pragma unroll
        for (int j = 0; j < 4; ++j) b[j] = Ws[kk][tc*4+j];
        #pragma unroll
        for (int i = 0; i < 4; ++i)
          #pragma unroll
          for (int j = 0; j < 4; ++j) accH[i][j] = fmaf(a[i], b[j], accH[i][j]);
      }
      __syncthreads();
    }
    // selu + bias, transposed store to LDS
    #pragma unroll
    for (int j = 0; j < 4; ++j) {
      int n = cch*64 + tc*4 + j;
      float bb = b1[n];
      #pragma unroll
      for (int i = 0; i < 4; ++i)
        HsT[tc*4+j][tr*4+i] = selu_f(accH[i][j] + bb);
    }
    __syncthreads();
    // accM += Hs(64x64) @ W2[cch*64 .. +64, 0:64]
    for (int k1 = 0; k1 < 64; k1 += 16) {
      int wr = tid >> 6, wc = tid & 63;
      #pragma unroll
      for (int rr = 0; rr < 4; ++rr)
        Ws[wr + rr*4][wc] = W2[(size_t)(cch*64 + k1 + wr + rr*4)*F_ + wc];
      __syncthreads();
      #pragma unroll
      for (int kk = 0; kk < 16; ++kk) {
        float a[4], b[4];
        #pragma unroll
        for (int i = 0; i < 4; ++i) a[i] = HsT[k1+kk][tr*4+i];
        #pragma unroll
        for (int j = 0; j < 4; ++j) b[j] = Ws[kk][tc*4+j];
        #pragma unroll
        for (int i = 0; i < 4; ++i)
          #pragma unroll
          for (int j = 0; j < 4; ++j) accM[i][j] = fmaf(a[i], b[j], accM[i][j]);
      }
      __syncthreads();
    }
  }
  #pragma unroll
  for (int j = 0; j < 4; ++j) {
    float bb = b2[tc*4+j];
    #pragma unroll
    for (int i = 0; i < 4; ++i)
      msg[(size_t)(m0 + tr*4 + i)*F_ + tc*4 + j] = accM[i][j] + bb;
  }
}

// segment softmax with weight^pow scaling; segments are contiguous SEGLEN runs
template<int SEGLEN, bool USE_IDX>
__global__ __launch_bounds__(256) void seg_attn(
    const float* __restrict__ gate, const float* __restrict__ wts,
    const int* __restrict__ nidx, const float* __restrict__ powp,
    float* __restrict__ attn, int nseg) {
  int n = blockIdx.x*256 + threadIdx.x;
  if (n >= nseg) return;
  float pw = *powp;
  float g[SEGLEN];
  float m = -1e30f;
  #pragma unroll
  for (int j = 0; j < SEGLEN; ++j) { g[j] = gate[n*SEGLEN+j]; m = fmaxf(m, g[j]); }
  float den = 0.f;
  #pragma unroll
  for (int j = 0; j < SEGLEN; ++j) {
    int widx = USE_IDX ? nidx[n*SEGLEN+j] : n*SEGLEN+j;
    float w = wts[widx];
    float v = powf(w, pw) * expf(g[j] - m);
    g[j] = v; den += v;
  }
  den += 1e-10f;
  #pragma unroll
  for (int j = 0; j < SEGLEN; ++j) attn[n*SEGLEN+j] = g[j] / den;
}

// fea_out[n,f] = (first ? fea_prev : fea_out)[n,f] + (1/H)*sum_j attn[n*15+j]*msg[n*15+j,f]
__global__ __launch_bounds__(256) void head_accum(
    const float* __restrict__ attn, const float* __restrict__ msg,
    const float* __restrict__ fea_prev, float* __restrict__ fea_out, int first) {
  int idx = blockIdx.x*256 + threadIdx.x;   // N_*F_
  int n = idx >> 6, f = idx & 63;
  float s = 0.f;
  #pragma unroll
  for (int j = 0; j < K_-1; ++j)
    s = fmaf(attn[n*(K_-1)+j], msg[(size_t)(n*(K_-1)+j)*F_ + f], s);
  s *= (1.f/(float)H_);
  fea_out[idx] = s + (first ? fea_prev[idx] : fea_out[idx]);
}

// out[g,f] (+)= (1/H) * sum_j attn[g*16+j]*msg[g*16+j, f]
__global__ __launch_bounds__(256) void cry_accum(
    const float* __restrict__ attn, const float* __restrict__ msg,
    float* __restrict__ outacc, int first) {
  int idx = blockIdx.x*256 + threadIdx.x;   // G_*F_
  int g = idx >> 6, f = idx & 63;
  float s = 0.f;
  #pragma unroll
  for (int j = 0; j < K_; ++j)
    s = fmaf(attn[g*K_+j], msg[(size_t)(g*K_+j)*F_ + f], s);
  s *= (1.f/(float)H_);
  outacc[idx] = first ? s : outacc[idx] + s;
}

extern "C" void kernel_launch(void* const* d_in, const int* in_sizes, int n_in,
                              void* d_out, int out_size, void* d_ws, size_t ws_size,
                              hipStream_t stream) {
  const float* elem_weights = (const float*)d_in[0];
  const float* elem_fea_in  = (const float*)d_in[1];
  const float* W_init = (const float*)d_in[2];
  const float* b_init = (const float*)d_in[3];
  const float* mg_W1  = (const float*)d_in[4];
  const float* mg_b1  = (const float*)d_in[5];
  const float* mg_W2  = (const float*)d_in[6];
  const float* mg_b2  = (const float*)d_in[7];
  const float* mm_W1  = (const float*)d_in[8];
  const float* mm_b1  = (const float*)d_in[9];
  const float* mm_W2  = (const float*)d_in[10];
  const float* mm_b2  = (const float*)d_in[11];
  const float* m_pow  = (const float*)d_in[12];
  const float* cg_W1  = (const float*)d_in[13];
  const float* cg_b1  = (const float*)d_in[14];
  const float* cg_W2  = (const float*)d_in[15];
  const float* cg_b2  = (const float*)d_in[16];
  const float* cm_W1  = (const float*)d_in[17];
  const float* cm_b1  = (const float*)d_in[18];
  const float* cm_W2  = (const float*)d_in[19];
  const float* cm_b2  = (const float*)d_in[20];
  const float* c_pow  = (const float*)d_in[21];
  const int* self_idx = (const int*)d_in[23];
  const int* nbr_idx  = (const int*)d_in[24];

  // f32 workspace layout (~19 MB)
  float* ws    = (float*)d_ws;
  float* feaA  = ws;                         // N*F
  float* feaB  = feaA  + (size_t)N_*F_;      // N*F
  float* msgb  = feaB  + (size_t)N_*F_;      // E*F
  float* gateb = msgb  + (size_t)E_*F_;      // E
  float* attnb = gateb + E_;                 // E

  float* out = (float*)d_out;                // [G, F] float32 per reference

  init_embed<<<N_, 64, 0, stream>>>(elem_fea_in, W_init, b_init, elem_weights, feaA);

  float* cur = feaA; float* nxt = feaB;
  for (int l = 0; l < L_; ++l) {
    for (int h = 0; h < H_; ++h) {
      int lh = l*H_ + h;
      fused_gate<2*F_, true><<<E_/64, 256, 0, stream>>>(
          cur, self_idx, nbr_idx,
          mg_W1 + (size_t)lh*2*F_*HID_, mg_b1 + (size_t)lh*HID_,
          mg_W2 + (size_t)lh*HID_, mg_b2 + lh, gateb);
      seg_attn<K_-1, true><<<(N_+255)/256, 256, 0, stream>>>(
          gateb, elem_weights, nbr_idx, m_pow + lh, attnb, N_);
      fused_msg<2*F_, true><<<E_/64, 256, 0, stream>>>(
          cur, self_idx, nbr_idx,
          mm_W1 + (size_t)lh*2*F_*HID_, mm_b1 + (size_t)lh*HID_,
          mm_W2 + (size_t)lh*HID_*F_, mm_b2 + (size_t)lh*F_, msgb);
      head_accum<<<(N_*F_)/256, 256, 0, stream>>>(attnb, msgb, cur, nxt, h == 0);
    }
    float* t = cur; cur = nxt; nxt = t;
  }

  for (int h = 0; h < H_; ++h) {
    fused_gate<F_, false><<<N_/64, 256, 0, stream>>>(
        cur, nullptr, nullptr,
        cg_W1 + (size_t)h*F_*HID_, cg_b1 + (size_t)h*HID_,
        cg_W2 + (size_t)h*HID_, cg_b2 + h, gateb);
    seg_attn<K_, false><<<(G_+255)/256, 256, 0, stream>>>(
        gateb, elem_weights, nullptr, c_pow + h, attnb, G_);
    fused_msg<F_, false><<<N_/64, 256, 0, stream>>>(
        cur, nullptr, nullptr,
        cm_W1 + (size_t)h*F_*HID_, cm_b1 + (size_t)h*HID_,
        cm_W2 + (size_t)h*HID_*F_, cm_b2 + (size_t)h*F_, msgb);
    cry_accum<<<(G_*F_)/256, 256, 0, stream>>>(attnb, msgb, out, h == 0);
  }
}

// Round 4
// 1799.013 us; speedup vs baseline: 1.5516x; 1.5516x over previous
//
#include <hip/hip_runtime.h>
#include <hip/hip_bf16.h>

#define G_ 256
#define K_ 16
#define L_ 3
#define H_ 3
#define F_ 64
#define EMB_ 200
#define HID_ 256
#define N_ (G_*K_)          // 4096 nodes
#define E_ (G_*K_*(K_-1))   // 61440 edges

typedef __attribute__((ext_vector_type(8))) short short8;
typedef __attribute__((ext_vector_type(4))) float f32x4;

__device__ __forceinline__ float selu_f(float x) {
  const float scale = 1.0507009873554804934193349852946f;
  const float alpha = 1.6732632423543772848170429916717f;
  return scale * (x > 0.f ? x : alpha * expm1f(x));
}

__device__ __forceinline__ unsigned short f2bf(float x) {
  __hip_bfloat16 h = __float2bfloat16(x);
  return *reinterpret_cast<unsigned short*>(&h);
}

// fea[n, 0:63] = elem_fea_in[n,:] @ W_init + b_init ; fea[n,63] = w[n]
__global__ __launch_bounds__(64) void init_embed(
    const float* __restrict__ fea_in, const float* __restrict__ W,
    const float* __restrict__ b, const float* __restrict__ wts,
    float* __restrict__ fea) {
  __shared__ float row[EMB_];
  int n = blockIdx.x;
  int j = threadIdx.x;
  for (int k = j; k < EMB_; k += 64) row[k] = fea_in[(size_t)n*EMB_ + k];
  __syncthreads();
  if (j < F_-1) {
    float s = b[j];
    for (int k = 0; k < EMB_; ++k) s = fmaf(row[k], W[k*(F_-1) + j], s);
    fea[(size_t)n*F_ + j] = s;
  } else {
    fea[(size_t)n*F_ + (F_-1)] = wts[n];
  }
}

// WcatT[lh][n][k] (bf16, n-major) : n<256 -> mgW1[k][n] ; 256..511 -> mgW1[64+k][n-256]
//                                  ; 512..767 -> mmW1[k][n-512] ; else mmW1[64+k][n-768]
__global__ __launch_bounds__(256) void prep_wcat(
    const float* __restrict__ mg_W1, const float* __restrict__ mm_W1,
    unsigned short* __restrict__ WcatT) {
  int idx = blockIdx.x*256 + threadIdx.x;   // 9*1024*64
  int lh = idx >> 16;
  int n  = (idx >> 6) & 1023;
  int k  = idx & 63;
  const float* W = (n < 512) ? mg_W1 : mm_W1;
  int nn = n & 511;
  int r  = (nn < 256) ? k : (64 + k);
  int c  = nn & 255;
  WcatT[idx] = f2bf(W[(size_t)lh*(2*F_*HID_) + r*HID_ + c]);
}

// W2mT[lh][f][k] = bf16(mm_W2[lh][k][f])
__global__ __launch_bounds__(256) void prep_w2mt(
    const float* __restrict__ mm_W2, unsigned short* __restrict__ W2mT) {
  int idx = blockIdx.x*256 + threadIdx.x;   // 9*64*256
  int lh = idx >> 14;
  int f  = (idx >> 8) & 63;
  int k  = idx & 255;
  W2mT[idx] = f2bf(mm_W2[(size_t)lh*(HID_*F_) + k*F_ + f]);
}

__global__ __launch_bounds__(256) void conv_bf16(
    const float* __restrict__ in, unsigned short* __restrict__ out, int n) {
  int i = blockIdx.x*256 + threadIdx.x;
  if (i < n) out[i] = f2bf(in[i]);
}

// PQ[4096][1024] = feaBF[4096][64] @ Wcat[64][1024]   (MFMA, bf16 in, f32 out)
__global__ __launch_bounds__(256) void gemm_pq(
    const unsigned short* __restrict__ A,   // [4096][64] bf16
    const unsigned short* __restrict__ BT,  // [1024][64] bf16 (n-major)
    float* __restrict__ C) {
  __shared__ __align__(16) unsigned short As[64][72];
  __shared__ __align__(16) unsigned short Bs[128][72];
  int t = threadIdx.x;
  int m0 = blockIdx.x * 64;
  int n0 = blockIdx.y * 128;
  {
    int row = t >> 2, ch = (t & 3) * 16;
    const uint4* src = (const uint4*)(A + (size_t)(m0 + row)*64 + ch);
    *(uint4*)&As[row][ch]     = src[0];
    *(uint4*)&As[row][ch + 8] = src[1];
    int row2 = t >> 1, ch2 = (t & 1) * 32;
    const uint4* s2 = (const uint4*)(BT + (size_t)(n0 + row2)*64 + ch2);
    uint4* d2 = (uint4*)&Bs[row2][ch2];
    d2[0] = s2[0]; d2[1] = s2[1]; d2[2] = s2[2]; d2[3] = s2[3];
  }
  __syncthreads();
  int w = t >> 6, lane = t & 63;
  int mr = lane & 15, q = lane >> 4;
  short8 a0 = *(const short8*)&As[w*16 + mr][q*8];
  short8 a1 = *(const short8*)&As[w*16 + mr][32 + q*8];
  #pragma unroll
  for (int nt = 0; nt < 8; ++nt) {
    short8 b0 = *(const short8*)&Bs[nt*16 + mr][q*8];
    short8 b1 = *(const short8*)&Bs[nt*16 + mr][32 + q*8];
    f32x4 z = {0.f, 0.f, 0.f, 0.f};
    z = __builtin_amdgcn_mfma_f32_16x16x32_bf16(a0, b0, z, 0, 0, 0);
    z = __builtin_amdgcn_mfma_f32_16x16x32_bf16(a1, b1, z, 0, 0, 0);
    #pragma unroll
    for (int r = 0; r < 4; ++r)
      C[(size_t)(m0 + w*16 + q*4 + r)*1024 + n0 + nt*16 + mr] = z[r];
  }
}

// Per-graph: gate[e]=selu(Pg[i]+Qg[j]+b1).W2+b2 ; softmax w/ w^pow per self node -> attn[E]
__global__ __launch_bounds__(256) void gate_attn(
    const float* __restrict__ PQ, const float* __restrict__ b1,
    const float* __restrict__ W2, const float* __restrict__ b2p,
    const float* __restrict__ powp, const float* __restrict__ wts,
    float* __restrict__ attn_out) {
  __shared__ float PQg[16][516];
  __shared__ float gateL[240];
  int t = threadIdx.x;
  int g = blockIdx.x, g16 = g * 16;
  #pragma unroll
  for (int s = 0; s < 8; ++s) {
    int u = s*256 + t;
    int row = u >> 7, c4 = (u & 127) * 4;
    *(float4*)&PQg[row][c4] = *(const float4*)(PQ + (size_t)(g16 + row)*1024 + c4);
  }
  __syncthreads();
  if (t < 240) {
    int i = t / 15, jj = t - i*15;
    int j = (jj < i) ? jj : jj + 1;
    float s = 0.f;
    #pragma unroll 4
    for (int c = 0; c < 256; ++c) {
      float h = selu_f(PQg[i][c] + PQg[j][256 + c] + b1[c]);
      s = fmaf(h, W2[c], s);
    }
    gateL[t] = s + b2p[0];
  }
  __syncthreads();
  if (t < 16) {
    int i = t;
    float pw = powp[0];
    float m = -1e30f;
    #pragma unroll
    for (int jj = 0; jj < 15; ++jj) m = fmaxf(m, gateL[i*15 + jj]);
    float v[15]; float den = 0.f;
    #pragma unroll
    for (int jj = 0; jj < 15; ++jj) {
      int j = (jj < i) ? jj : jj + 1;
      float w = wts[g16 + j];
      float x = powf(w, pw) * expf(gateL[i*15 + jj] - m);
      v[jj] = x; den += x;
    }
    den += 1e-10f;
    #pragma unroll
    for (int jj = 0; jj < 15; ++jj)
      attn_out[(size_t)g*240 + i*15 + jj] = v[jj] / den;
  }
}

// Per-graph: hid=selu(Pm[i]+Qm[j]+b1) -> (MFMA) msg = hid@W2 ; fea_nxt += attn-weighted mean
__global__ __launch_bounds__(256) void msg_accum(
    const float* __restrict__ PQ, const unsigned short* __restrict__ W2T,
    const float* __restrict__ b1, const float* __restrict__ b2,
    const float* __restrict__ attn, const float* __restrict__ fea_cur,
    float* __restrict__ fea_nxt, int first) {
  __shared__ float PQm[16][516];
  __shared__ __align__(16) unsigned short hidc[240][40];
  __shared__ __align__(16) unsigned short W2c[64][40];
  __shared__ float attnL[240];
  __shared__ float accum[16][64];
  __shared__ float sumat[16];
  int t = threadIdx.x;
  int g = blockIdx.x, g16 = g * 16;
  #pragma unroll
  for (int s = 0; s < 8; ++s) {
    int u = s*256 + t;
    int row = u >> 7, c4 = (u & 127) * 4;
    *(float4*)&PQm[row][c4] = *(const float4*)(PQ + (size_t)(g16 + row)*1024 + 512 + c4);
  }
  if (t < 240) attnL[t] = attn[(size_t)g*240 + t];
  #pragma unroll
  for (int s = 0; s < 4; ++s) ((float*)accum)[s*256 + t] = 0.f;
  __syncthreads();
  if (t < 16) {
    float s = 0.f;
    for (int jj = 0; jj < 15; ++jj) s += attnL[t*15 + jj];
    sumat[t] = s;
  }
  int w = t >> 6, lane = t & 63, mr = lane & 15, q = lane >> 4;
  int nmt = (w < 3) ? 4 : 3;   // m-tiles per wave: 15 tiles of 16 edges
  f32x4 acc[4][4];
  #pragma unroll
  for (int mi = 0; mi < 4; ++mi)
    #pragma unroll
    for (int nt = 0; nt < 4; ++nt) { f32x4 z = {0.f,0.f,0.f,0.f}; acc[mi][nt] = z; }

  for (int kc = 0; kc < 8; ++kc) {          // K=256 in chunks of 32
    for (int s = 0; s < 30; ++s) {          // hid chunk: 240x32
      int u = s*256 + t;
      int e = u >> 5, c = u & 31;
      int i = e / 15, jj = e - i*15;
      int j = (jj < i) ? jj : jj + 1;
      int cc = kc*32 + c;
      hidc[e][c] = f2bf(selu_f(PQm[i][cc] + PQm[j][256 + cc] + b1[cc]));
    }
    #pragma unroll
    for (int s = 0; s < 8; ++s) {           // W2 chunk: 64x32
      int u = s*256 + t;
      int n = u >> 5, c = u & 31;
      W2c[n][c] = W2T[n*256 + kc*32 + c];
    }
    __syncthreads();
    short8 b[4];
    #pragma unroll
    for (int nt = 0; nt < 4; ++nt)
      b[nt] = *(const short8*)&W2c[nt*16 + mr][q*8];
    for (int mi = 0; mi < nmt; ++mi) {
      int mt = w + mi*4;
      short8 a = *(const short8*)&hidc[mt*16 + mr][q*8];
      #pragma unroll
      for (int nt = 0; nt < 4; ++nt)
        acc[mi][nt] = __builtin_amdgcn_mfma_f32_16x16x32_bf16(a, b[nt], acc[mi][nt], 0, 0, 0);
    }
    __syncthreads();
  }
  // attn-weighted accumulate into per-node accum (run-length reduce then LDS atomics)
  for (int mi = 0; mi < nmt; ++mi) {
    int mt = w + mi*4;
    int ebase = mt*16 + q*4;
    #pragma unroll
    for (int nt = 0; nt < 4; ++nt) {
      int f = nt*16 + mr;
      int icur = ebase / 15; float vsum = 0.f;
      #pragma unroll
      for (int r = 0; r < 4; ++r) {
        int e = ebase + r;
        int ie = e / 15;
        float v = acc[mi][nt][r] * attnL[e];
        if (ie != icur) { atomicAdd(&accum[icur][f], vsum); vsum = 0.f; icur = ie; }
        vsum += v;
      }
      atomicAdd(&accum[icur][f], vsum);
    }
  }
  __syncthreads();
  #pragma unroll
  for (int s = 0; s < 4; ++s) {
    int u = s*256 + t;
    int i = u >> 6, f = u & 63;
    float val = (accum[i][f] + b2[f]*sumat[i]) * (1.f/3.f);
    size_t o = (size_t)(g16 + i)*64 + f;
    fea_nxt[o] = (first ? fea_cur[o] : fea_nxt[o]) + val;
  }
}

// ------------------- crystal phase (f32, unchanged from R3) -------------------
template<int KD, bool GATHER>
__global__ __launch_bounds__(256) void fused_gate(
    const float* __restrict__ fea, const int* __restrict__ self_idx,
    const int* __restrict__ nbr_idx,
    const float* __restrict__ W1, const float* __restrict__ b1,
    const float* __restrict__ W2, const float* __restrict__ b2p,
    float* __restrict__ gate) {
  __shared__ float AsT[KD][68];
  __shared__ float Ws[16][68];
  __shared__ float red[64][17];
  int tid = threadIdx.x;
  int m0 = blockIdx.x * 64;
  for (int idx = tid; idx < 64*KD; idx += 256) {
    int r = idx / KD, c = idx - r*KD;
    float v;
    if (GATHER) {
      int node = (c < F_) ? self_idx[m0+r] : nbr_idx[m0+r];
      v = fea[node*F_ + (c & (F_-1))];
    } else {
      v = fea[(size_t)(m0+r)*KD + c];
    }
    AsT[c][r] = v;
  }
  __syncthreads();
  int tr = tid >> 4, tc = tid & 15;
  float partial[4] = {0.f, 0.f, 0.f, 0.f};
  for (int cch = 0; cch < HID_/64; ++cch) {
    float acc[4][4] = {};
    for (int k0 = 0; k0 < KD; k0 += 16) {
      int wr = tid >> 6, wc = tid & 63;
      #pragma unroll
      for (int rr = 0; rr < 4; ++rr)
        Ws[wr + rr*4][wc] = W1[(size_t)(k0 + wr + rr*4)*HID_ + cch*64 + wc];
      __syncthreads();
      #pragma unroll
      for (int kk = 0; kk < 16; ++kk) {
        float a[4], b[4];
        #pragma unroll
        for (int i = 0; i < 4; ++i) a[i] = AsT[k0+kk][tr*4+i];
        #pragma unroll
        for (int j = 0; j < 4; ++j) b[j] = Ws[kk][tc*4+j];
        #pragma unroll
        for (int i = 0; i < 4; ++i)
          #pragma unroll
          for (int j = 0; j < 4; ++j) acc[i][j] = fmaf(a[i], b[j], acc[i][j]);
      }
      __syncthreads();
    }
    #pragma unroll
    for (int j = 0; j < 4; ++j) {
      int n = cch*64 + tc*4 + j;
      float w2 = W2[n];
      float bb = b1[n];
      #pragma unroll
      for (int i = 0; i < 4; ++i)
        partial[i] = fmaf(selu_f(acc[i][j] + bb), w2, partial[i]);
    }
  }
  #pragma unroll
  for (int i = 0; i < 4; ++i) red[tr*4+i][tc] = partial[i];
  __syncthreads();
  if (tid < 64) {
    float s = 0.f;
    #pragma unroll
    for (int t2 = 0; t2 < 16; ++t2) s += red[tid][t2];
    gate[m0 + tid] = s + *b2p;
  }
}

template<int KD, bool GATHER>
__global__ __launch_bounds__(256) void fused_msg(
    const float* __restrict__ fea, const int* __restrict__ self_idx,
    const int* __restrict__ nbr_idx,
    const float* __restrict__ W1, const float* __restrict__ b1,
    const float* __restrict__ W2, const float* __restrict__ b2,
    float* __restrict__ msg) {
  __shared__ float AsT[KD][68];
  __shared__ float HsT[64][68];
  __shared__ float Ws[16][68];
  int tid = threadIdx.x;
  int m0 = blockIdx.x * 64;
  for (int idx = tid; idx < 64*KD; idx += 256) {
    int r = idx / KD, c = idx - r*KD;
    float v;
    if (GATHER) {
      int node = (c < F_) ? self_idx[m0+r] : nbr_idx[m0+r];
      v = fea[node*F_ + (c & (F_-1))];
    } else {
      v = fea[(size_t)(m0+r)*KD + c];
    }
    AsT[c][r] = v;
  }
  __syncthreads();
  int tr = tid >> 4, tc = tid & 15;
  float accM[4][4] = {};
  for (int cch = 0; cch < HID_/64; ++cch) {
    float accH[4][4] = {};
    for (int k0 = 0; k0 < KD; k0 += 16) {
      int wr = tid >> 6, wc = tid & 63;
      #pragma unroll
      for (int rr = 0; rr < 4; ++rr)
        Ws[wr + rr*4][wc] = W1[(size_t)(k0 + wr + rr*4)*HID_ + cch*64 + wc];
      __syncthreads();
      #pragma unroll
      for (int kk = 0; kk < 16; ++kk) {
        float a[4], b[4];
        #pragma unroll
        for (int i = 0; i < 4; ++i) a[i] = AsT[k0+kk][tr*4+i];
        #pragma unroll
        for (int j = 0; j < 4; ++j) b[j] = Ws[kk][tc*4+j];
        #pragma unroll
        for (int i = 0; i < 4; ++i)
          #pragma unroll
          for (int j = 0; j < 4; ++j) accH[i][j] = fmaf(a[i], b[j], accH[i][j]);
      }
      __syncthreads();
    }
    #pragma unroll
    for (int j = 0; j < 4; ++j) {
      int n = cch*64 + tc*4 + j;
      float bb = b1[n];
      #pragma unroll
      for (int i = 0; i < 4; ++i)
        HsT[tc*4+j][tr*4+i] = selu_f(accH[i][j] + bb);
    }
    __syncthreads();
    for (int k1 = 0; k1 < 64; k1 += 16) {
      int wr = tid >> 6, wc = tid & 63;
      #pragma unroll
      for (int rr = 0; rr < 4; ++rr)
        Ws[wr + rr*4][wc] = W2[(size_t)(cch*64 + k1 + wr + rr*4)*F_ + wc];
      __syncthreads();
      #pragma unroll
      for (int kk = 0; kk < 16; ++kk) {
        float a[4], b[4];
        #pragma unroll
        for (int i = 0; i < 4; ++i) a[i] = HsT[k1+kk][tr*4+i];
        #pragma unroll
        for (int j = 0; j < 4; ++j) b[j] = Ws[kk][tc*4+j];
        #pragma unroll
        for (int i = 0; i < 4; ++i)
          #pragma unroll
          for (int j = 0; j < 4; ++j) accM[i][j] = fmaf(a[i], b[j], accM[i][j]);
      }
      __syncthreads();
    }
  }
  #pragma unroll
  for (int j = 0; j < 4; ++j) {
    float bb = b2[tc*4+j];
    #pragma unroll
    for (int i = 0; i < 4; ++i)
      msg[(size_t)(m0 + tr*4 + i)*F_ + tc*4 + j] = accM[i][j] + bb;
  }
}

template<int SEGLEN, bool USE_IDX>
__global__ __launch_bounds__(256) void seg_attn(
    const float* __restrict__ gate, const float* __restrict__ wts,
    const int* __restrict__ nidx, const float* __restrict__ powp,
    float* __restrict__ attn, int nseg) {
  int n = blockIdx.x*256 + threadIdx.x;
  if (n >= nseg) return;
  float pw = *powp;
  float g[SEGLEN];
  float m = -1e30f;
  #pragma unroll
  for (int j = 0; j < SEGLEN; ++j) { g[j] = gate[n*SEGLEN+j]; m = fmaxf(m, g[j]); }
  float den = 0.f;
  #pragma unroll
  for (int j = 0; j < SEGLEN; ++j) {
    int widx = USE_IDX ? nidx[n*SEGLEN+j] : n*SEGLEN+j;
    float w = wts[widx];
    float v = powf(w, pw) * expf(g[j] - m);
    g[j] = v; den += v;
  }
  den += 1e-10f;
  #pragma unroll
  for (int j = 0; j < SEGLEN; ++j) attn[n*SEGLEN+j] = g[j] / den;
}

__global__ __launch_bounds__(256) void cry_accum(
    const float* __restrict__ attn, const float* __restrict__ msg,
    float* __restrict__ outacc, int first) {
  int idx = blockIdx.x*256 + threadIdx.x;   // G_*F_
  int g = idx >> 6, f = idx & 63;
  float s = 0.f;
  #pragma unroll
  for (int j = 0; j < K_; ++j)
    s = fmaf(attn[g*K_+j], msg[(size_t)(g*K_+j)*F_ + f], s);
  s *= (1.f/(float)H_);
  outacc[idx] = first ? s : outacc[idx] + s;
}

extern "C" void kernel_launch(void* const* d_in, const int* in_sizes, int n_in,
                              void* d_out, int out_size, void* d_ws, size_t ws_size,
                              hipStream_t stream) {
  const float* elem_weights = (const float*)d_in[0];
  const float* elem_fea_in  = (const float*)d_in[1];
  const float* W_init = (const float*)d_in[2];
  const float* b_init = (const float*)d_in[3];
  const float* mg_W1  = (const float*)d_in[4];
  const float* mg_b1  = (const float*)d_in[5];
  const float* mg_W2  = (const float*)d_in[6];
  const float* mg_b2  = (const float*)d_in[7];
  const float* mm_W1  = (const float*)d_in[8];
  const float* mm_b1  = (const float*)d_in[9];
  const float* mm_W2  = (const float*)d_in[10];
  const float* mm_b2  = (const float*)d_in[11];
  const float* m_pow  = (const float*)d_in[12];
  const float* cg_W1  = (const float*)d_in[13];
  const float* cg_b1  = (const float*)d_in[14];
  const float* cg_W2  = (const float*)d_in[15];
  const float* cg_b2  = (const float*)d_in[16];
  const float* cm_W1  = (const float*)d_in[17];
  const float* cm_b1  = (const float*)d_in[18];
  const float* cm_W2  = (const float*)d_in[19];
  const float* cm_b2  = (const float*)d_in[20];
  const float* c_pow  = (const float*)d_in[21];

  // workspace layout (~21 MB)
  float* ws    = (float*)d_ws;
  float* PQ    = ws;                            // 4096*1024 f32
  float* feaA  = PQ   + (size_t)4096*1024;      // N*F
  float* feaB  = feaA + (size_t)N_*F_;          // N*F
  float* attnb = feaB + (size_t)N_*F_;          // E_
  unsigned short* feaBF = (unsigned short*)(attnb + E_);   // N*F bf16
  unsigned short* WcatT = feaBF + (size_t)N_*F_;           // 9*1024*64
  unsigned short* W2mT  = WcatT + (size_t)9*1024*64;       // 9*64*256
  float* gatec = attnb;            // crystal gate (N_) — attnb free by then
  float* attnc = attnb + N_;       // crystal attn (N_)
  float* msgc  = PQ;               // crystal msg (N_*F_) — PQ free by then

  prep_wcat<<<(9*1024*64)/256, 256, 0, stream>>>(mg_W1, mm_W1, WcatT);
  prep_w2mt<<<(9*64*256)/256, 256, 0, stream>>>(mm_W2, W2mT);
  init_embed<<<N_, 64, 0, stream>>>(elem_fea_in, W_init, b_init, elem_weights, feaA);

  float* cur = feaA; float* nxt = feaB;
  for (int l = 0; l < L_; ++l) {
    conv_bf16<<<(N_*F_)/256, 256, 0, stream>>>(cur, feaBF, N_*F_);
    for (int h = 0; h < H_; ++h) {
      int lh = l*H_ + h;
      gemm_pq<<<dim3(64, 8), 256, 0, stream>>>(feaBF, WcatT + (size_t)lh*1024*64, PQ);
      gate_attn<<<G_, 256, 0, stream>>>(
          PQ, mg_b1 + (size_t)lh*HID_, mg_W2 + (size_t)lh*HID_, mg_b2 + lh,
          m_pow + lh, elem_weights, attnb);
      msg_accum<<<G_, 256, 0, stream>>>(
          PQ, W2mT + (size_t)lh*64*256, mm_b1 + (size_t)lh*HID_,
          mm_b2 + (size_t)lh*F_, attnb, cur, nxt, h == 0);
    }
    float* t = cur; cur = nxt; nxt = t;
  }

  float* out = (float*)d_out;
  for (int h = 0; h < H_; ++h) {
    fused_gate<F_, false><<<N_/64, 256, 0, stream>>>(
        cur, nullptr, nullptr,
        cg_W1 + (size_t)h*F_*HID_, cg_b1 + (size_t)h*HID_,
        cg_W2 + (size_t)h*HID_, cg_b2 + h, gatec);
    seg_attn<K_, false><<<(G_+255)/256, 256, 0, stream>>>(
        gatec, elem_weights, nullptr, c_pow + h, attnc, G_);
    fused_msg<F_, false><<<N_/64, 256, 0, stream>>>(
        cur, nullptr, nullptr,
        cm_W1 + (size_t)h*F_*HID_, cm_b1 + (size_t)h*HID_,
        cm_W2 + (size_t)h*HID_*F_, cm_b2 + (size_t)h*F_, msgc);
    cry_accum<<<(G_*F_)/256, 256, 0, stream>>>(attnc, msgc, out, h == 0);
  }
}

// Round 5
// 1295.650 us; speedup vs baseline: 2.1544x; 1.3885x over previous
//
#include <hip/hip_runtime.h>
#include <hip/hip_bf16.h>

#define G_ 256
#define K_ 16
#define L_ 3
#define H_ 3
#define F_ 64
#define EMB_ 200
#define HID_ 256
#define N_ (G_*K_)          // 4096 nodes
#define E_ (G_*K_*(K_-1))   // 61440 edges

typedef __attribute__((ext_vector_type(8))) short short8;
typedef __attribute__((ext_vector_type(4))) float f32x4;

__device__ __forceinline__ float selu_f(float x) {
  const float scale = 1.0507009873554804934193349852946f;
  const float alpha = 1.6732632423543772848170429916717f;
  return scale * (x > 0.f ? x : alpha * expm1f(x));
}

__device__ __forceinline__ unsigned short f2bf(float x) {
  __hip_bfloat16 h = __float2bfloat16(x);
  return *reinterpret_cast<unsigned short*>(&h);
}

// fea[n, 0:63] = elem_fea_in[n,:] @ W_init + b_init ; fea[n,63] = w[n]
__global__ __launch_bounds__(64) void init_embed(
    const float* __restrict__ fea_in, const float* __restrict__ W,
    const float* __restrict__ b, const float* __restrict__ wts,
    float* __restrict__ fea) {
  __shared__ float row[EMB_];
  int n = blockIdx.x;
  int j = threadIdx.x;
  for (int k = j; k < EMB_; k += 64) row[k] = fea_in[(size_t)n*EMB_ + k];
  __syncthreads();
  if (j < F_-1) {
    float s = b[j];
    for (int k = 0; k < EMB_; ++k) s = fmaf(row[k], W[k*(F_-1) + j], s);
    fea[(size_t)n*F_ + j] = s;
  } else {
    fea[(size_t)n*F_ + (F_-1)] = wts[n];
  }
}

// WcatT[lh][n][k] (bf16, n-major): n<256 -> mgW1[k][n]; 256..511 -> mgW1[64+k][n-256]
//                                 ; 512..767 -> mmW1[k][n-512]; else mmW1[64+k][n-768]
__global__ __launch_bounds__(256) void prep_wcat(
    const float* __restrict__ mg_W1, const float* __restrict__ mm_W1,
    unsigned short* __restrict__ WcatT) {
  int idx = blockIdx.x*256 + threadIdx.x;   // 9*1024*64
  int lh = idx >> 16;
  int n  = (idx >> 6) & 1023;
  int k  = idx & 63;
  const float* W = (n < 512) ? mg_W1 : mm_W1;
  int nn = n & 511;
  int r  = (nn < 256) ? k : (64 + k);
  int c  = nn & 255;
  WcatT[idx] = f2bf(W[(size_t)lh*(2*F_*HID_) + r*HID_ + c]);
}

// W2mT[lh][f][k] = bf16(mm_W2[lh][k][f])
__global__ __launch_bounds__(256) void prep_w2mt(
    const float* __restrict__ mm_W2, unsigned short* __restrict__ W2mT) {
  int idx = blockIdx.x*256 + threadIdx.x;   // 9*64*256
  int lh = idx >> 14;
  int f  = (idx >> 8) & 63;
  int k  = idx & 255;
  W2mT[idx] = f2bf(mm_W2[(size_t)lh*(HID_*F_) + k*F_ + f]);
}

// WcryT[n][k] (bf16, n-major, 1536 x 64): h=n/512, r=n%512;
//   r<256 -> cg_W1[h][k][r] ; else cm_W1[h][k][r-256]
__global__ __launch_bounds__(256) void prep_wcry(
    const float* __restrict__ cg_W1, const float* __restrict__ cm_W1,
    unsigned short* __restrict__ WcryT) {
  int idx = blockIdx.x*256 + threadIdx.x;   // 1536*64
  int n = idx >> 6, k = idx & 63;
  int h = n >> 9, r = n & 511;
  float v = (r < 256) ? cg_W1[(size_t)h*F_*HID_ + k*HID_ + r]
                      : cm_W1[(size_t)h*F_*HID_ + k*HID_ + (r - 256)];
  WcryT[idx] = f2bf(v);
}

// W2cT[h][f][k] = bf16(cm_W2[h][k][f])
__global__ __launch_bounds__(256) void prep_w2c(
    const float* __restrict__ cm_W2, unsigned short* __restrict__ W2cT) {
  int idx = blockIdx.x*256 + threadIdx.x;   // 3*64*256
  int h = idx >> 14;
  int f = (idx >> 8) & 63;
  int k = idx & 255;
  W2cT[idx] = f2bf(cm_W2[(size_t)h*HID_*F_ + k*F_ + f]);
}

__global__ __launch_bounds__(256) void conv_bf16(
    const float* __restrict__ in, unsigned short* __restrict__ out, int n) {
  int i = blockIdx.x*256 + threadIdx.x;
  if (i < n) out[i] = f2bf(in[i]);
}

// C[4096][NSTR block] = A[4096][64] @ BT^T ; BT is [n][k] bf16, MFMA f32 accum
__global__ __launch_bounds__(256) void gemm_pq(
    const unsigned short* __restrict__ A,   // [4096][64] bf16
    const unsigned short* __restrict__ BT,  // [Ntot][64] bf16 (n-major)
    float* __restrict__ C, int NSTR) {
  __shared__ __align__(16) unsigned short As[64][72];
  __shared__ __align__(16) unsigned short Bs[128][72];
  int t = threadIdx.x;
  int m0 = blockIdx.x * 64;
  int n0 = blockIdx.y * 128;
  {
    int row = t >> 2, ch = (t & 3) * 16;
    const uint4* src = (const uint4*)(A + (size_t)(m0 + row)*64 + ch);
    *(uint4*)&As[row][ch]     = src[0];
    *(uint4*)&As[row][ch + 8] = src[1];
    int row2 = t >> 1, ch2 = (t & 1) * 32;
    const uint4* s2 = (const uint4*)(BT + (size_t)(n0 + row2)*64 + ch2);
    uint4* d2 = (uint4*)&Bs[row2][ch2];
    d2[0] = s2[0]; d2[1] = s2[1]; d2[2] = s2[2]; d2[3] = s2[3];
  }
  __syncthreads();
  int w = t >> 6, lane = t & 63;
  int mr = lane & 15, q = lane >> 4;
  short8 a0 = *(const short8*)&As[w*16 + mr][q*8];
  short8 a1 = *(const short8*)&As[w*16 + mr][32 + q*8];
  #pragma unroll
  for (int nt = 0; nt < 8; ++nt) {
    short8 b0 = *(const short8*)&Bs[nt*16 + mr][q*8];
    short8 b1 = *(const short8*)&Bs[nt*16 + mr][32 + q*8];
    f32x4 z = {0.f, 0.f, 0.f, 0.f};
    z = __builtin_amdgcn_mfma_f32_16x16x32_bf16(a0, b0, z, 0, 0, 0);
    z = __builtin_amdgcn_mfma_f32_16x16x32_bf16(a1, b1, z, 0, 0, 0);
    #pragma unroll
    for (int r = 0; r < 4; ++r)
      C[(size_t)(m0 + w*16 + q*4 + r)*NSTR + n0 + nt*16 + mr] = z[r];
  }
}

// Per-graph edge gate+attn (unchanged from R4)
__global__ __launch_bounds__(256) void gate_attn(
    const float* __restrict__ PQ, const float* __restrict__ b1,
    const float* __restrict__ W2, const float* __restrict__ b2p,
    const float* __restrict__ powp, const float* __restrict__ wts,
    float* __restrict__ attn_out) {
  __shared__ float PQg[16][516];
  __shared__ float gateL[240];
  int t = threadIdx.x;
  int g = blockIdx.x, g16 = g * 16;
  #pragma unroll
  for (int s = 0; s < 8; ++s) {
    int u = s*256 + t;
    int row = u >> 7, c4 = (u & 127) * 4;
    *(float4*)&PQg[row][c4] = *(const float4*)(PQ + (size_t)(g16 + row)*1024 + c4);
  }
  __syncthreads();
  if (t < 240) {
    int i = t / 15, jj = t - i*15;
    int j = (jj < i) ? jj : jj + 1;
    float s = 0.f;
    #pragma unroll 4
    for (int c = 0; c < 256; ++c) {
      float h = selu_f(PQg[i][c] + PQg[j][256 + c] + b1[c]);
      s = fmaf(h, W2[c], s);
    }
    gateL[t] = s + b2p[0];
  }
  __syncthreads();
  if (t < 16) {
    int i = t;
    float pw = powp[0];
    float m = -1e30f;
    #pragma unroll
    for (int jj = 0; jj < 15; ++jj) m = fmaxf(m, gateL[i*15 + jj]);
    float v[15]; float den = 0.f;
    #pragma unroll
    for (int jj = 0; jj < 15; ++jj) {
      int j = (jj < i) ? jj : jj + 1;
      float w = wts[g16 + j];
      float x = powf(w, pw) * expf(gateL[i*15 + jj] - m);
      v[jj] = x; den += x;
    }
    den += 1e-10f;
    #pragma unroll
    for (int jj = 0; jj < 15; ++jj)
      attn_out[(size_t)g*240 + i*15 + jj] = v[jj] / den;
  }
}

// Per-graph edge msg + residual accumulate (unchanged from R4)
__global__ __launch_bounds__(256) void msg_accum(
    const float* __restrict__ PQ, const unsigned short* __restrict__ W2T,
    const float* __restrict__ b1, const float* __restrict__ b2,
    const float* __restrict__ attn, const float* __restrict__ fea_cur,
    float* __restrict__ fea_nxt, int first) {
  __shared__ float PQm[16][516];
  __shared__ __align__(16) unsigned short hidc[240][40];
  __shared__ __align__(16) unsigned short W2c[64][40];
  __shared__ float attnL[240];
  __shared__ float accum[16][64];
  __shared__ float sumat[16];
  int t = threadIdx.x;
  int g = blockIdx.x, g16 = g * 16;
  #pragma unroll
  for (int s = 0; s < 8; ++s) {
    int u = s*256 + t;
    int row = u >> 7, c4 = (u & 127) * 4;
    *(float4*)&PQm[row][c4] = *(const float4*)(PQ + (size_t)(g16 + row)*1024 + 512 + c4);
  }
  if (t < 240) attnL[t] = attn[(size_t)g*240 + t];
  #pragma unroll
  for (int s = 0; s < 4; ++s) ((float*)accum)[s*256 + t] = 0.f;
  __syncthreads();
  if (t < 16) {
    float s = 0.f;
    for (int jj = 0; jj < 15; ++jj) s += attnL[t*15 + jj];
    sumat[t] = s;
  }
  int w = t >> 6, lane = t & 63, mr = lane & 15, q = lane >> 4;
  int nmt = (w < 3) ? 4 : 3;
  f32x4 acc[4][4];
  #pragma unroll
  for (int mi = 0; mi < 4; ++mi)
    #pragma unroll
    for (int nt = 0; nt < 4; ++nt) { f32x4 z = {0.f,0.f,0.f,0.f}; acc[mi][nt] = z; }

  for (int kc = 0; kc < 8; ++kc) {
    for (int s = 0; s < 30; ++s) {
      int u = s*256 + t;
      int e = u >> 5, c = u & 31;
      int i = e / 15, jj = e - i*15;
      int j = (jj < i) ? jj : jj + 1;
      int cc = kc*32 + c;
      hidc[e][c] = f2bf(selu_f(PQm[i][cc] + PQm[j][256 + cc] + b1[cc]));
    }
    #pragma unroll
    for (int s = 0; s < 8; ++s) {
      int u = s*256 + t;
      int n = u >> 5, c = u & 31;
      W2c[n][c] = W2T[n*256 + kc*32 + c];
    }
    __syncthreads();
    short8 b[4];
    #pragma unroll
    for (int nt = 0; nt < 4; ++nt)
      b[nt] = *(const short8*)&W2c[nt*16 + mr][q*8];
    for (int mi = 0; mi < nmt; ++mi) {
      int mt = w + mi*4;
      short8 a = *(const short8*)&hidc[mt*16 + mr][q*8];
      #pragma unroll
      for (int nt = 0; nt < 4; ++nt)
        acc[mi][nt] = __builtin_amdgcn_mfma_f32_16x16x32_bf16(a, b[nt], acc[mi][nt], 0, 0, 0);
    }
    __syncthreads();
  }
  for (int mi = 0; mi < nmt; ++mi) {
    int mt = w + mi*4;
    int ebase = mt*16 + q*4;
    #pragma unroll
    for (int nt = 0; nt < 4; ++nt) {
      int f = nt*16 + mr;
      int icur = ebase / 15; float vsum = 0.f;
      #pragma unroll
      for (int r = 0; r < 4; ++r) {
        int e = ebase + r;
        int ie = e / 15;
        float v = acc[mi][nt][r] * attnL[e];
        if (ie != icur) { atomicAdd(&accum[icur][f], vsum); vsum = 0.f; icur = ie; }
        vsum += v;
      }
      atomicAdd(&accum[icur][f], vsum);
    }
  }
  __syncthreads();
  #pragma unroll
  for (int s = 0; s < 4; ++s) {
    int u = s*256 + t;
    int i = u >> 6, f = u & 63;
    float val = (accum[i][f] + b2[f]*sumat[i]) * (1.f/3.f);
    size_t o = (size_t)(g16 + i)*64 + f;
    fea_nxt[o] = (first ? fea_cur[o] : fea_nxt[o]) + val;
  }
}

// ---------------------------------------------------------------------------
// Crystal phase, fully fused: per graph, all 3 heads.
// PQc[node][h*512 + c]: c<256 gate pre-act col c ; c>=256 msg pre-act col c-256
// ---------------------------------------------------------------------------
__global__ __launch_bounds__(256) void cry_fused(
    const float* __restrict__ PQc,          // [4096][1536]
    const unsigned short* __restrict__ W2cT,// [3][64][256] bf16
    const float* __restrict__ cg_b1, const float* __restrict__ cg_W2,
    const float* __restrict__ cg_b2, const float* __restrict__ cm_b1,
    const float* __restrict__ cm_b2, const float* __restrict__ c_pow,
    const float* __restrict__ wts, float* __restrict__ out) {
  __shared__ float PQh[16][520];
  __shared__ float gred[16][18];
  __shared__ float attnL[16];
  __shared__ float sumatS;
  __shared__ __align__(16) unsigned short hidc[16][264];
  __shared__ float outg[64];
  int t = threadIdx.x;
  int g = blockIdx.x, g16 = g*16;
  if (t < 64) outg[t] = 0.f;
  for (int h = 0; h < H_; ++h) {
    __syncthreads();
    #pragma unroll
    for (int s = 0; s < 8; ++s) {
      int u = s*256 + t;
      int row = u >> 7, c4 = (u & 127)*4;
      *(float4*)&PQh[row][c4] = *(const float4*)(PQc + (size_t)(g16+row)*1536 + h*512 + c4);
    }
    __syncthreads();
    {
      int i = t >> 4, c0 = (t & 15) * 16;
      float s = 0.f;
      #pragma unroll
      for (int c = c0; c < c0+16; ++c)
        s = fmaf(selu_f(PQh[i][c] + cg_b1[h*HID_ + c]), cg_W2[h*HID_ + c], s);
      gred[i][t & 15] = s;
    }
    __syncthreads();
    if (t < 16) {
      float sg = 0.f;
      #pragma unroll
      for (int u2 = 0; u2 < 16; ++u2) sg += gred[t][u2];
      gred[t][16] = sg + cg_b2[h];
    }
    __syncthreads();
    if (t == 0) {
      float pw = c_pow[h];
      float m = -1e30f;
      #pragma unroll
      for (int i = 0; i < 16; ++i) m = fmaxf(m, gred[i][16]);
      float den = 0.f; float v[16];
      #pragma unroll
      for (int i = 0; i < 16; ++i) {
        float x = powf(wts[g16+i], pw) * expf(gred[i][16] - m);
        v[i] = x; den += x;
      }
      den += 1e-10f;
      float sa = 0.f;
      #pragma unroll
      for (int i = 0; i < 16; ++i) { float a = v[i]/den; attnL[i] = a; sa += a; }
      sumatS = sa;
    }
    {
      int i = t >> 4, c0 = (t & 15) * 16;
      #pragma unroll
      for (int c = c0; c < c0+16; ++c)
        hidc[i][c] = f2bf(selu_f(PQh[i][256 + c] + cm_b1[h*HID_ + c]));
    }
    __syncthreads();
    int w = t >> 6, lane = t & 63, mr = lane & 15, q = lane >> 4;
    f32x4 acc = {0.f, 0.f, 0.f, 0.f};
    #pragma unroll
    for (int kc = 0; kc < 8; ++kc) {
      short8 a = *(const short8*)&hidc[mr][kc*32 + q*8];
      short8 b = *(const short8*)&W2cT[((size_t)h*64 + w*16 + mr)*HID_ + kc*32 + q*8];
      acc = __builtin_amdgcn_mfma_f32_16x16x32_bf16(a, b, acc, 0, 0, 0);
    }
    float p = 0.f;
    #pragma unroll
    for (int r = 0; r < 4; ++r) p = fmaf(attnL[q*4+r], acc[r], p);
    atomicAdd(&outg[w*16+mr], p);
    if (q == 0) atomicAdd(&outg[w*16+mr], cm_b2[h*F_ + w*16 + mr]*sumatS);
  }
  __syncthreads();
  if (t < 64) out[(size_t)g*64 + t] = outg[t] * (1.f/(float)H_);
}

extern "C" void kernel_launch(void* const* d_in, const int* in_sizes, int n_in,
                              void* d_out, int out_size, void* d_ws, size_t ws_size,
                              hipStream_t stream) {
  const float* elem_weights = (const float*)d_in[0];
  const float* elem_fea_in  = (const float*)d_in[1];
  const float* W_init = (const float*)d_in[2];
  const float* b_init = (const float*)d_in[3];
  const float* mg_W1  = (const float*)d_in[4];
  const float* mg_b1  = (const float*)d_in[5];
  const float* mg_W2  = (const float*)d_in[6];
  const float* mg_b2  = (const float*)d_in[7];
  const float* mm_W1  = (const float*)d_in[8];
  const float* mm_b1  = (const float*)d_in[9];
  const float* mm_W2  = (const float*)d_in[10];
  const float* mm_b2  = (const float*)d_in[11];
  const float* m_pow  = (const float*)d_in[12];
  const float* cg_W1  = (const float*)d_in[13];
  const float* cg_b1  = (const float*)d_in[14];
  const float* cg_W2  = (const float*)d_in[15];
  const float* cg_b2  = (const float*)d_in[16];
  const float* cm_W1  = (const float*)d_in[17];
  const float* cm_b1  = (const float*)d_in[18];
  const float* cm_W2  = (const float*)d_in[19];
  const float* cm_b2  = (const float*)d_in[20];
  const float* c_pow  = (const float*)d_in[21];

  // workspace layout (~29 MB). PQ region shared: edge PQ [4096*1024] during
  // layers; crystal PQc [4096*1536] after (edge PQ dead by then).
  float* ws    = (float*)d_ws;
  float* PQ    = ws;                               // union region, 4096*1536 f32
  float* PQc   = ws;
  float* feaA  = ws   + (size_t)4096*1536;         // N*F
  float* feaB  = feaA + (size_t)N_*F_;             // N*F
  float* attnb = feaB + (size_t)N_*F_;             // E_
  unsigned short* feaBF = (unsigned short*)(attnb + E_);   // N*F bf16
  unsigned short* WcatT = feaBF + (size_t)N_*F_;           // 9*1024*64
  unsigned short* W2mT  = WcatT + (size_t)9*1024*64;       // 9*64*256
  unsigned short* WcryT = W2mT  + (size_t)9*64*256;        // 1536*64
  unsigned short* W2cT  = WcryT + (size_t)1536*64;         // 3*64*256

  prep_wcat<<<(9*1024*64)/256, 256, 0, stream>>>(mg_W1, mm_W1, WcatT);
  prep_w2mt<<<(9*64*256)/256, 256, 0, stream>>>(mm_W2, W2mT);
  prep_wcry<<<(1536*64)/256, 256, 0, stream>>>(cg_W1, cm_W1, WcryT);
  prep_w2c<<<(3*64*256)/256, 256, 0, stream>>>(cm_W2, W2cT);
  init_embed<<<N_, 64, 0, stream>>>(elem_fea_in, W_init, b_init, elem_weights, feaA);

  float* cur = feaA; float* nxt = feaB;
  for (int l = 0; l < L_; ++l) {
    conv_bf16<<<(N_*F_)/256, 256, 0, stream>>>(cur, feaBF, N_*F_);
    for (int h = 0; h < H_; ++h) {
      int lh = l*H_ + h;
      gemm_pq<<<dim3(64, 8), 256, 0, stream>>>(feaBF, WcatT + (size_t)lh*1024*64, PQ, 1024);
      gate_attn<<<G_, 256, 0, stream>>>(
          PQ, mg_b1 + (size_t)lh*HID_, mg_W2 + (size_t)lh*HID_, mg_b2 + lh,
          m_pow + lh, elem_weights, attnb);
      msg_accum<<<G_, 256, 0, stream>>>(
          PQ, W2mT + (size_t)lh*64*256, mm_b1 + (size_t)lh*HID_,
          mm_b2 + (size_t)lh*F_, attnb, cur, nxt, h == 0);
    }
    float* t = cur; cur = nxt; nxt = t;
  }

  // crystal phase
  conv_bf16<<<(N_*F_)/256, 256, 0, stream>>>(cur, feaBF, N_*F_);
  gemm_pq<<<dim3(64, 12), 256, 0, stream>>>(feaBF, WcryT, PQc, 1536);
  cry_fused<<<G_, 256, 0, stream>>>(
      PQc, W2cT, cg_b1, cg_W2, cg_b2, cm_b1, cm_b2, c_pow,
      elem_weights, (float*)d_out);
}

// Round 7
// 689.568 us; speedup vs baseline: 4.0479x; 1.8789x over previous
//
#include <hip/hip_runtime.h>
#include <hip/hip_bf16.h>

#define G_ 256
#define K_ 16
#define L_ 3
#define H_ 3
#define F_ 64
#define EMB_ 200
#define HID_ 256
#define N_ (G_*K_)          // 4096 nodes
#define E_ (G_*K_*(K_-1))   // 61440 edges

typedef __attribute__((ext_vector_type(8))) short short8;
typedef __attribute__((ext_vector_type(4))) float f32x4;

__device__ __forceinline__ float selu_f(float x) {
  const float scale = 1.0507009873554804934193349852946f;
  const float alpha = 1.6732632423543772848170429916717f;
  float e = __expf(x) - 1.0f;          // fast expm1 (v_exp_f32)
  return x > 0.f ? scale * x : scale * alpha * e;
}

__device__ __forceinline__ unsigned short f2bf(float x) {
  __hip_bfloat16 h = __float2bfloat16(x);
  return *reinterpret_cast<unsigned short*>(&h);
}

// fea[n, 0:63] = elem_fea_in[n,:] @ W_init + b_init ; fea[n,63] = w[n]
__global__ __launch_bounds__(64) void init_embed(
    const float* __restrict__ fea_in, const float* __restrict__ W,
    const float* __restrict__ b, const float* __restrict__ wts,
    float* __restrict__ fea) {
  __shared__ float row[EMB_];
  int n = blockIdx.x;
  int j = threadIdx.x;
  for (int k = j; k < EMB_; k += 64) row[k] = fea_in[(size_t)n*EMB_ + k];
  __syncthreads();
  if (j < F_-1) {
    float s = b[j];
    for (int k = 0; k < EMB_; ++k) s = fmaf(row[k], W[k*(F_-1) + j], s);
    fea[(size_t)n*F_ + j] = s;
  } else {
    fea[(size_t)n*F_ + (F_-1)] = wts[n];
  }
}

// WcatT[lh][n][k] (bf16, n-major): n<256 -> mgW1[k][n]; 256..511 -> mgW1[64+k][n-256]
//                                 ; 512..767 -> mmW1[k][n-512]; else mmW1[64+k][n-768]
__global__ __launch_bounds__(256) void prep_wcat(
    const float* __restrict__ mg_W1, const float* __restrict__ mm_W1,
    unsigned short* __restrict__ WcatT) {
  int idx = blockIdx.x*256 + threadIdx.x;   // 9*1024*64
  int lh = idx >> 16;
  int n  = (idx >> 6) & 1023;
  int k  = idx & 63;
  const float* W = (n < 512) ? mg_W1 : mm_W1;
  int nn = n & 511;
  int r  = (nn < 256) ? k : (64 + k);
  int c  = nn & 255;
  WcatT[idx] = f2bf(W[(size_t)lh*(2*F_*HID_) + r*HID_ + c]);
}

// W2mT[lh][f][k] = bf16(mm_W2[lh][k][f])
__global__ __launch_bounds__(256) void prep_w2mt(
    const float* __restrict__ mm_W2, unsigned short* __restrict__ W2mT) {
  int idx = blockIdx.x*256 + threadIdx.x;   // 9*64*256
  int lh = idx >> 14;
  int f  = (idx >> 8) & 63;
  int k  = idx & 255;
  W2mT[idx] = f2bf(mm_W2[(size_t)lh*(HID_*F_) + k*F_ + f]);
}

// WcryT[n][k] (bf16, n-major, 1536 x 64)
__global__ __launch_bounds__(256) void prep_wcry(
    const float* __restrict__ cg_W1, const float* __restrict__ cm_W1,
    unsigned short* __restrict__ WcryT) {
  int idx = blockIdx.x*256 + threadIdx.x;   // 1536*64
  int n = idx >> 6, k = idx & 63;
  int h = n >> 9, r = n & 511;
  float v = (r < 256) ? cg_W1[(size_t)h*F_*HID_ + k*HID_ + r]
                      : cm_W1[(size_t)h*F_*HID_ + k*HID_ + (r - 256)];
  WcryT[idx] = f2bf(v);
}

// W2cT[h][f][k] = bf16(cm_W2[h][k][f])
__global__ __launch_bounds__(256) void prep_w2c(
    const float* __restrict__ cm_W2, unsigned short* __restrict__ W2cT) {
  int idx = blockIdx.x*256 + threadIdx.x;   // 3*64*256
  int h = idx >> 14;
  int f = (idx >> 8) & 63;
  int k = idx & 255;
  W2cT[idx] = f2bf(cm_W2[(size_t)h*HID_*F_ + k*F_ + f]);
}

__global__ __launch_bounds__(256) void conv_bf16(
    const float* __restrict__ in, unsigned short* __restrict__ out, int n) {
  int i = blockIdx.x*256 + threadIdx.x;
  if (i < n) out[i] = f2bf(in[i]);
}

// feaBF = bf16(cur) ; fea_nxt = cur  (residual base for atomic head accumulation)
__global__ __launch_bounds__(256) void conv_copy(
    const float* __restrict__ in, unsigned short* __restrict__ outbf,
    float* __restrict__ outf, int n) {
  int i = blockIdx.x*256 + threadIdx.x;
  if (i < n) { float v = in[i]; outbf[i] = f2bf(v); outf[i] = v; }
}

// C[4096][NSTR] = A[4096][64] @ BT^T ; BT is [n][k] bf16, MFMA f32 accum
__global__ __launch_bounds__(256) void gemm_pq(
    const unsigned short* __restrict__ A,   // [4096][64] bf16
    const unsigned short* __restrict__ BT,  // [Ntot][64] bf16 (n-major)
    float* __restrict__ C, int NSTR) {
  __shared__ __align__(16) unsigned short As[64][72];
  __shared__ __align__(16) unsigned short Bs[128][72];
  int t = threadIdx.x;
  int m0 = blockIdx.x * 64;
  int n0 = blockIdx.y * 128;
  {
    int row = t >> 2, ch = (t & 3) * 16;
    const uint4* src = (const uint4*)(A + (size_t)(m0 + row)*64 + ch);
    *(uint4*)&As[row][ch]     = src[0];
    *(uint4*)&As[row][ch + 8] = src[1];
    int row2 = t >> 1, ch2 = (t & 1) * 32;
    const uint4* s2 = (const uint4*)(BT + (size_t)(n0 + row2)*64 + ch2);
    uint4* d2 = (uint4*)&Bs[row2][ch2];
    d2[0] = s2[0]; d2[1] = s2[1]; d2[2] = s2[2]; d2[3] = s2[3];
  }
  __syncthreads();
  int w = t >> 6, lane = t & 63;
  int mr = lane & 15, q = lane >> 4;
  short8 a0 = *(const short8*)&As[w*16 + mr][q*8];
  short8 a1 = *(const short8*)&As[w*16 + mr][32 + q*8];
  #pragma unroll
  for (int nt = 0; nt < 8; ++nt) {
    short8 b0 = *(const short8*)&Bs[nt*16 + mr][q*8];
    short8 b1 = *(const short8*)&Bs[nt*16 + mr][32 + q*8];
    f32x4 z = {0.f, 0.f, 0.f, 0.f};
    z = __builtin_amdgcn_mfma_f32_16x16x32_bf16(a0, b0, z, 0, 0, 0);
    z = __builtin_amdgcn_mfma_f32_16x16x32_bf16(a1, b1, z, 0, 0, 0);
    #pragma unroll
    for (int r = 0; r < 4; ++r)
      C[(size_t)(m0 + w*16 + q*4 + r)*NSTR + n0 + nt*16 + mr] = z[r];
  }
}

// Per-(graph,head) edge gate + softmax-attn. grid (G_, 3).
// PQ[node][h*1024 + c]: c<256 P_g; 256..511 Q_g; 512..767 P_m; 768..1023 Q_m
__global__ __launch_bounds__(256) void gate_attn(
    const float* __restrict__ PQ, const float* __restrict__ mg_b1,
    const float* __restrict__ mg_W2, const float* __restrict__ mg_b2,
    const float* __restrict__ m_pow, const float* __restrict__ wts,
    float* __restrict__ attn_out, int l) {
  __shared__ float PQg[16][516];
  __shared__ float bw[512];       // [0:256) b1, [256:512) W2
  __shared__ float gateL[240];
  int t = threadIdx.x;
  int g = blockIdx.x, g16 = g * 16;
  int h = blockIdx.y, lh = l*H_ + h;
  #pragma unroll
  for (int s = 0; s < 8; ++s) {
    int u = s*256 + t;
    int row = u >> 7, c4 = (u & 127) * 4;
    *(float4*)&PQg[row][c4] =
        *(const float4*)(PQ + (size_t)(g16 + row)*3072 + h*1024 + c4);
  }
  bw[t]       = mg_b1[lh*HID_ + t];    // 256 threads: both halves explicitly
  bw[256 + t] = mg_W2[lh*HID_ + t];
  __syncthreads();
  if (t < 240) {
    int i = t / 15, jj = t - i*15;
    int j = (jj < i) ? jj : jj + 1;
    float s = 0.f;
    #pragma unroll 4
    for (int c = 0; c < 256; ++c) {
      float hv = selu_f(PQg[i][c] + PQg[j][256 + c] + bw[c]);
      s = fmaf(hv, bw[256 + c], s);
    }
    gateL[t] = s + mg_b2[lh];
  }
  __syncthreads();
  if (t < 16) {
    int i = t;
    float pw = m_pow[lh];
    float m = -1e30f;
    #pragma unroll
    for (int jj = 0; jj < 15; ++jj) m = fmaxf(m, gateL[i*15 + jj]);
    float v[15]; float den = 0.f;
    #pragma unroll
    for (int jj = 0; jj < 15; ++jj) {
      int j = (jj < i) ? jj : jj + 1;
      float w = wts[g16 + j];
      float x = __powf(w, pw) * __expf(gateL[i*15 + jj] - m);
      v[jj] = x; den += x;
    }
    den += 1e-10f;
    #pragma unroll
    for (int jj = 0; jj < 15; ++jj)
      attn_out[((size_t)h*G_ + g)*240 + i*15 + jj] = v[jj] / den;
  }
}

// Per-(graph,head) msg path, barrier-free K-loop: A fragments computed from
// global PQ (selu on the fly), B fragments straight from W2T. grid (G_, 3).
// fea_nxt pre-initialized to fea_cur; heads atomicAdd their (1/3)-contribution.
__global__ __launch_bounds__(256) void msg_accum(
    const float* __restrict__ PQ, const unsigned short* __restrict__ W2T,
    const float* __restrict__ mm_b1, const float* __restrict__ mm_b2,
    const float* __restrict__ attnb, float* __restrict__ fea_nxt, int l) {
  __shared__ float attnL[240];
  __shared__ float b1s[256];
  __shared__ float accum[16][64];
  __shared__ float sumat[16];
  int t = threadIdx.x;
  int g = blockIdx.x, g16 = g * 16;
  int h = blockIdx.y, lh = l*H_ + h;
  const float* Pbase = PQ + (size_t)g16*3072 + h*1024 + 512;
  const float* Qbase = PQ + (size_t)g16*3072 + h*1024 + 768;
  if (t < 240) attnL[t] = attnb[((size_t)h*G_ + g)*240 + t];
  b1s[t] = mm_b1[lh*HID_ + t];
  #pragma unroll
  for (int s = 0; s < 4; ++s) ((float*)accum)[s*256 + t] = 0.f;
  __syncthreads();
  if (t < 16) {
    float s = 0.f;
    #pragma unroll
    for (int jj = 0; jj < 15; ++jj) s += attnL[t*15 + jj];
    sumat[t] = s;
  }
  int w = t >> 6, lane = t & 63, mr = lane & 15, q = lane >> 4;
  int nmt = (w < 3) ? 4 : 3;   // 15 m-tiles of 16 edges over 4 waves
  f32x4 acc[4][4];
  #pragma unroll
  for (int mi = 0; mi < 4; ++mi)
    #pragma unroll
    for (int nt = 0; nt < 4; ++nt) { f32x4 z = {0.f,0.f,0.f,0.f}; acc[mi][nt] = z; }

  // precompute per-lane edge/node indices for each mi
  int iL[4], jL[4];
  #pragma unroll
  for (int mi = 0; mi < 4; ++mi) {
    int e = (w + mi*4)*16 + mr;
    int i = e / 15, jj = e - i*15;
    iL[mi] = i; jL[mi] = (jj < i) ? jj : jj + 1;
  }
  const unsigned short* W2lh = W2T + (size_t)lh*64*256;

  for (int kc = 0; kc < 8; ++kc) {
    int k0 = kc*32 + q*8;
    short8 bf[4];
    #pragma unroll
    for (int nt = 0; nt < 4; ++nt)
      bf[nt] = *(const short8*)&W2lh[(size_t)(nt*16 + mr)*256 + k0];
    for (int mi = 0; mi < nmt; ++mi) {
      const float* Pp = Pbase + (size_t)iL[mi]*3072 + k0;
      const float* Qp = Qbase + (size_t)jL[mi]*3072 + k0;
      float4 p0 = *(const float4*)Pp;
      float4 p1 = *(const float4*)(Pp + 4);
      float4 q0 = *(const float4*)Qp;
      float4 q1 = *(const float4*)(Qp + 4);
      short8 a;
      a[0] = (short)f2bf(selu_f(p0.x + q0.x + b1s[k0+0]));
      a[1] = (short)f2bf(selu_f(p0.y + q0.y + b1s[k0+1]));
      a[2] = (short)f2bf(selu_f(p0.z + q0.z + b1s[k0+2]));
      a[3] = (short)f2bf(selu_f(p0.w + q0.w + b1s[k0+3]));
      a[4] = (short)f2bf(selu_f(p1.x + q1.x + b1s[k0+4]));
      a[5] = (short)f2bf(selu_f(p1.y + q1.y + b1s[k0+5]));
      a[6] = (short)f2bf(selu_f(p1.z + q1.z + b1s[k0+6]));
      a[7] = (short)f2bf(selu_f(p1.w + q1.w + b1s[k0+7]));
      #pragma unroll
      for (int nt = 0; nt < 4; ++nt)
        acc[mi][nt] = __builtin_amdgcn_mfma_f32_16x16x32_bf16(a, bf[nt], acc[mi][nt], 0, 0, 0);
    }
  }
  // attn-weighted accumulate into per-node LDS accum (C row = q*4+r, col = nt*16+mr)
  for (int mi = 0; mi < nmt; ++mi) {
    int ebase = (w + mi*4)*16 + q*4;
    #pragma unroll
    for (int nt = 0; nt < 4; ++nt) {
      int f = nt*16 + mr;
      int icur = ebase / 15; float vsum = 0.f;
      #pragma unroll
      for (int r = 0; r < 4; ++r) {
        int e = ebase + r;
        int ie = e / 15;
        float v = acc[mi][nt][r] * attnL[e];
        if (ie != icur) { atomicAdd(&accum[icur][f], vsum); vsum = 0.f; icur = ie; }
        vsum += v;
      }
      atomicAdd(&accum[icur][f], vsum);
    }
  }
  __syncthreads();
  #pragma unroll
  for (int s = 0; s < 4; ++s) {
    int u = s*256 + t;
    int i = u >> 6, f = u & 63;
    float val = (accum[i][f] + mm_b2[lh*F_ + f]*sumat[i]) * (1.f/3.f);
    atomicAdd(&fea_nxt[(size_t)(g16 + i)*64 + f], val);
  }
}

// Crystal phase, fully fused: per graph, all 3 heads
__global__ __launch_bounds__(256) void cry_fused(
    const float* __restrict__ PQc,          // [4096][1536]
    const unsigned short* __restrict__ W2cT,// [3][64][256] bf16
    const float* __restrict__ cg_b1, const float* __restrict__ cg_W2,
    const float* __restrict__ cg_b2, const float* __restrict__ cm_b1,
    const float* __restrict__ cm_b2, const float* __restrict__ c_pow,
    const float* __restrict__ wts, float* __restrict__ out) {
  __shared__ float PQh[16][520];
  __shared__ float gred[16][18];
  __shared__ float attnL[16];
  __shared__ float sumatS;
  __shared__ __align__(16) unsigned short hidc[16][264];
  __shared__ float outg[64];
  int t = threadIdx.x;
  int g = blockIdx.x, g16 = g*16;
  if (t < 64) outg[t] = 0.f;
  for (int h = 0; h < H_; ++h) {
    __syncthreads();
    #pragma unroll
    for (int s = 0; s < 8; ++s) {
      int u = s*256 + t;
      int row = u >> 7, c4 = (u & 127)*4;
      *(float4*)&PQh[row][c4] = *(const float4*)(PQc + (size_t)(g16+row)*1536 + h*512 + c4);
    }
    __syncthreads();
    {
      int i = t >> 4, c0 = (t & 15) * 16;
      float s = 0.f;
      #pragma unroll
      for (int c = c0; c < c0+16; ++c)
        s = fmaf(selu_f(PQh[i][c] + cg_b1[h*HID_ + c]), cg_W2[h*HID_ + c], s);
      gred[i][t & 15] = s;
    }
    __syncthreads();
    if (t < 16) {
      float sg = 0.f;
      #pragma unroll
      for (int u2 = 0; u2 < 16; ++u2) sg += gred[t][u2];
      gred[t][16] = sg + cg_b2[h];
    }
    __syncthreads();
    if (t == 0) {
      float pw = c_pow[h];
      float m = -1e30f;
      #pragma unroll
      for (int i = 0; i < 16; ++i) m = fmaxf(m, gred[i][16]);
      float den = 0.f; float v[16];
      #pragma unroll
      for (int i = 0; i < 16; ++i) {
        float x = __powf(wts[g16+i], pw) * __expf(gred[i][16] - m);
        v[i] = x; den += x;
      }
      den += 1e-10f;
      float sa = 0.f;
      #pragma unroll
      for (int i = 0; i < 16; ++i) { float a = v[i]/den; attnL[i] = a; sa += a; }
      sumatS = sa;
    }
    {
      int i = t >> 4, c0 = (t & 15) * 16;
      #pragma unroll
      for (int c = c0; c < c0+16; ++c)
        hidc[i][c] = f2bf(selu_f(PQh[i][256 + c] + cm_b1[h*HID_ + c]));
    }
    __syncthreads();
    int w = t >> 6, lane = t & 63, mr = lane & 15, q = lane >> 4;
    f32x4 acc = {0.f, 0.f, 0.f, 0.f};
    #pragma unroll
    for (int kc = 0; kc < 8; ++kc) {
      short8 a = *(const short8*)&hidc[mr][kc*32 + q*8];
      short8 b = *(const short8*)&W2cT[((size_t)h*64 + w*16 + mr)*HID_ + kc*32 + q*8];
      acc = __builtin_amdgcn_mfma_f32_16x16x32_bf16(a, b, acc, 0, 0, 0);
    }
    float p = 0.f;
    #pragma unroll
    for (int r = 0; r < 4; ++r) p = fmaf(attnL[q*4+r], acc[r], p);
    atomicAdd(&outg[w*16+mr], p);
    if (q == 0) atomicAdd(&outg[w*16+mr], cm_b2[h*F_ + w*16 + mr]*sumatS);
  }
  __syncthreads();
  if (t < 64) out[(size_t)g*64 + t] = outg[t] * (1.f/(float)H_);
}

extern "C" void kernel_launch(void* const* d_in, const int* in_sizes, int n_in,
                              void* d_out, int out_size, void* d_ws, size_t ws_size,
                              hipStream_t stream) {
  const float* elem_weights = (const float*)d_in[0];
  const float* elem_fea_in  = (const float*)d_in[1];
  const float* W_init = (const float*)d_in[2];
  const float* b_init = (const float*)d_in[3];
  const float* mg_W1  = (const float*)d_in[4];
  const float* mg_b1  = (const float*)d_in[5];
  const float* mg_W2  = (const float*)d_in[6];
  const float* mg_b2  = (const float*)d_in[7];
  const float* mm_W1  = (const float*)d_in[8];
  const float* mm_b1  = (const float*)d_in[9];
  const float* mm_W2  = (const float*)d_in[10];
  const float* mm_b2  = (const float*)d_in[11];
  const float* m_pow  = (const float*)d_in[12];
  const float* cg_W1  = (const float*)d_in[13];
  const float* cg_b1  = (const float*)d_in[14];
  const float* cg_W2  = (const float*)d_in[15];
  const float* cg_b2  = (const float*)d_in[16];
  const float* cm_W1  = (const float*)d_in[17];
  const float* cm_b1  = (const float*)d_in[18];
  const float* cm_W2  = (const float*)d_in[19];
  const float* cm_b2  = (const float*)d_in[20];
  const float* c_pow  = (const float*)d_in[21];

  // workspace (~56 MB): PQ union region [4096*3072 f32] (edge layers) /
  // PQc [4096*1536] (crystal), then small buffers.
  float* ws    = (float*)d_ws;
  float* PQ    = ws;
  float* PQc   = ws;
  float* feaA  = ws   + (size_t)4096*3072;
  float* feaB  = feaA + (size_t)N_*F_;
  float* attnb = feaB + (size_t)N_*F_;                     // 3*G*240
  unsigned short* feaBF = (unsigned short*)(attnb + 3*G_*240);
  unsigned short* WcatT = feaBF + (size_t)N_*F_;           // 9*1024*64
  unsigned short* W2mT  = WcatT + (size_t)9*1024*64;       // 9*64*256
  unsigned short* WcryT = W2mT  + (size_t)9*64*256;        // 1536*64
  unsigned short* W2cT  = WcryT + (size_t)1536*64;         // 3*64*256

  prep_wcat<<<(9*1024*64)/256, 256, 0, stream>>>(mg_W1, mm_W1, WcatT);
  prep_w2mt<<<(9*64*256)/256, 256, 0, stream>>>(mm_W2, W2mT);
  prep_wcry<<<(1536*64)/256, 256, 0, stream>>>(cg_W1, cm_W1, WcryT);
  prep_w2c<<<(3*64*256)/256, 256, 0, stream>>>(cm_W2, W2cT);
  init_embed<<<N_, 64, 0, stream>>>(elem_fea_in, W_init, b_init, elem_weights, feaA);

  float* cur = feaA; float* nxt = feaB;
  for (int l = 0; l < L_; ++l) {
    conv_copy<<<(N_*F_)/256, 256, 0, stream>>>(cur, feaBF, nxt, N_*F_);
    gemm_pq<<<dim3(64, 24), 256, 0, stream>>>(
        feaBF, WcatT + (size_t)(3*l)*1024*64, PQ, 3072);
    gate_attn<<<dim3(G_, H_), 256, 0, stream>>>(
        PQ, mg_b1, mg_W2, mg_b2, m_pow, elem_weights, attnb, l);
    msg_accum<<<dim3(G_, H_), 256, 0, stream>>>(
        PQ, W2mT, mm_b1, mm_b2, attnb, nxt, l);
    float* t = cur; cur = nxt; nxt = t;
  }

  // crystal phase
  conv_bf16<<<(N_*F_)/256, 256, 0, stream>>>(cur, feaBF, N_*F_);
  gemm_pq<<<dim3(64, 12), 256, 0, stream>>>(feaBF, WcryT, PQc, 1536);
  cry_fused<<<G_, 256, 0, stream>>>(
      PQc, W2cT, cg_b1, cg_W2, cg_b2, cm_b1, cm_b2, c_pow,
      elem_weights, (float*)d_out);
}

// Round 8
// 482.639 us; speedup vs baseline: 5.7835x; 1.4287x over previous
//
#include <hip/hip_runtime.h>
#include <hip/hip_bf16.h>

#define G_ 256
#define K_ 16
#define L_ 3
#define H_ 3
#define F_ 64
#define EMB_ 200
#define HID_ 256
#define N_ (G_*K_)          // 4096 nodes
#define E_ (G_*K_*(K_-1))   // 61440 edges

typedef __attribute__((ext_vector_type(8))) short short8;
typedef __attribute__((ext_vector_type(4))) float f32x4;

__device__ __forceinline__ float selu_f(float x) {
  const float scale = 1.0507009873554804934193349852946f;
  const float alpha = 1.6732632423543772848170429916717f;
  float e = __expf(x) - 1.0f;          // fast expm1 (v_exp_f32)
  return x > 0.f ? scale * x : scale * alpha * e;
}

__device__ __forceinline__ unsigned short f2bf(float x) {
  __hip_bfloat16 h = __float2bfloat16(x);
  return *reinterpret_cast<unsigned short*>(&h);
}

// fea[n, 0:63] = elem_fea_in[n,:] @ W_init + b_init ; fea[n,63] = w[n]
__global__ __launch_bounds__(64) void init_embed(
    const float* __restrict__ fea_in, const float* __restrict__ W,
    const float* __restrict__ b, const float* __restrict__ wts,
    float* __restrict__ fea) {
  __shared__ float row[EMB_];
  int n = blockIdx.x;
  int j = threadIdx.x;
  for (int k = j; k < EMB_; k += 64) row[k] = fea_in[(size_t)n*EMB_ + k];
  __syncthreads();
  if (j < F_-1) {
    float s = b[j];
    for (int k = 0; k < EMB_; ++k) s = fmaf(row[k], W[k*(F_-1) + j], s);
    fea[(size_t)n*F_ + j] = s;
  } else {
    fea[(size_t)n*F_ + (F_-1)] = wts[n];
  }
}

// WcatT[lh][n][k] (bf16, n-major): n<256 -> mgW1[k][n]; 256..511 -> mgW1[64+k][n-256]
//                                 ; 512..767 -> mmW1[k][n-512]; else mmW1[64+k][n-768]
__global__ __launch_bounds__(256) void prep_wcat(
    const float* __restrict__ mg_W1, const float* __restrict__ mm_W1,
    unsigned short* __restrict__ WcatT) {
  int idx = blockIdx.x*256 + threadIdx.x;   // 9*1024*64
  int lh = idx >> 16;
  int n  = (idx >> 6) & 1023;
  int k  = idx & 63;
  const float* W = (n < 512) ? mg_W1 : mm_W1;
  int nn = n & 511;
  int r  = (nn < 256) ? k : (64 + k);
  int c  = nn & 255;
  WcatT[idx] = f2bf(W[(size_t)lh*(2*F_*HID_) + r*HID_ + c]);
}

// W2mT[lh][f][k] = bf16(mm_W2[lh][k][f])
__global__ __launch_bounds__(256) void prep_w2mt(
    const float* __restrict__ mm_W2, unsigned short* __restrict__ W2mT) {
  int idx = blockIdx.x*256 + threadIdx.x;   // 9*64*256
  int lh = idx >> 14;
  int f  = (idx >> 8) & 63;
  int k  = idx & 255;
  W2mT[idx] = f2bf(mm_W2[(size_t)lh*(HID_*F_) + k*F_ + f]);
}

// WcryT[n][k] (bf16, n-major, 1536 x 64)
__global__ __launch_bounds__(256) void prep_wcry(
    const float* __restrict__ cg_W1, const float* __restrict__ cm_W1,
    unsigned short* __restrict__ WcryT) {
  int idx = blockIdx.x*256 + threadIdx.x;   // 1536*64
  int n = idx >> 6, k = idx & 63;
  int h = n >> 9, r = n & 511;
  float v = (r < 256) ? cg_W1[(size_t)h*F_*HID_ + k*HID_ + r]
                      : cm_W1[(size_t)h*F_*HID_ + k*HID_ + (r - 256)];
  WcryT[idx] = f2bf(v);
}

// W2cT[h][f][k] = bf16(cm_W2[h][k][f])
__global__ __launch_bounds__(256) void prep_w2c(
    const float* __restrict__ cm_W2, unsigned short* __restrict__ W2cT) {
  int idx = blockIdx.x*256 + threadIdx.x;   // 3*64*256
  int h = idx >> 14;
  int f = (idx >> 8) & 63;
  int k = idx & 255;
  W2cT[idx] = f2bf(cm_W2[(size_t)h*HID_*F_ + k*F_ + f]);
}

__global__ __launch_bounds__(256) void conv_bf16(
    const float* __restrict__ in, unsigned short* __restrict__ out, int n) {
  int i = blockIdx.x*256 + threadIdx.x;
  if (i < n) out[i] = f2bf(in[i]);
}

// feaBF = bf16(cur) ; fea_nxt = cur  (residual base for atomic head accumulation)
__global__ __launch_bounds__(256) void conv_copy(
    const float* __restrict__ in, unsigned short* __restrict__ outbf,
    float* __restrict__ outf, int n) {
  int i = blockIdx.x*256 + threadIdx.x;
  if (i < n) { float v = in[i]; outbf[i] = f2bf(v); outf[i] = v; }
}

// C[4096][NSTR] = A[4096][64] @ BT^T ; BT is [n][k] bf16, MFMA f32 accum
__global__ __launch_bounds__(256) void gemm_pq(
    const unsigned short* __restrict__ A,   // [4096][64] bf16
    const unsigned short* __restrict__ BT,  // [Ntot][64] bf16 (n-major)
    float* __restrict__ C, int NSTR) {
  __shared__ __align__(16) unsigned short As[64][72];
  __shared__ __align__(16) unsigned short Bs[128][72];
  int t = threadIdx.x;
  int m0 = blockIdx.x * 64;
  int n0 = blockIdx.y * 128;
  {
    int row = t >> 2, ch = (t & 3) * 16;
    const uint4* src = (const uint4*)(A + (size_t)(m0 + row)*64 + ch);
    *(uint4*)&As[row][ch]     = src[0];
    *(uint4*)&As[row][ch + 8] = src[1];
    int row2 = t >> 1, ch2 = (t & 1) * 32;
    const uint4* s2 = (const uint4*)(BT + (size_t)(n0 + row2)*64 + ch2);
    uint4* d2 = (uint4*)&Bs[row2][ch2];
    d2[0] = s2[0]; d2[1] = s2[1]; d2[2] = s2[2]; d2[3] = s2[3];
  }
  __syncthreads();
  int w = t >> 6, lane = t & 63;
  int mr = lane & 15, q = lane >> 4;
  short8 a0 = *(const short8*)&As[w*16 + mr][q*8];
  short8 a1 = *(const short8*)&As[w*16 + mr][32 + q*8];
  #pragma unroll
  for (int nt = 0; nt < 8; ++nt) {
    short8 b0 = *(const short8*)&Bs[nt*16 + mr][q*8];
    short8 b1 = *(const short8*)&Bs[nt*16 + mr][32 + q*8];
    f32x4 z = {0.f, 0.f, 0.f, 0.f};
    z = __builtin_amdgcn_mfma_f32_16x16x32_bf16(a0, b0, z, 0, 0, 0);
    z = __builtin_amdgcn_mfma_f32_16x16x32_bf16(a1, b1, z, 0, 0, 0);
    #pragma unroll
    for (int r = 0; r < 4; ++r)
      C[(size_t)(m0 + w*16 + q*4 + r)*NSTR + n0 + nt*16 + mr] = z[r];
  }
}

// Per-(graph,head) edge gate + softmax-attn. grid (G_, 3).
// PQ[node][h*1024 + c]: c<256 P_g; 256..511 Q_g; 512..767 P_m; 768..1023 Q_m
__global__ __launch_bounds__(256) void gate_attn(
    const float* __restrict__ PQ, const float* __restrict__ mg_b1,
    const float* __restrict__ mg_W2, const float* __restrict__ mg_b2,
    const float* __restrict__ m_pow, const float* __restrict__ wts,
    float* __restrict__ attn_out, int l) {
  __shared__ float PQg[16][516];
  __shared__ float bw[512];       // [0:256) b1, [256:512) W2
  __shared__ float gateL[240];
  int t = threadIdx.x;
  int g = blockIdx.x, g16 = g * 16;
  int h = blockIdx.y, lh = l*H_ + h;
  #pragma unroll
  for (int s = 0; s < 8; ++s) {
    int u = s*256 + t;
    int row = u >> 7, c4 = (u & 127) * 4;
    *(float4*)&PQg[row][c4] =
        *(const float4*)(PQ + (size_t)(g16 + row)*3072 + h*1024 + c4);
  }
  bw[t]       = mg_b1[lh*HID_ + t];    // 256 threads: both halves explicitly
  bw[256 + t] = mg_W2[lh*HID_ + t];
  __syncthreads();
  if (t < 240) {
    int i = t / 15, jj = t - i*15;
    int j = (jj < i) ? jj : jj + 1;
    float s = 0.f;
    #pragma unroll 4
    for (int c = 0; c < 256; ++c) {
      float hv = selu_f(PQg[i][c] + PQg[j][256 + c] + bw[c]);
      s = fmaf(hv, bw[256 + c], s);
    }
    gateL[t] = s + mg_b2[lh];
  }
  __syncthreads();
  if (t < 16) {
    int i = t;
    float pw = m_pow[lh];
    float m = -1e30f;
    #pragma unroll
    for (int jj = 0; jj < 15; ++jj) m = fmaxf(m, gateL[i*15 + jj]);
    float v[15]; float den = 0.f;
    #pragma unroll
    for (int jj = 0; jj < 15; ++jj) {
      int j = (jj < i) ? jj : jj + 1;
      float w = wts[g16 + j];
      float x = __powf(w, pw) * __expf(gateL[i*15 + jj] - m);
      v[jj] = x; den += x;
    }
    den += 1e-10f;
    #pragma unroll
    for (int jj = 0; jj < 15; ++jj)
      attn_out[((size_t)h*G_ + g)*240 + i*15 + jj] = v[jj] / den;
  }
}

// Per-(graph,head) msg path, barrier-free K-loop. grid (G_, 3).
// mi-loop is compile-time unrolled with wave-uniform guard so acc[][] stays
// statically indexed -> registers (dynamic nmt loop caused scratch spill, R7).
__global__ __launch_bounds__(256) void msg_accum(
    const float* __restrict__ PQ, const unsigned short* __restrict__ W2T,
    const float* __restrict__ mm_b1, const float* __restrict__ mm_b2,
    const float* __restrict__ attnb, float* __restrict__ fea_nxt, int l) {
  __shared__ float attnL[240];
  __shared__ float b1s[256];
  __shared__ float accum[16][64];
  __shared__ float sumat[16];
  int t = threadIdx.x;
  int g = blockIdx.x, g16 = g * 16;
  int h = blockIdx.y, lh = l*H_ + h;
  const float* Pbase = PQ + (size_t)g16*3072 + h*1024 + 512;
  const float* Qbase = PQ + (size_t)g16*3072 + h*1024 + 768;
  if (t < 240) attnL[t] = attnb[((size_t)h*G_ + g)*240 + t];
  b1s[t] = mm_b1[lh*HID_ + t];
  #pragma unroll
  for (int s = 0; s < 4; ++s) ((float*)accum)[s*256 + t] = 0.f;
  __syncthreads();
  if (t < 16) {
    float s = 0.f;
    #pragma unroll
    for (int jj = 0; jj < 15; ++jj) s += attnL[t*15 + jj];
    sumat[t] = s;
  }
  int w = t >> 6, lane = t & 63, mr = lane & 15, q = lane >> 4;
  f32x4 acc[4][4];
  #pragma unroll
  for (int mi = 0; mi < 4; ++mi)
    #pragma unroll
    for (int nt = 0; nt < 4; ++nt) { f32x4 z = {0.f,0.f,0.f,0.f}; acc[mi][nt] = z; }

  // per-lane edge/node indices for each mi (mt = w + mi*4, 15 m-tiles total)
  int iL[4], jL[4];
  #pragma unroll
  for (int mi = 0; mi < 4; ++mi) {
    int mt = w + mi*4;
    int e = (mt < 15 ? mt : 0)*16 + mr;
    int i = e / 15, jj = e - i*15;
    iL[mi] = i; jL[mi] = (jj < i) ? jj : jj + 1;
  }
  const unsigned short* W2lh = W2T + (size_t)lh*64*256;

  for (int kc = 0; kc < 8; ++kc) {
    int k0 = kc*32 + q*8;
    short8 bf[4];
    #pragma unroll
    for (int nt = 0; nt < 4; ++nt)
      bf[nt] = *(const short8*)&W2lh[(size_t)(nt*16 + mr)*256 + k0];
    #pragma unroll
    for (int mi = 0; mi < 4; ++mi) {
      if (w + mi*4 < 15) {              // wave-uniform guard, compile-time mi
        const float* Pp = Pbase + (size_t)iL[mi]*3072 + k0;
        const float* Qp = Qbase + (size_t)jL[mi]*3072 + k0;
        float4 p0 = *(const float4*)Pp;
        float4 p1 = *(const float4*)(Pp + 4);
        float4 q0 = *(const float4*)Qp;
        float4 q1 = *(const float4*)(Qp + 4);
        short8 a;
        a[0] = (short)f2bf(selu_f(p0.x + q0.x + b1s[k0+0]));
        a[1] = (short)f2bf(selu_f(p0.y + q0.y + b1s[k0+1]));
        a[2] = (short)f2bf(selu_f(p0.z + q0.z + b1s[k0+2]));
        a[3] = (short)f2bf(selu_f(p0.w + q0.w + b1s[k0+3]));
        a[4] = (short)f2bf(selu_f(p1.x + q1.x + b1s[k0+4]));
        a[5] = (short)f2bf(selu_f(p1.y + q1.y + b1s[k0+5]));
        a[6] = (short)f2bf(selu_f(p1.z + q1.z + b1s[k0+6]));
        a[7] = (short)f2bf(selu_f(p1.w + q1.w + b1s[k0+7]));
        #pragma unroll
        for (int nt = 0; nt < 4; ++nt)
          acc[mi][nt] = __builtin_amdgcn_mfma_f32_16x16x32_bf16(a, bf[nt], acc[mi][nt], 0, 0, 0);
      }
    }
  }
  // attn-weighted accumulate into per-node LDS accum (C row = q*4+r, col = nt*16+mr)
  #pragma unroll
  for (int mi = 0; mi < 4; ++mi) {
    if (w + mi*4 < 15) {
      int ebase = (w + mi*4)*16 + q*4;
      #pragma unroll
      for (int nt = 0; nt < 4; ++nt) {
        int f = nt*16 + mr;
        int icur = ebase / 15; float vsum = 0.f;
        #pragma unroll
        for (int r = 0; r < 4; ++r) {
          int e = ebase + r;
          int ie = e / 15;
          float v = acc[mi][nt][r] * attnL[e];
          if (ie != icur) { atomicAdd(&accum[icur][f], vsum); vsum = 0.f; icur = ie; }
          vsum += v;
        }
        atomicAdd(&accum[icur][f], vsum);
      }
    }
  }
  __syncthreads();
  #pragma unroll
  for (int s = 0; s < 4; ++s) {
    int u = s*256 + t;
    int i = u >> 6, f = u & 63;
    float val = (accum[i][f] + mm_b2[lh*F_ + f]*sumat[i]) * (1.f/3.f);
    atomicAdd(&fea_nxt[(size_t)(g16 + i)*64 + f], val);
  }
}

// Crystal phase, fully fused: per graph, all 3 heads
__global__ __launch_bounds__(256) void cry_fused(
    const float* __restrict__ PQc,          // [4096][1536]
    const unsigned short* __restrict__ W2cT,// [3][64][256] bf16
    const float* __restrict__ cg_b1, const float* __restrict__ cg_W2,
    const float* __restrict__ cg_b2, const float* __restrict__ cm_b1,
    const float* __restrict__ cm_b2, const float* __restrict__ c_pow,
    const float* __restrict__ wts, float* __restrict__ out) {
  __shared__ float PQh[16][520];
  __shared__ float gred[16][18];
  __shared__ float attnL[16];
  __shared__ float sumatS;
  __shared__ __align__(16) unsigned short hidc[16][264];
  __shared__ float outg[64];
  int t = threadIdx.x;
  int g = blockIdx.x, g16 = g*16;
  if (t < 64) outg[t] = 0.f;
  for (int h = 0; h < H_; ++h) {
    __syncthreads();
    #pragma unroll
    for (int s = 0; s < 8; ++s) {
      int u = s*256 + t;
      int row = u >> 7, c4 = (u & 127)*4;
      *(float4*)&PQh[row][c4] = *(const float4*)(PQc + (size_t)(g16+row)*1536 + h*512 + c4);
    }
    __syncthreads();
    {
      int i = t >> 4, c0 = (t & 15) * 16;
      float s = 0.f;
      #pragma unroll
      for (int c = c0; c < c0+16; ++c)
        s = fmaf(selu_f(PQh[i][c] + cg_b1[h*HID_ + c]), cg_W2[h*HID_ + c], s);
      gred[i][t & 15] = s;
    }
    __syncthreads();
    if (t < 16) {
      float sg = 0.f;
      #pragma unroll
      for (int u2 = 0; u2 < 16; ++u2) sg += gred[t][u2];
      gred[t][16] = sg + cg_b2[h];
    }
    __syncthreads();
    if (t == 0) {
      float pw = c_pow[h];
      float m = -1e30f;
      #pragma unroll
      for (int i = 0; i < 16; ++i) m = fmaxf(m, gred[i][16]);
      float den = 0.f; float v[16];
      #pragma unroll
      for (int i = 0; i < 16; ++i) {
        float x = __powf(wts[g16+i], pw) * __expf(gred[i][16] - m);
        v[i] = x; den += x;
      }
      den += 1e-10f;
      float sa = 0.f;
      #pragma unroll
      for (int i = 0; i < 16; ++i) { float a = v[i]/den; attnL[i] = a; sa += a; }
      sumatS = sa;
    }
    {
      int i = t >> 4, c0 = (t & 15) * 16;
      #pragma unroll
      for (int c = c0; c < c0+16; ++c)
        hidc[i][c] = f2bf(selu_f(PQh[i][256 + c] + cm_b1[h*HID_ + c]));
    }
    __syncthreads();
    int w = t >> 6, lane = t & 63, mr = lane & 15, q = lane >> 4;
    f32x4 acc = {0.f, 0.f, 0.f, 0.f};
    #pragma unroll
    for (int kc = 0; kc < 8; ++kc) {
      short8 a = *(const short8*)&hidc[mr][kc*32 + q*8];
      short8 b = *(const short8*)&W2cT[((size_t)h*64 + w*16 + mr)*HID_ + kc*32 + q*8];
      acc = __builtin_amdgcn_mfma_f32_16x16x32_bf16(a, b, acc, 0, 0, 0);
    }
    float p = 0.f;
    #pragma unroll
    for (int r = 0; r < 4; ++r) p = fmaf(attnL[q*4+r], acc[r], p);
    atomicAdd(&outg[w*16+mr], p);
    if (q == 0) atomicAdd(&outg[w*16+mr], cm_b2[h*F_ + w*16 + mr]*sumatS);
  }
  __syncthreads();
  if (t < 64) out[(size_t)g*64 + t] = outg[t] * (1.f/(float)H_);
}

extern "C" void kernel_launch(void* const* d_in, const int* in_sizes, int n_in,
                              void* d_out, int out_size, void* d_ws, size_t ws_size,
                              hipStream_t stream) {
  const float* elem_weights = (const float*)d_in[0];
  const float* elem_fea_in  = (const float*)d_in[1];
  const float* W_init = (const float*)d_in[2];
  const float* b_init = (const float*)d_in[3];
  const float* mg_W1  = (const float*)d_in[4];
  const float* mg_b1  = (const float*)d_in[5];
  const float* mg_W2  = (const float*)d_in[6];
  const float* mg_b2  = (const float*)d_in[7];
  const float* mm_W1  = (const float*)d_in[8];
  const float* mm_b1  = (const float*)d_in[9];
  const float* mm_W2  = (const float*)d_in[10];
  const float* mm_b2  = (const float*)d_in[11];
  const float* m_pow  = (const float*)d_in[12];
  const float* cg_W1  = (const float*)d_in[13];
  const float* cg_b1  = (const float*)d_in[14];
  const float* cg_W2  = (const float*)d_in[15];
  const float* cg_b2  = (const float*)d_in[16];
  const float* cm_W1  = (const float*)d_in[17];
  const float* cm_b1  = (const float*)d_in[18];
  const float* cm_W2  = (const float*)d_in[19];
  const float* cm_b2  = (const float*)d_in[20];
  const float* c_pow  = (const float*)d_in[21];

  // workspace (~56 MB): PQ union region [4096*3072 f32] (edge layers) /
  // PQc [4096*1536] (crystal), then small buffers.
  float* ws    = (float*)d_ws;
  float* PQ    = ws;
  float* PQc   = ws;
  float* feaA  = ws   + (size_t)4096*3072;
  float* feaB  = feaA + (size_t)N_*F_;
  float* attnb = feaB + (size_t)N_*F_;                     // 3*G*240
  unsigned short* feaBF = (unsigned short*)(attnb + 3*G_*240);
  unsigned short* WcatT = feaBF + (size_t)N_*F_;           // 9*1024*64
  unsigned short* W2mT  = WcatT + (size_t)9*1024*64;       // 9*64*256
  unsigned short* WcryT = W2mT  + (size_t)9*64*256;        // 1536*64
  unsigned short* W2cT  = WcryT + (size_t)1536*64;         // 3*64*256

  prep_wcat<<<(9*1024*64)/256, 256, 0, stream>>>(mg_W1, mm_W1, WcatT);
  prep_w2mt<<<(9*64*256)/256, 256, 0, stream>>>(mm_W2, W2mT);
  prep_wcry<<<(1536*64)/256, 256, 0, stream>>>(cg_W1, cm_W1, WcryT);
  prep_w2c<<<(3*64*256)/256, 256, 0, stream>>>(cm_W2, W2cT);
  init_embed<<<N_, 64, 0, stream>>>(elem_fea_in, W_init, b_init, elem_weights, feaA);

  float* cur = feaA; float* nxt = feaB;
  for (int l = 0; l < L_; ++l) {
    conv_copy<<<(N_*F_)/256, 256, 0, stream>>>(cur, feaBF, nxt, N_*F_);
    gemm_pq<<<dim3(64, 24), 256, 0, stream>>>(
        feaBF, WcatT + (size_t)(3*l)*1024*64, PQ, 3072);
    gate_attn<<<dim3(G_, H_), 256, 0, stream>>>(
        PQ, mg_b1, mg_W2, mg_b2, m_pow, elem_weights, attnb, l);
    msg_accum<<<dim3(G_, H_), 256, 0, stream>>>(
        PQ, W2mT, mm_b1, mm_b2, attnb, nxt, l);
    float* t = cur; cur = nxt; nxt = t;
  }

  // crystal phase
  conv_bf16<<<(N_*F_)/256, 256, 0, stream>>>(cur, feaBF, N_*F_);
  gemm_pq<<<dim3(64, 12), 256, 0, stream>>>(feaBF, WcryT, PQc, 1536);
  cry_fused<<<G_, 256, 0, stream>>>(
      PQc, W2cT, cg_b1, cg_W2, cg_b2, cm_b1, cm_b2, c_pow,
      elem_weights, (float*)d_out);
}

// Round 9
// 417.041 us; speedup vs baseline: 6.6932x; 1.1573x over previous
//
#include <hip/hip_runtime.h>
#include <hip/hip_bf16.h>

#define G_ 256
#define K_ 16
#define L_ 3
#define H_ 3
#define F_ 64
#define EMB_ 200
#define HID_ 256
#define N_ (G_*K_)          // 4096 nodes
#define E_ (G_*K_*(K_-1))   // 61440 edges

typedef __attribute__((ext_vector_type(8))) short short8;
typedef __attribute__((ext_vector_type(4))) float f32x4;

__device__ __forceinline__ float selu_f(float x) {
  const float scale = 1.0507009873554804934193349852946f;
  const float alpha = 1.6732632423543772848170429916717f;
  float e = __expf(x) - 1.0f;          // fast expm1 (v_exp_f32)
  return x > 0.f ? scale * x : scale * alpha * e;
}

__device__ __forceinline__ unsigned short f2bf(float x) {
  __hip_bfloat16 h = __float2bfloat16(x);
  return *reinterpret_cast<unsigned short*>(&h);
}

__device__ __forceinline__ float bf2f(unsigned short u) {
  union { unsigned int i; float f; } v;
  v.i = ((unsigned int)u) << 16;
  return v.f;
}

// fea[n, 0:63] = elem_fea_in[n,:] @ W_init + b_init ; fea[n,63] = w[n]
__global__ __launch_bounds__(64) void init_embed(
    const float* __restrict__ fea_in, const float* __restrict__ W,
    const float* __restrict__ b, const float* __restrict__ wts,
    float* __restrict__ fea) {
  __shared__ float row[EMB_];
  int n = blockIdx.x;
  int j = threadIdx.x;
  for (int k = j; k < EMB_; k += 64) row[k] = fea_in[(size_t)n*EMB_ + k];
  __syncthreads();
  if (j < F_-1) {
    float s = b[j];
    for (int k = 0; k < EMB_; ++k) s = fmaf(row[k], W[k*(F_-1) + j], s);
    fea[(size_t)n*F_ + j] = s;
  } else {
    fea[(size_t)n*F_ + (F_-1)] = wts[n];
  }
}

// WcatT[lh][n][k] (bf16, n-major): n<256 -> mgW1[k][n]; 256..511 -> mgW1[64+k][n-256]
//                                 ; 512..767 -> mmW1[k][n-512]; else mmW1[64+k][n-768]
__global__ __launch_bounds__(256) void prep_wcat(
    const float* __restrict__ mg_W1, const float* __restrict__ mm_W1,
    unsigned short* __restrict__ WcatT) {
  int idx = blockIdx.x*256 + threadIdx.x;   // 9*1024*64
  int lh = idx >> 16;
  int n  = (idx >> 6) & 1023;
  int k  = idx & 63;
  const float* W = (n < 512) ? mg_W1 : mm_W1;
  int nn = n & 511;
  int r  = (nn < 256) ? k : (64 + k);
  int c  = nn & 255;
  WcatT[idx] = f2bf(W[(size_t)lh*(2*F_*HID_) + r*HID_ + c]);
}

// W2mT[lh][f][k] = bf16(mm_W2[lh][k][f])
__global__ __launch_bounds__(256) void prep_w2mt(
    const float* __restrict__ mm_W2, unsigned short* __restrict__ W2mT) {
  int idx = blockIdx.x*256 + threadIdx.x;   // 9*64*256
  int lh = idx >> 14;
  int f  = (idx >> 8) & 63;
  int k  = idx & 255;
  W2mT[idx] = f2bf(mm_W2[(size_t)lh*(HID_*F_) + k*F_ + f]);
}

// WcryT[n][k] (bf16, n-major, 1536 x 64)
__global__ __launch_bounds__(256) void prep_wcry(
    const float* __restrict__ cg_W1, const float* __restrict__ cm_W1,
    unsigned short* __restrict__ WcryT) {
  int idx = blockIdx.x*256 + threadIdx.x;   // 1536*64
  int n = idx >> 6, k = idx & 63;
  int h = n >> 9, r = n & 511;
  float v = (r < 256) ? cg_W1[(size_t)h*F_*HID_ + k*HID_ + r]
                      : cm_W1[(size_t)h*F_*HID_ + k*HID_ + (r - 256)];
  WcryT[idx] = f2bf(v);
}

// W2cT[h][f][k] = bf16(cm_W2[h][k][f])
__global__ __launch_bounds__(256) void prep_w2c(
    const float* __restrict__ cm_W2, unsigned short* __restrict__ W2cT) {
  int idx = blockIdx.x*256 + threadIdx.x;   // 3*64*256
  int h = idx >> 14;
  int f = (idx >> 8) & 63;
  int k = idx & 255;
  W2cT[idx] = f2bf(cm_W2[(size_t)h*HID_*F_ + k*F_ + f]);
}

__global__ __launch_bounds__(256) void conv_bf16(
    const float* __restrict__ in, unsigned short* __restrict__ out, int n) {
  int i = blockIdx.x*256 + threadIdx.x;
  if (i < n) out[i] = f2bf(in[i]);
}

// feaBF = bf16(cur) ; fea_nxt = cur  (residual base for atomic head accumulation)
__global__ __launch_bounds__(256) void conv_copy(
    const float* __restrict__ in, unsigned short* __restrict__ outbf,
    float* __restrict__ outf, int n) {
  int i = blockIdx.x*256 + threadIdx.x;
  if (i < n) { float v = in[i]; outbf[i] = f2bf(v); outf[i] = v; }
}

// C[4096][NSTR] (bf16) = A[4096][64] @ BT^T ; BT is [n][k] bf16, MFMA f32 accum
__global__ __launch_bounds__(256) void gemm_pq(
    const unsigned short* __restrict__ A,   // [4096][64] bf16
    const unsigned short* __restrict__ BT,  // [Ntot][64] bf16 (n-major)
    unsigned short* __restrict__ C, int NSTR) {
  __shared__ __align__(16) unsigned short As[64][72];
  __shared__ __align__(16) unsigned short Bs[128][72];
  int t = threadIdx.x;
  int m0 = blockIdx.x * 64;
  int n0 = blockIdx.y * 128;
  {
    int row = t >> 2, ch = (t & 3) * 16;
    const uint4* src = (const uint4*)(A + (size_t)(m0 + row)*64 + ch);
    *(uint4*)&As[row][ch]     = src[0];
    *(uint4*)&As[row][ch + 8] = src[1];
    int row2 = t >> 1, ch2 = (t & 1) * 32;
    const uint4* s2 = (const uint4*)(BT + (size_t)(n0 + row2)*64 + ch2);
    uint4* d2 = (uint4*)&Bs[row2][ch2];
    d2[0] = s2[0]; d2[1] = s2[1]; d2[2] = s2[2]; d2[3] = s2[3];
  }
  __syncthreads();
  int w = t >> 6, lane = t & 63;
  int mr = lane & 15, q = lane >> 4;
  short8 a0 = *(const short8*)&As[w*16 + mr][q*8];
  short8 a1 = *(const short8*)&As[w*16 + mr][32 + q*8];
  #pragma unroll
  for (int nt = 0; nt < 8; ++nt) {
    short8 b0 = *(const short8*)&Bs[nt*16 + mr][q*8];
    short8 b1 = *(const short8*)&Bs[nt*16 + mr][32 + q*8];
    f32x4 z = {0.f, 0.f, 0.f, 0.f};
    z = __builtin_amdgcn_mfma_f32_16x16x32_bf16(a0, b0, z, 0, 0, 0);
    z = __builtin_amdgcn_mfma_f32_16x16x32_bf16(a1, b1, z, 0, 0, 0);
    #pragma unroll
    for (int r = 0; r < 4; ++r)
      C[(size_t)(m0 + w*16 + q*4 + r)*NSTR + n0 + nt*16 + mr] = f2bf(z[r]);
  }
}

// ---------------------------------------------------------------------------
// Fused per-(graph,head) edge phase: gate -> softmax attn -> msg MFMA -> accum.
// PQ (bf16) [node][h*1024 + {Pg:0..255, Qg:256..511, Pm:512..767, Qm:768..1023}]
// Stage PQg in LDS, gate+attn in-block, restage PQm, barrier-free MFMA K-loop
// reading LDS (latency ~10cyc vs ~300 global). grid (G_, H_).
// ---------------------------------------------------------------------------
__global__ __launch_bounds__(256) void edge_fused(
    const unsigned short* __restrict__ PQ, const unsigned short* __restrict__ W2T,
    const float* __restrict__ mg_b1, const float* __restrict__ mg_W2,
    const float* __restrict__ mg_b2, const float* __restrict__ m_pow,
    const float* __restrict__ mm_b1, const float* __restrict__ mm_b2,
    const float* __restrict__ wts, float* __restrict__ fea_nxt, int l) {
  __shared__ __align__(16) unsigned short PQs[16][520];  // pad 8 shorts: 16B-aligned rows, 4-bank skew
  __shared__ float bw[512];        // [0:256) b1, [256:512) W2gate
  __shared__ float gateA[240];     // gate logits -> attn (in place)
  __shared__ float accum[16][64];
  __shared__ float sumat[16];
  int t = threadIdx.x;
  int g = blockIdx.x, g16 = g * 16;
  int h = blockIdx.y, lh = l*H_ + h;

  // stage PQg (16 x 512 bf16)
  #pragma unroll
  for (int s = 0; s < 4; ++s) {
    int u = s*256 + t;                 // 1024 uint4 loads
    int row = u >> 6, c8 = (u & 63) * 8;
    *(uint4*)&PQs[row][c8] = *(const uint4*)(PQ + (size_t)(g16+row)*3072 + h*1024 + c8);
  }
  bw[t]       = mg_b1[lh*HID_ + t];
  bw[256 + t] = mg_W2[lh*HID_ + t];
  #pragma unroll
  for (int s = 0; s < 4; ++s) ((float*)accum)[s*256 + t] = 0.f;
  __syncthreads();

  // gate logits (240 edges)
  if (t < 240) {
    int i = t / 15, jj = t - i*15;
    int j = (jj < i) ? jj : jj + 1;
    float s = 0.f;
    #pragma unroll
    for (int c8 = 0; c8 < 256; c8 += 8) {
      short8 pv = *(const short8*)&PQs[i][c8];
      short8 qv = *(const short8*)&PQs[j][256 + c8];
      #pragma unroll
      for (int r = 0; r < 8; ++r) {
        float hv = selu_f(bf2f((unsigned short)pv[r]) + bf2f((unsigned short)qv[r]) + bw[c8+r]);
        s = fmaf(hv, bw[256 + c8 + r], s);
      }
    }
    gateA[t] = s + mg_b2[lh];
  }
  __syncthreads();

  // softmax attn (t<16) + restage PQm over PQs + reload b1(msg)
  if (t < 16) {
    int i = t;
    float pw = m_pow[lh];
    float m = -1e30f;
    #pragma unroll
    for (int jj = 0; jj < 15; ++jj) m = fmaxf(m, gateA[i*15 + jj]);
    float v[15]; float den = 0.f;
    #pragma unroll
    for (int jj = 0; jj < 15; ++jj) {
      int j = (jj < i) ? jj : jj + 1;
      float x = __powf(wts[g16 + j], pw) * __expf(gateA[i*15 + jj] - m);
      v[jj] = x; den += x;
    }
    den += 1e-10f;
    float sa = 0.f;
    #pragma unroll
    for (int jj = 0; jj < 15; ++jj) {
      float a = v[jj] / den; gateA[i*15 + jj] = a; sa += a;
    }
    sumat[i] = sa;
  }
  #pragma unroll
  for (int s = 0; s < 4; ++s) {
    int u = s*256 + t;
    int row = u >> 6, c8 = (u & 63) * 8;
    *(uint4*)&PQs[row][c8] = *(const uint4*)(PQ + (size_t)(g16+row)*3072 + h*1024 + 512 + c8);
  }
  bw[t] = mm_b1[lh*HID_ + t];
  __syncthreads();

  // msg MFMA, barrier-free K-loop from LDS
  int w = t >> 6, lane = t & 63, mr = lane & 15, q = lane >> 4;
  f32x4 acc[4][4];
  #pragma unroll
  for (int mi = 0; mi < 4; ++mi)
    #pragma unroll
    for (int nt = 0; nt < 4; ++nt) { f32x4 z = {0.f,0.f,0.f,0.f}; acc[mi][nt] = z; }
  int iL[4], jL[4];
  #pragma unroll
  for (int mi = 0; mi < 4; ++mi) {
    int mt = w + mi*4;
    int e = (mt < 15 ? mt : 0)*16 + mr;
    int i = e / 15, jj = e - i*15;
    iL[mi] = i; jL[mi] = (jj < i) ? jj : jj + 1;
  }
  const unsigned short* W2lh = W2T + (size_t)lh*64*256;

  for (int kc = 0; kc < 8; ++kc) {
    int k0 = kc*32 + q*8;
    short8 bfr[4];
    #pragma unroll
    for (int nt = 0; nt < 4; ++nt)
      bfr[nt] = *(const short8*)&W2lh[(size_t)(nt*16 + mr)*256 + k0];
    #pragma unroll
    for (int mi = 0; mi < 4; ++mi) {
      if (w + mi*4 < 15) {             // wave-uniform, compile-time mi
        short8 pv = *(const short8*)&PQs[iL[mi]][k0];
        short8 qv = *(const short8*)&PQs[jL[mi]][256 + k0];
        short8 a;
        #pragma unroll
        for (int r = 0; r < 8; ++r)
          a[r] = (short)f2bf(selu_f(
              bf2f((unsigned short)pv[r]) + bf2f((unsigned short)qv[r]) + bw[k0+r]));
        #pragma unroll
        for (int nt = 0; nt < 4; ++nt)
          acc[mi][nt] = __builtin_amdgcn_mfma_f32_16x16x32_bf16(a, bfr[nt], acc[mi][nt], 0, 0, 0);
      }
    }
  }
  // attn-weighted accumulate (C row = q*4+r, col = nt*16+mr)
  #pragma unroll
  for (int mi = 0; mi < 4; ++mi) {
    if (w + mi*4 < 15) {
      int ebase = (w + mi*4)*16 + q*4;
      #pragma unroll
      for (int nt = 0; nt < 4; ++nt) {
        int f = nt*16 + mr;
        int icur = ebase / 15; float vsum = 0.f;
        #pragma unroll
        for (int r = 0; r < 4; ++r) {
          int e = ebase + r;
          int ie = e / 15;
          float v = acc[mi][nt][r] * gateA[e];
          if (ie != icur) { atomicAdd(&accum[icur][f], vsum); vsum = 0.f; icur = ie; }
          vsum += v;
        }
        atomicAdd(&accum[icur][f], vsum);
      }
    }
  }
  __syncthreads();
  #pragma unroll
  for (int s = 0; s < 4; ++s) {
    int u = s*256 + t;
    int i = u >> 6, f = u & 63;
    float val = (accum[i][f] + mm_b2[lh*F_ + f]*sumat[i]) * (1.f/3.f);
    atomicAdd(&fea_nxt[(size_t)(g16 + i)*64 + f], val);
  }
}

// Crystal phase, fully fused: per graph, all 3 heads (PQc now bf16)
__global__ __launch_bounds__(256) void cry_fused(
    const unsigned short* __restrict__ PQc, // [4096][1536] bf16
    const unsigned short* __restrict__ W2cT,// [3][64][256] bf16
    const float* __restrict__ cg_b1, const float* __restrict__ cg_W2,
    const float* __restrict__ cg_b2, const float* __restrict__ cm_b1,
    const float* __restrict__ cm_b2, const float* __restrict__ c_pow,
    const float* __restrict__ wts, float* __restrict__ out) {
  __shared__ float PQh[16][520];
  __shared__ float gred[16][18];
  __shared__ float attnL[16];
  __shared__ float sumatS;
  __shared__ __align__(16) unsigned short hidc[16][264];
  __shared__ float outg[64];
  int t = threadIdx.x;
  int g = blockIdx.x, g16 = g*16;
  if (t < 64) outg[t] = 0.f;
  for (int h = 0; h < H_; ++h) {
    __syncthreads();
    #pragma unroll
    for (int s = 0; s < 4; ++s) {
      int u = s*256 + t;                 // 1024 loads of 8 bf16
      int row = u >> 6, c8 = (u & 63) * 8;
      short8 raw = *(const short8*)(PQc + (size_t)(g16+row)*1536 + h*512 + c8);
      #pragma unroll
      for (int r = 0; r < 8; ++r) PQh[row][c8+r] = bf2f((unsigned short)raw[r]);
    }
    __syncthreads();
    {
      int i = t >> 4, c0 = (t & 15) * 16;
      float s = 0.f;
      #pragma unroll
      for (int c = c0; c < c0+16; ++c)
        s = fmaf(selu_f(PQh[i][c] + cg_b1[h*HID_ + c]), cg_W2[h*HID_ + c], s);
      gred[i][t & 15] = s;
    }
    __syncthreads();
    if (t < 16) {
      float sg = 0.f;
      #pragma unroll
      for (int u2 = 0; u2 < 16; ++u2) sg += gred[t][u2];
      gred[t][16] = sg + cg_b2[h];
    }
    __syncthreads();
    if (t == 0) {
      float pw = c_pow[h];
      float m = -1e30f;
      #pragma unroll
      for (int i = 0; i < 16; ++i) m = fmaxf(m, gred[i][16]);
      float den = 0.f; float v[16];
      #pragma unroll
      for (int i = 0; i < 16; ++i) {
        float x = __powf(wts[g16+i], pw) * __expf(gred[i][16] - m);
        v[i] = x; den += x;
      }
      den += 1e-10f;
      float sa = 0.f;
      #pragma unroll
      for (int i = 0; i < 16; ++i) { float a = v[i]/den; attnL[i] = a; sa += a; }
      sumatS = sa;
    }
    {
      int i = t >> 4, c0 = (t & 15) * 16;
      #pragma unroll
      for (int c = c0; c < c0+16; ++c)
        hidc[i][c] = f2bf(selu_f(PQh[i][256 + c] + cm_b1[h*HID_ + c]));
    }
    __syncthreads();
    int w = t >> 6, lane = t & 63, mr = lane & 15, q = lane >> 4;
    f32x4 acc = {0.f, 0.f, 0.f, 0.f};
    #pragma unroll
    for (int kc = 0; kc < 8; ++kc) {
      short8 a = *(const short8*)&hidc[mr][kc*32 + q*8];
      short8 b = *(const short8*)&W2cT[((size_t)h*64 + w*16 + mr)*HID_ + kc*32 + q*8];
      acc = __builtin_amdgcn_mfma_f32_16x16x32_bf16(a, b, acc, 0, 0, 0);
    }
    float p = 0.f;
    #pragma unroll
    for (int r = 0; r < 4; ++r) p = fmaf(attnL[q*4+r], acc[r], p);
    atomicAdd(&outg[w*16+mr], p);
    if (q == 0) atomicAdd(&outg[w*16+mr], cm_b2[h*F_ + w*16 + mr]*sumatS);
  }
  __syncthreads();
  if (t < 64) out[(size_t)g*64 + t] = outg[t] * (1.f/(float)H_);
}

extern "C" void kernel_launch(void* const* d_in, const int* in_sizes, int n_in,
                              void* d_out, int out_size, void* d_ws, size_t ws_size,
                              hipStream_t stream) {
  const float* elem_weights = (const float*)d_in[0];
  const float* elem_fea_in  = (const float*)d_in[1];
  const float* W_init = (const float*)d_in[2];
  const float* b_init = (const float*)d_in[3];
  const float* mg_W1  = (const float*)d_in[4];
  const float* mg_b1  = (const float*)d_in[5];
  const float* mg_W2  = (const float*)d_in[6];
  const float* mg_b2  = (const float*)d_in[7];
  const float* mm_W1  = (const float*)d_in[8];
  const float* mm_b1  = (const float*)d_in[9];
  const float* mm_W2  = (const float*)d_in[10];
  const float* mm_b2  = (const float*)d_in[11];
  const float* m_pow  = (const float*)d_in[12];
  const float* cg_W1  = (const float*)d_in[13];
  const float* cg_b1  = (const float*)d_in[14];
  const float* cg_W2  = (const float*)d_in[15];
  const float* cg_b2  = (const float*)d_in[16];
  const float* cm_W1  = (const float*)d_in[17];
  const float* cm_b1  = (const float*)d_in[18];
  const float* cm_W2  = (const float*)d_in[19];
  const float* cm_b2  = (const float*)d_in[20];
  const float* c_pow  = (const float*)d_in[21];

  // workspace (~30 MB): PQ bf16 union region [4096*3072 ushort] (edge) /
  // PQc bf16 [4096*1536] (crystal), then small buffers.
  float* ws = (float*)d_ws;
  unsigned short* PQ  = (unsigned short*)ws;
  unsigned short* PQc = (unsigned short*)ws;
  float* feaA  = ws   + (size_t)4096*3072/2;     // after bf16 PQ region
  float* feaB  = feaA + (size_t)N_*F_;
  unsigned short* feaBF = (unsigned short*)(feaB + (size_t)N_*F_);
  unsigned short* WcatT = feaBF + (size_t)N_*F_;           // 9*1024*64
  unsigned short* W2mT  = WcatT + (size_t)9*1024*64;       // 9*64*256
  unsigned short* WcryT = W2mT  + (size_t)9*64*256;        // 1536*64
  unsigned short* W2cT  = WcryT + (size_t)1536*64;         // 3*64*256

  prep_wcat<<<(9*1024*64)/256, 256, 0, stream>>>(mg_W1, mm_W1, WcatT);
  prep_w2mt<<<(9*64*256)/256, 256, 0, stream>>>(mm_W2, W2mT);
  prep_wcry<<<(1536*64)/256, 256, 0, stream>>>(cg_W1, cm_W1, WcryT);
  prep_w2c<<<(3*64*256)/256, 256, 0, stream>>>(cm_W2, W2cT);
  init_embed<<<N_, 64, 0, stream>>>(elem_fea_in, W_init, b_init, elem_weights, feaA);

  float* cur = feaA; float* nxt = feaB;
  for (int l = 0; l < L_; ++l) {
    conv_copy<<<(N_*F_)/256, 256, 0, stream>>>(cur, feaBF, nxt, N_*F_);
    gemm_pq<<<dim3(64, 24), 256, 0, stream>>>(
        feaBF, WcatT + (size_t)(3*l)*1024*64, PQ, 3072);
    edge_fused<<<dim3(G_, H_), 256, 0, stream>>>(
        PQ, W2mT, mg_b1, mg_W2, mg_b2, m_pow, mm_b1, mm_b2,
        elem_weights, nxt, l);
    float* t = cur; cur = nxt; nxt = t;
  }

  // crystal phase
  conv_bf16<<<(N_*F_)/256, 256, 0, stream>>>(cur, feaBF, N_*F_);
  gemm_pq<<<dim3(64, 12), 256, 0, stream>>>(feaBF, WcryT, PQc, 1536);
  cry_fused<<<G_, 256, 0, stream>>>(
      PQc, W2cT, cg_b1, cg_W2, cg_b2, cm_b1, cm_b2, c_pow,
      elem_weights, (float*)d_out);
}

// Round 10
// 391.455 us; speedup vs baseline: 7.1307x; 1.0654x over previous
//
#include <hip/hip_runtime.h>
#include <hip/hip_bf16.h>

#define G_ 256
#define K_ 16
#define L_ 3
#define H_ 3
#define F_ 64
#define EMB_ 200
#define HID_ 256
#define N_ (G_*K_)          // 4096 nodes
#define E_ (G_*K_*(K_-1))   // 61440 edges

typedef __attribute__((ext_vector_type(8))) short short8;
typedef __attribute__((ext_vector_type(4))) float f32x4;

#define SELU_S 1.0507009873554804934193349852946f
#define SELU_SA (1.0507009873554804934193349852946f*1.6732632423543772848170429916717f)

// 5-op selu: exp, fma, mul, cmp, cndmask
__device__ __forceinline__ float selu_f(float x) {
  float e = __expf(x);
  float neg = fmaf(SELU_SA, e, -SELU_SA);
  float pos = SELU_S * x;
  return x > 0.f ? pos : neg;
}

__device__ __forceinline__ unsigned short f2bf(float x) {
  __hip_bfloat16 h = __float2bfloat16(x);
  return *reinterpret_cast<unsigned short*>(&h);
}

// packed 2xf32 -> 2xbf16 (v_cvt_pk_bf16_f32 on gfx950)
__device__ __forceinline__ unsigned int f2bf2(float a, float b) {
  float2 t; t.x = a; t.y = b;
  __hip_bfloat162 h = __float22bfloat162_rn(t);
  return *reinterpret_cast<unsigned int*>(&h);
}

__device__ __forceinline__ float bf2f(unsigned short u) {
  union { unsigned int i; float f; } v;
  v.i = ((unsigned int)u) << 16;
  return v.f;
}

// fea[n, 0:63] = elem_fea_in[n,:] @ W_init + b_init ; fea[n,63] = w[n]
__global__ __launch_bounds__(64) void init_embed(
    const float* __restrict__ fea_in, const float* __restrict__ W,
    const float* __restrict__ b, const float* __restrict__ wts,
    float* __restrict__ fea) {
  __shared__ float row[EMB_];
  int n = blockIdx.x;
  int j = threadIdx.x;
  for (int k = j; k < EMB_; k += 64) row[k] = fea_in[(size_t)n*EMB_ + k];
  __syncthreads();
  if (j < F_-1) {
    float s = b[j];
    for (int k = 0; k < EMB_; ++k) s = fmaf(row[k], W[k*(F_-1) + j], s);
    fea[(size_t)n*F_ + j] = s;
  } else {
    fea[(size_t)n*F_ + (F_-1)] = wts[n];
  }
}

// WcatT[lh][n][k] (bf16, n-major)
__global__ __launch_bounds__(256) void prep_wcat(
    const float* __restrict__ mg_W1, const float* __restrict__ mm_W1,
    unsigned short* __restrict__ WcatT) {
  int idx = blockIdx.x*256 + threadIdx.x;   // 9*1024*64
  int lh = idx >> 16;
  int n  = (idx >> 6) & 1023;
  int k  = idx & 63;
  const float* W = (n < 512) ? mg_W1 : mm_W1;
  int nn = n & 511;
  int r  = (nn < 256) ? k : (64 + k);
  int c  = nn & 255;
  WcatT[idx] = f2bf(W[(size_t)lh*(2*F_*HID_) + r*HID_ + c]);
}

// W2mT[lh][f][k] = bf16(mm_W2[lh][k][f])
__global__ __launch_bounds__(256) void prep_w2mt(
    const float* __restrict__ mm_W2, unsigned short* __restrict__ W2mT) {
  int idx = blockIdx.x*256 + threadIdx.x;   // 9*64*256
  int lh = idx >> 14;
  int f  = (idx >> 8) & 63;
  int k  = idx & 255;
  W2mT[idx] = f2bf(mm_W2[(size_t)lh*(HID_*F_) + k*F_ + f]);
}

// WcryT[n][k] (bf16, n-major, 1536 x 64)
__global__ __launch_bounds__(256) void prep_wcry(
    const float* __restrict__ cg_W1, const float* __restrict__ cm_W1,
    unsigned short* __restrict__ WcryT) {
  int idx = blockIdx.x*256 + threadIdx.x;   // 1536*64
  int n = idx >> 6, k = idx & 63;
  int h = n >> 9, r = n & 511;
  float v = (r < 256) ? cg_W1[(size_t)h*F_*HID_ + k*HID_ + r]
                      : cm_W1[(size_t)h*F_*HID_ + k*HID_ + (r - 256)];
  WcryT[idx] = f2bf(v);
}

// W2cT[h][f][k] = bf16(cm_W2[h][k][f])
__global__ __launch_bounds__(256) void prep_w2c(
    const float* __restrict__ cm_W2, unsigned short* __restrict__ W2cT) {
  int idx = blockIdx.x*256 + threadIdx.x;   // 3*64*256
  int h = idx >> 14;
  int f = (idx >> 8) & 63;
  int k = idx & 255;
  W2cT[idx] = f2bf(cm_W2[(size_t)h*HID_*F_ + k*F_ + f]);
}

__global__ __launch_bounds__(256) void conv_bf16(
    const float* __restrict__ in, unsigned short* __restrict__ out, int n) {
  int i = blockIdx.x*256 + threadIdx.x;
  if (i < n) out[i] = f2bf(in[i]);
}

// feaBF = bf16(cur) ; fea_nxt = cur  (residual base for atomic head accumulation)
__global__ __launch_bounds__(256) void conv_copy(
    const float* __restrict__ in, unsigned short* __restrict__ outbf,
    float* __restrict__ outf, int n) {
  int i = blockIdx.x*256 + threadIdx.x;
  if (i < n) { float v = in[i]; outbf[i] = f2bf(v); outf[i] = v; }
}

// C[4096][NSTR] (bf16) = A[4096][64] @ BT^T ; BT is [n][k] bf16, MFMA f32 accum
__global__ __launch_bounds__(256) void gemm_pq(
    const unsigned short* __restrict__ A,   // [4096][64] bf16
    const unsigned short* __restrict__ BT,  // [Ntot][64] bf16 (n-major)
    unsigned short* __restrict__ C, int NSTR) {
  __shared__ __align__(16) unsigned short As[64][72];
  __shared__ __align__(16) unsigned short Bs[128][72];
  int t = threadIdx.x;
  int m0 = blockIdx.x * 64;
  int n0 = blockIdx.y * 128;
  {
    int row = t >> 2, ch = (t & 3) * 16;
    const uint4* src = (const uint4*)(A + (size_t)(m0 + row)*64 + ch);
    *(uint4*)&As[row][ch]     = src[0];
    *(uint4*)&As[row][ch + 8] = src[1];
    int row2 = t >> 1, ch2 = (t & 1) * 32;
    const uint4* s2 = (const uint4*)(BT + (size_t)(n0 + row2)*64 + ch2);
    uint4* d2 = (uint4*)&Bs[row2][ch2];
    d2[0] = s2[0]; d2[1] = s2[1]; d2[2] = s2[2]; d2[3] = s2[3];
  }
  __syncthreads();
  int w = t >> 6, lane = t & 63;
  int mr = lane & 15, q = lane >> 4;
  short8 a0 = *(const short8*)&As[w*16 + mr][q*8];
  short8 a1 = *(const short8*)&As[w*16 + mr][32 + q*8];
  #pragma unroll
  for (int nt = 0; nt < 8; ++nt) {
    short8 b0 = *(const short8*)&Bs[nt*16 + mr][q*8];
    short8 b1 = *(const short8*)&Bs[nt*16 + mr][32 + q*8];
    f32x4 z = {0.f, 0.f, 0.f, 0.f};
    z = __builtin_amdgcn_mfma_f32_16x16x32_bf16(a0, b0, z, 0, 0, 0);
    z = __builtin_amdgcn_mfma_f32_16x16x32_bf16(a1, b1, z, 0, 0, 0);
    #pragma unroll
    for (int r = 0; r < 4; ++r)
      C[(size_t)(m0 + w*16 + q*4 + r)*NSTR + n0 + nt*16 + mr] = f2bf(z[r]);
  }
}

// ---------------------------------------------------------------------------
// Fused edge phase, grid (G_, H_, 2): sub-block s owns self-nodes i0=s*8..+8
// (120 edges). gate -> softmax -> msg MFMA -> accum, all in one launch.
// PQ (bf16) [node][h*1024 + {Pg:0..255, Qg:256..511, Pm:512..767, Qm:768..1023}]
// ---------------------------------------------------------------------------
__global__ __launch_bounds__(256, 5) void edge_fused(
    const unsigned short* __restrict__ PQ, const unsigned short* __restrict__ W2T,
    const float* __restrict__ mg_b1, const float* __restrict__ mg_W2,
    const float* __restrict__ mg_b2, const float* __restrict__ m_pow,
    const float* __restrict__ mm_b1, const float* __restrict__ mm_b2,
    const float* __restrict__ wts, float* __restrict__ fea_nxt, int l) {
  __shared__ __align__(16) unsigned short Ps[8][264];   // P rows (this sub-block's nodes)
  __shared__ __align__(16) unsigned short Qs[16][264];  // Q rows (all 16 nodes)
  __shared__ float bw[512];        // [0:256) b1, [256:512) W2gate
  __shared__ float gred[120][2];
  __shared__ float gateA[120];     // attn in place
  __shared__ float accum[9][68];   // row 8 = dummy for masked edges
  __shared__ float sumat[8];
  int t = threadIdx.x;
  int g = blockIdx.x, g16 = g * 16;
  int h = blockIdx.y, lh = l*H_ + h;
  int sb = blockIdx.z, i0 = sb * 8;
  const unsigned short* base = PQ + (size_t)g16*3072 + h*1024;

  // stage gate P (8 rows) + Q (16 rows)
  {
    int u = t;                       // 256 uint4 for Ps
    int row = u >> 5, c8 = (u & 31) * 8;
    *(uint4*)&Ps[row][c8] = *(const uint4*)(base + (size_t)(i0+row)*3072 + c8);
    #pragma unroll
    for (int s2 = 0; s2 < 2; ++s2) { // 512 uint4 for Qs
      int u2 = s2*256 + t;
      int row2 = u2 >> 5, d8 = (u2 & 31) * 8;
      *(uint4*)&Qs[row2][d8] = *(const uint4*)(base + (size_t)row2*3072 + 256 + d8);
    }
  }
  bw[t]       = mg_b1[lh*HID_ + t];
  bw[256 + t] = mg_W2[lh*HID_ + t];
  {
    int u = t; if (u < 9*68/4*4) {}  // accum zero: 612 floats
    #pragma unroll
    for (int s2 = 0; s2 < 3; ++s2) {
      int idx = s2*256 + t;
      if (idx < 9*68) ((float*)accum)[idx] = 0.f;
    }
  }
  __syncthreads();

  // gate logits: 2 threads per edge, 128 cols each
  if (t < 240) {
    int e = t >> 1, half = t & 1;
    int il = e / 15, jj = e - il*15;
    int ig = i0 + il;
    int j = (jj < ig) ? jj : jj + 1;
    int c0 = half * 128;
    float s = 0.f;
    #pragma unroll
    for (int c8 = 0; c8 < 128; c8 += 8) {
      short8 pv = *(const short8*)&Ps[il][c0 + c8];
      short8 qv = *(const short8*)&Qs[j][c0 + c8];
      #pragma unroll
      for (int r = 0; r < 8; ++r) {
        float hv = selu_f(bf2f((unsigned short)pv[r]) + bf2f((unsigned short)qv[r]) + bw[c0+c8+r]);
        s = fmaf(hv, bw[256 + c0 + c8 + r], s);
      }
    }
    gred[e][half] = s;
  }
  __syncthreads();

  // softmax attn (t<8) over 15 edges of node i0+t
  if (t < 8) {
    int il = t, ig = i0 + t;
    float pw = m_pow[lh];
    float b2v = mg_b2[lh];
    float gl[15];
    float m = -1e30f;
    #pragma unroll
    for (int jj = 0; jj < 15; ++jj) {
      float v = gred[il*15 + jj][0] + gred[il*15 + jj][1] + b2v;
      gl[jj] = v; m = fmaxf(m, v);
    }
    float den = 0.f;
    #pragma unroll
    for (int jj = 0; jj < 15; ++jj) {
      int j = (jj < ig) ? jj : jj + 1;
      float x = __powf(wts[g16 + j], pw) * __expf(gl[jj] - m);
      gl[jj] = x; den += x;
    }
    den += 1e-10f;
    float sa = 0.f;
    #pragma unroll
    for (int jj = 0; jj < 15; ++jj) {
      float a = gl[jj] / den; gateA[il*15 + jj] = a; sa += a;
    }
    sumat[il] = sa;
  }
  // restage msg P/Q over same buffers
  {
    int u = t;
    int row = u >> 5, c8 = (u & 31) * 8;
    uint4 pv = *(const uint4*)(base + (size_t)(i0+row)*3072 + 512 + c8);
    #pragma unroll
    for (int s2 = 0; s2 < 2; ++s2) {
      int u2 = s2*256 + t;
      int row2 = u2 >> 5, d8 = (u2 & 31) * 8;
      uint4 qv = *(const uint4*)(base + (size_t)row2*3072 + 768 + d8);
      __syncthreads();               // ensure gate reads done before overwrite (first iter only matters)
      if (s2 == 0) *(uint4*)&Ps[row][c8] = pv;
      *(uint4*)&Qs[row2][d8] = qv;
    }
  }
  if (t < 256) bw[t] = mm_b1[lh*HID_ + t];
  __syncthreads();

  // msg MFMA: 8 m-tiles (last half-masked), 2 per wave, barrier-free K-loop
  int w = t >> 6, lane = t & 63, mr = lane & 15, q = lane >> 4;
  f32x4 acc[2][4];
  #pragma unroll
  for (int mi = 0; mi < 2; ++mi)
    #pragma unroll
    for (int nt = 0; nt < 4; ++nt) { f32x4 z = {0.f,0.f,0.f,0.f}; acc[mi][nt] = z; }
  int iL[2], jL[2];
  #pragma unroll
  for (int mi = 0; mi < 2; ++mi) {
    int e = (w*2 + mi)*16 + mr;      // 0..127
    int ev = (e < 120) ? e : 0;
    int il = ev / 15, jj = ev - il*15;
    int ig = i0 + il;
    iL[mi] = il; jL[mi] = (jj < ig) ? jj : jj + 1;
  }
  const unsigned short* W2lh = W2T + (size_t)lh*64*256;

  for (int kc = 0; kc < 8; ++kc) {
    int k0 = kc*32 + q*8;
    short8 bfr[4];
    #pragma unroll
    for (int nt = 0; nt < 4; ++nt)
      bfr[nt] = *(const short8*)&W2lh[(size_t)(nt*16 + mr)*256 + k0];
    #pragma unroll
    for (int mi = 0; mi < 2; ++mi) {
      short8 pv = *(const short8*)&Ps[iL[mi]][k0];
      short8 qv = *(const short8*)&Qs[jL[mi]][k0];
      float hv[8];
      #pragma unroll
      for (int r = 0; r < 8; ++r)
        hv[r] = selu_f(bf2f((unsigned short)pv[r]) + bf2f((unsigned short)qv[r]) + bw[k0+r]);
      unsigned int apk[4];
      #pragma unroll
      for (int r2 = 0; r2 < 4; ++r2) apk[r2] = f2bf2(hv[2*r2], hv[2*r2+1]);
      short8 a = *reinterpret_cast<short8*>(apk);
      #pragma unroll
      for (int nt = 0; nt < 4; ++nt)
        acc[mi][nt] = __builtin_amdgcn_mfma_f32_16x16x32_bf16(a, bfr[nt], acc[mi][nt], 0, 0, 0);
    }
  }
  // attn-weighted accumulate (C row = q*4+r, col = nt*16+mr)
  #pragma unroll
  for (int mi = 0; mi < 2; ++mi) {
    int ebase = (w*2 + mi)*16 + q*4;
    #pragma unroll
    for (int nt = 0; nt < 4; ++nt) {
      int f = nt*16 + mr;
      int icur = ebase / 15; float vsum = 0.f;
      #pragma unroll
      for (int r = 0; r < 4; ++r) {
        int e = ebase + r;
        int ie = e / 15;               // 0..8 (8 = masked tail)
        float at = (e < 120) ? gateA[e] : 0.f;
        float v = acc[mi][nt][r] * at;
        if (ie != icur) { atomicAdd(&accum[icur][f], vsum); vsum = 0.f; icur = ie; }
        vsum += v;
      }
      atomicAdd(&accum[icur][f], vsum);
    }
  }
  __syncthreads();
  #pragma unroll
  for (int s2 = 0; s2 < 2; ++s2) {
    int u = s2*256 + t;
    int il = u >> 6, f = u & 63;
    float val = (accum[il][f] + mm_b2[lh*F_ + f]*sumat[il]) * (1.f/3.f);
    atomicAdd(&fea_nxt[(size_t)(g16 + i0 + il)*64 + f], val);
  }
}

// Crystal phase, fully fused: per graph, all 3 heads (PQc bf16)
__global__ __launch_bounds__(256) void cry_fused(
    const unsigned short* __restrict__ PQc, // [4096][1536] bf16
    const unsigned short* __restrict__ W2cT,// [3][64][256] bf16
    const float* __restrict__ cg_b1, const float* __restrict__ cg_W2,
    const float* __restrict__ cg_b2, const float* __restrict__ cm_b1,
    const float* __restrict__ cm_b2, const float* __restrict__ c_pow,
    const float* __restrict__ wts, float* __restrict__ out) {
  __shared__ float PQh[16][520];
  __shared__ float gred[16][18];
  __shared__ float attnL[16];
  __shared__ float sumatS;
  __shared__ __align__(16) unsigned short hidc[16][264];
  __shared__ float outg[64];
  int t = threadIdx.x;
  int g = blockIdx.x, g16 = g*16;
  if (t < 64) outg[t] = 0.f;
  for (int h = 0; h < H_; ++h) {
    __syncthreads();
    #pragma unroll
    for (int s = 0; s < 4; ++s) {
      int u = s*256 + t;
      int row = u >> 6, c8 = (u & 63) * 8;
      short8 raw = *(const short8*)(PQc + (size_t)(g16+row)*1536 + h*512 + c8);
      #pragma unroll
      for (int r = 0; r < 8; ++r) PQh[row][c8+r] = bf2f((unsigned short)raw[r]);
    }
    __syncthreads();
    {
      int i = t >> 4, c0 = (t & 15) * 16;
      float s = 0.f;
      #pragma unroll
      for (int c = c0; c < c0+16; ++c)
        s = fmaf(selu_f(PQh[i][c] + cg_b1[h*HID_ + c]), cg_W2[h*HID_ + c], s);
      gred[i][t & 15] = s;
    }
    __syncthreads();
    if (t < 16) {
      float sg = 0.f;
      #pragma unroll
      for (int u2 = 0; u2 < 16; ++u2) sg += gred[t][u2];
      gred[t][16] = sg + cg_b2[h];
    }
    __syncthreads();
    if (t == 0) {
      float pw = c_pow[h];
      float m = -1e30f;
      #pragma unroll
      for (int i = 0; i < 16; ++i) m = fmaxf(m, gred[i][16]);
      float den = 0.f; float v[16];
      #pragma unroll
      for (int i = 0; i < 16; ++i) {
        float x = __powf(wts[g16+i], pw) * __expf(gred[i][16] - m);
        v[i] = x; den += x;
      }
      den += 1e-10f;
      float sa = 0.f;
      #pragma unroll
      for (int i = 0; i < 16; ++i) { float a = v[i]/den; attnL[i] = a; sa += a; }
      sumatS = sa;
    }
    {
      int i = t >> 4, c0 = (t & 15) * 16;
      #pragma unroll
      for (int c = c0; c < c0+16; ++c)
        hidc[i][c] = f2bf(selu_f(PQh[i][256 + c] + cm_b1[h*HID_ + c]));
    }
    __syncthreads();
    int w = t >> 6, lane = t & 63, mr = lane & 15, q = lane >> 4;
    f32x4 acc = {0.f, 0.f, 0.f, 0.f};
    #pragma unroll
    for (int kc = 0; kc < 8; ++kc) {
      short8 a = *(const short8*)&hidc[mr][kc*32 + q*8];
      short8 b = *(const short8*)&W2cT[((size_t)h*64 + w*16 + mr)*HID_ + kc*32 + q*8];
      acc = __builtin_amdgcn_mfma_f32_16x16x32_bf16(a, b, acc, 0, 0, 0);
    }
    float p = 0.f;
    #pragma unroll
    for (int r = 0; r < 4; ++r) p = fmaf(attnL[q*4+r], acc[r], p);
    atomicAdd(&outg[w*16+mr], p);
    if (q == 0) atomicAdd(&outg[w*16+mr], cm_b2[h*F_ + w*16 + mr]*sumatS);
  }
  __syncthreads();
  if (t < 64) out[(size_t)g*64 + t] = outg[t] * (1.f/(float)H_);
}

extern "C" void kernel_launch(void* const* d_in, const int* in_sizes, int n_in,
                              void* d_out, int out_size, void* d_ws, size_t ws_size,
                              hipStream_t stream) {
  const float* elem_weights = (const float*)d_in[0];
  const float* elem_fea_in  = (const float*)d_in[1];
  const float* W_init = (const float*)d_in[2];
  const float* b_init = (const float*)d_in[3];
  const float* mg_W1  = (const float*)d_in[4];
  const float* mg_b1  = (const float*)d_in[5];
  const float* mg_W2  = (const float*)d_in[6];
  const float* mg_b2  = (const float*)d_in[7];
  const float* mm_W1  = (const float*)d_in[8];
  const float* mm_b1  = (const float*)d_in[9];
  const float* mm_W2  = (const float*)d_in[10];
  const float* mm_b2  = (const float*)d_in[11];
  const float* m_pow  = (const float*)d_in[12];
  const float* cg_W1  = (const float*)d_in[13];
  const float* cg_b1  = (const float*)d_in[14];
  const float* cg_W2  = (const float*)d_in[15];
  const float* cg_b2  = (const float*)d_in[16];
  const float* cm_W1  = (const float*)d_in[17];
  const float* cm_b1  = (const float*)d_in[18];
  const float* cm_W2  = (const float*)d_in[19];
  const float* cm_b2  = (const float*)d_in[20];
  const float* c_pow  = (const float*)d_in[21];

  // workspace (~30 MB): PQ bf16 union region [4096*3072 ushort] (edge) /
  // PQc bf16 [4096*1536] (crystal), then small buffers.
  float* ws = (float*)d_ws;
  unsigned short* PQ  = (unsigned short*)ws;
  unsigned short* PQc = (unsigned short*)ws;
  float* feaA  = ws   + (size_t)4096*3072/2;     // after bf16 PQ region
  float* feaB  = feaA + (size_t)N_*F_;
  unsigned short* feaBF = (unsigned short*)(feaB + (size_t)N_*F_);
  unsigned short* WcatT = feaBF + (size_t)N_*F_;           // 9*1024*64
  unsigned short* W2mT  = WcatT + (size_t)9*1024*64;       // 9*64*256
  unsigned short* WcryT = W2mT  + (size_t)9*64*256;        // 1536*64
  unsigned short* W2cT  = WcryT + (size_t)1536*64;         // 3*64*256

  prep_wcat<<<(9*1024*64)/256, 256, 0, stream>>>(mg_W1, mm_W1, WcatT);
  prep_w2mt<<<(9*64*256)/256, 256, 0, stream>>>(mm_W2, W2mT);
  prep_wcry<<<(1536*64)/256, 256, 0, stream>>>(cg_W1, cm_W1, WcryT);
  prep_w2c<<<(3*64*256)/256, 256, 0, stream>>>(cm_W2, W2cT);
  init_embed<<<N_, 64, 0, stream>>>(elem_fea_in, W_init, b_init, elem_weights, feaA);

  float* cur = feaA; float* nxt = feaB;
  for (int l = 0; l < L_; ++l) {
    conv_copy<<<(N_*F_)/256, 256, 0, stream>>>(cur, feaBF, nxt, N_*F_);
    gemm_pq<<<dim3(64, 24), 256, 0, stream>>>(
        feaBF, WcatT + (size_t)(3*l)*1024*64, PQ, 3072);
    edge_fused<<<dim3(G_, H_, 2), 256, 0, stream>>>(
        PQ, W2mT, mg_b1, mg_W2, mg_b2, m_pow, mm_b1, mm_b2,
        elem_weights, nxt, l);
    float* t = cur; cur = nxt; nxt = t;
  }

  // crystal phase
  conv_bf16<<<(N_*F_)/256, 256, 0, stream>>>(cur, feaBF, N_*F_);
  gemm_pq<<<dim3(64, 12), 256, 0, stream>>>(feaBF, WcryT, PQc, 1536);
  cry_fused<<<G_, 256, 0, stream>>>(
      PQc, W2cT, cg_b1, cg_W2, cg_b2, cm_b1, cm_b2, c_pow,
      elem_weights, (float*)d_out);
}

// Round 11
// 377.940 us; speedup vs baseline: 7.3857x; 1.0358x over previous
//
#include <hip/hip_runtime.h>
#include <hip/hip_bf16.h>

#define G_ 256
#define K_ 16
#define L_ 3
#define H_ 3
#define F_ 64
#define EMB_ 200
#define HID_ 256
#define N_ (G_*K_)          // 4096 nodes
#define E_ (G_*K_*(K_-1))   // 61440 edges

typedef __attribute__((ext_vector_type(8))) short short8;
typedef __attribute__((ext_vector_type(4))) float f32x4;

#define SELU_S 1.0507009873554804934193349852946f
#define SELU_SA (1.0507009873554804934193349852946f*1.6732632423543772848170429916717f)

// 5-op selu: exp, fma, mul, cmp, cndmask
__device__ __forceinline__ float selu_f(float x) {
  float e = __expf(x);
  float neg = fmaf(SELU_SA, e, -SELU_SA);
  float pos = SELU_S * x;
  return x > 0.f ? pos : neg;
}

__device__ __forceinline__ unsigned short f2bf(float x) {
  __hip_bfloat16 h = __float2bfloat16(x);
  return *reinterpret_cast<unsigned short*>(&h);
}

// packed 2xf32 -> 2xbf16
__device__ __forceinline__ unsigned int f2bf2(float a, float b) {
  float2 t; t.x = a; t.y = b;
  __hip_bfloat162 h = __float22bfloat162_rn(t);
  return *reinterpret_cast<unsigned int*>(&h);
}

__device__ __forceinline__ float bf2f(unsigned short u) {
  union { unsigned int i; float f; } v;
  v.i = ((unsigned int)u) << 16;
  return v.f;
}

// fea[n, 0:63] = elem_fea_in[n,:] @ W_init + b_init ; fea[n,63] = w[n]
__global__ __launch_bounds__(64) void init_embed(
    const float* __restrict__ fea_in, const float* __restrict__ W,
    const float* __restrict__ b, const float* __restrict__ wts,
    float* __restrict__ fea) {
  __shared__ float row[EMB_];
  int n = blockIdx.x;
  int j = threadIdx.x;
  for (int k = j; k < EMB_; k += 64) row[k] = fea_in[(size_t)n*EMB_ + k];
  __syncthreads();
  if (j < F_-1) {
    float s = b[j];
    for (int k = 0; k < EMB_; ++k) s = fmaf(row[k], W[k*(F_-1) + j], s);
    fea[(size_t)n*F_ + j] = s;
  } else {
    fea[(size_t)n*F_ + (F_-1)] = wts[n];
  }
}

// WcatT[lh][n][k] (bf16, n-major)
__global__ __launch_bounds__(256) void prep_wcat(
    const float* __restrict__ mg_W1, const float* __restrict__ mm_W1,
    unsigned short* __restrict__ WcatT) {
  int idx = blockIdx.x*256 + threadIdx.x;   // 9*1024*64
  int lh = idx >> 16;
  int n  = (idx >> 6) & 1023;
  int k  = idx & 63;
  const float* W = (n < 512) ? mg_W1 : mm_W1;
  int nn = n & 511;
  int r  = (nn < 256) ? k : (64 + k);
  int c  = nn & 255;
  WcatT[idx] = f2bf(W[(size_t)lh*(2*F_*HID_) + r*HID_ + c]);
}

// W2mT[lh][f][k] = bf16(mm_W2[lh][k][f])
__global__ __launch_bounds__(256) void prep_w2mt(
    const float* __restrict__ mm_W2, unsigned short* __restrict__ W2mT) {
  int idx = blockIdx.x*256 + threadIdx.x;   // 9*64*256
  int lh = idx >> 14;
  int f  = (idx >> 8) & 63;
  int k  = idx & 255;
  W2mT[idx] = f2bf(mm_W2[(size_t)lh*(HID_*F_) + k*F_ + f]);
}

// WcryT[n][k] (bf16, n-major, 1536 x 64)
__global__ __launch_bounds__(256) void prep_wcry(
    const float* __restrict__ cg_W1, const float* __restrict__ cm_W1,
    unsigned short* __restrict__ WcryT) {
  int idx = blockIdx.x*256 + threadIdx.x;   // 1536*64
  int n = idx >> 6, k = idx & 63;
  int h = n >> 9, r = n & 511;
  float v = (r < 256) ? cg_W1[(size_t)h*F_*HID_ + k*HID_ + r]
                      : cm_W1[(size_t)h*F_*HID_ + k*HID_ + (r - 256)];
  WcryT[idx] = f2bf(v);
}

// W2cT[h][f][k] = bf16(cm_W2[h][k][f])
__global__ __launch_bounds__(256) void prep_w2c(
    const float* __restrict__ cm_W2, unsigned short* __restrict__ W2cT) {
  int idx = blockIdx.x*256 + threadIdx.x;   // 3*64*256
  int h = idx >> 14;
  int f = (idx >> 8) & 63;
  int k = idx & 255;
  W2cT[idx] = f2bf(cm_W2[(size_t)h*HID_*F_ + k*F_ + f]);
}

// bias_e[l][3072]: h*1024 + [0,256)=mg_b1 ; [512,768)=mm_b1 ; else 0
// bias_c[1536]:    h*512  + [0,256)=cg_b1 ; [256,512)=cm_b1
__global__ __launch_bounds__(256) void prep_bias(
    const float* __restrict__ mg_b1, const float* __restrict__ mm_b1,
    const float* __restrict__ cg_b1, const float* __restrict__ cm_b1,
    float* __restrict__ bias_e, float* __restrict__ bias_c) {
  int idx = blockIdx.x*256 + threadIdx.x;   // 9216 + 1536
  if (idx < 9216) {
    int l = idx / 3072, c = idx - l*3072;
    int h = c >> 10, cc = c & 1023;
    int lh = l*H_ + h;
    float v = 0.f;
    if (cc < 256) v = mg_b1[lh*HID_ + cc];
    else if (cc >= 512 && cc < 768) v = mm_b1[lh*HID_ + (cc - 512)];
    bias_e[idx] = v;
  } else if (idx < 9216 + 1536) {
    int c = idx - 9216;
    int h = c >> 9, cc = c & 511;
    bias_c[c] = (cc < 256) ? cg_b1[h*HID_ + cc] : cm_b1[h*HID_ + (cc - 256)];
  }
}

__global__ __launch_bounds__(256) void conv_bf16(
    const float* __restrict__ in, unsigned short* __restrict__ out, int n) {
  int i = blockIdx.x*256 + threadIdx.x;
  if (i < n) out[i] = f2bf(in[i]);
}

// feaBF = bf16(cur) ; fea_nxt = cur
__global__ __launch_bounds__(256) void conv_copy(
    const float* __restrict__ in, unsigned short* __restrict__ outbf,
    float* __restrict__ outf, int n) {
  int i = blockIdx.x*256 + threadIdx.x;
  if (i < n) { float v = in[i]; outbf[i] = f2bf(v); outf[i] = v; }
}

// C[4096][NSTR] (bf16) = A[4096][64] @ BT^T + bias ; MFMA f32 accum
__global__ __launch_bounds__(256) void gemm_pq(
    const unsigned short* __restrict__ A,   // [4096][64] bf16
    const unsigned short* __restrict__ BT,  // [Ntot][64] bf16 (n-major)
    const float* __restrict__ bias,         // [Ntot]
    unsigned short* __restrict__ C, int NSTR) {
  __shared__ __align__(16) unsigned short As[64][72];
  __shared__ __align__(16) unsigned short Bs[128][72];
  __shared__ float bs[128];
  int t = threadIdx.x;
  int m0 = blockIdx.x * 64;
  int n0 = blockIdx.y * 128;
  {
    int row = t >> 2, ch = (t & 3) * 16;
    const uint4* src = (const uint4*)(A + (size_t)(m0 + row)*64 + ch);
    *(uint4*)&As[row][ch]     = src[0];
    *(uint4*)&As[row][ch + 8] = src[1];
    int row2 = t >> 1, ch2 = (t & 1) * 32;
    const uint4* s2 = (const uint4*)(BT + (size_t)(n0 + row2)*64 + ch2);
    uint4* d2 = (uint4*)&Bs[row2][ch2];
    d2[0] = s2[0]; d2[1] = s2[1]; d2[2] = s2[2]; d2[3] = s2[3];
  }
  if (t < 128) bs[t] = bias[n0 + t];
  __syncthreads();
  int w = t >> 6, lane = t & 63;
  int mr = lane & 15, q = lane >> 4;
  short8 a0 = *(const short8*)&As[w*16 + mr][q*8];
  short8 a1 = *(const short8*)&As[w*16 + mr][32 + q*8];
  #pragma unroll
  for (int nt = 0; nt < 8; ++nt) {
    short8 b0 = *(const short8*)&Bs[nt*16 + mr][q*8];
    short8 b1 = *(const short8*)&Bs[nt*16 + mr][32 + q*8];
    f32x4 z = {0.f, 0.f, 0.f, 0.f};
    z = __builtin_amdgcn_mfma_f32_16x16x32_bf16(a0, b0, z, 0, 0, 0);
    z = __builtin_amdgcn_mfma_f32_16x16x32_bf16(a1, b1, z, 0, 0, 0);
    float bb = bs[nt*16 + mr];
    #pragma unroll
    for (int r = 0; r < 4; ++r)
      C[(size_t)(m0 + w*16 + q*4 + r)*NSTR + n0 + nt*16 + mr] = f2bf(z[r] + bb);
  }
}

// ---------------------------------------------------------------------------
// Fused edge phase, 512 threads, grid (G_, H_): one block per (graph, head).
// PQ (bf16, b1 pre-folded into P parts): [node][h*1024 + {Pg,Qg,Pm,Qm} x256]
// All 4 quarters staged once; gate (480 thr, interleaved halves) -> softmax ->
// msg MFMA (15 m-tiles over 8 waves) -> attn-weighted accum -> atomic residual.
// ---------------------------------------------------------------------------
__global__ __launch_bounds__(512, 4) void edge_fused(
    const unsigned short* __restrict__ PQ, const unsigned short* __restrict__ W2T,
    const float* __restrict__ mg_W2, const float* __restrict__ mg_b2,
    const float* __restrict__ m_pow, const float* __restrict__ mm_b2,
    const float* __restrict__ wts, float* __restrict__ fea_nxt, int l) {
  __shared__ __align__(16) unsigned short PQs[16][1032];  // 516 words/row, skew 4
  __shared__ float w2g[256];
  __shared__ float gred[240][2];
  __shared__ float gateA[240];
  __shared__ float accum[16][68];
  __shared__ float sumat[16];
  int t = threadIdx.x;
  int g = blockIdx.x, g16 = g * 16;
  int h = blockIdx.y, lh = l*H_ + h;
  const unsigned short* base = PQ + (size_t)g16*3072 + h*1024;

  // stage 16 rows x 1024 bf16 (2048 uint4, 4 per thread)
  #pragma unroll
  for (int s = 0; s < 4; ++s) {
    int u = s*512 + t;
    int row = u >> 7, c8 = (u & 127) * 8;
    *(uint4*)&PQs[row][c8] = *(const uint4*)(base + (size_t)row*3072 + c8);
  }
  if (t < 256) w2g[t] = mg_W2[lh*HID_ + t];
  #pragma unroll
  for (int s = 0; s < 3; ++s) {
    int idx = s*512 + t;
    if (idx < 16*68) ((float*)accum)[idx] = 0.f;
  }
  __syncthreads();

  // gate: 2 threads/edge, interleaved 8-col chunks (pair-lane offset 4 words)
  if (t < 480) {
    int e = t >> 1, half = t & 1;
    int i = e / 15, jj = e - i*15;
    int j = (jj < i) ? jj : jj + 1;
    float s = 0.f;
    #pragma unroll
    for (int u = 0; u < 16; ++u) {
      int c = half*8 + u*16;
      short8 pv = *(const short8*)&PQs[i][c];
      short8 qv = *(const short8*)&PQs[j][256 + c];
      #pragma unroll
      for (int r = 0; r < 8; ++r) {
        float hv = selu_f(bf2f((unsigned short)pv[r]) + bf2f((unsigned short)qv[r]));
        s = fmaf(hv, w2g[c + r], s);
      }
    }
    gred[e][half] = s;
  }
  __syncthreads();

  // softmax attn (t<16) over 15 edges of node t
  if (t < 16) {
    int i = t;
    float pw = m_pow[lh];
    float b2v = mg_b2[lh];
    float gl[15];
    float m = -1e30f;
    #pragma unroll
    for (int jj = 0; jj < 15; ++jj) {
      float v = gred[i*15 + jj][0] + gred[i*15 + jj][1] + b2v;
      gl[jj] = v; m = fmaxf(m, v);
    }
    float den = 0.f;
    #pragma unroll
    for (int jj = 0; jj < 15; ++jj) {
      int j = (jj < i) ? jj : jj + 1;
      float x = __powf(wts[g16 + j], pw) * __expf(gl[jj] - m);
      gl[jj] = x; den += x;
    }
    den += 1e-10f;
    float sa = 0.f;
    #pragma unroll
    for (int jj = 0; jj < 15; ++jj) {
      float a = gl[jj] / den; gateA[i*15 + jj] = a; sa += a;
    }
    sumat[i] = sa;
  }
  __syncthreads();

  // msg MFMA: 15 m-tiles over 8 waves (2 per wave, last slot masked)
  int w = t >> 6, lane = t & 63, mr = lane & 15, q = lane >> 4;
  f32x4 acc[2][4];
  #pragma unroll
  for (int mi = 0; mi < 2; ++mi)
    #pragma unroll
    for (int nt = 0; nt < 4; ++nt) { f32x4 z = {0.f,0.f,0.f,0.f}; acc[mi][nt] = z; }
  int iL[2], jL[2];
  #pragma unroll
  for (int mi = 0; mi < 2; ++mi) {
    int mt = w*2 + mi; if (mt > 14) mt = 14;
    int e = mt*16 + mr;
    int i = e / 15, jj = e - i*15;
    iL[mi] = i; jL[mi] = (jj < i) ? jj : jj + 1;
  }
  const unsigned short* W2lh = W2T + (size_t)lh*64*256;

  for (int kc = 0; kc < 8; ++kc) {
    int k0 = kc*32 + q*8;
    short8 bfr[4];
    #pragma unroll
    for (int nt = 0; nt < 4; ++nt)
      bfr[nt] = *(const short8*)&W2lh[(size_t)(nt*16 + mr)*256 + k0];
    #pragma unroll
    for (int mi = 0; mi < 2; ++mi) {
      if (w*2 + mi < 15) {            // wave-uniform, compile-time mi
        short8 pv = *(const short8*)&PQs[iL[mi]][512 + k0];
        short8 qv = *(const short8*)&PQs[jL[mi]][768 + k0];
        float hv[8];
        #pragma unroll
        for (int r = 0; r < 8; ++r)
          hv[r] = selu_f(bf2f((unsigned short)pv[r]) + bf2f((unsigned short)qv[r]));
        unsigned int apk[4];
        #pragma unroll
        for (int r2 = 0; r2 < 4; ++r2) apk[r2] = f2bf2(hv[2*r2], hv[2*r2+1]);
        short8 a = *reinterpret_cast<short8*>(apk);
        #pragma unroll
        for (int nt = 0; nt < 4; ++nt)
          acc[mi][nt] = __builtin_amdgcn_mfma_f32_16x16x32_bf16(a, bfr[nt], acc[mi][nt], 0, 0, 0);
      }
    }
  }
  // attn-weighted accumulate (C row = q*4+r, col = nt*16+mr)
  #pragma unroll
  for (int mi = 0; mi < 2; ++mi) {
    if (w*2 + mi < 15) {
      int ebase = (w*2 + mi)*16 + q*4;
      #pragma unroll
      for (int nt = 0; nt < 4; ++nt) {
        int f = nt*16 + mr;
        int icur = ebase / 15; float vsum = 0.f;
        #pragma unroll
        for (int r = 0; r < 4; ++r) {
          int e = ebase + r;
          int ie = e / 15;
          float v = acc[mi][nt][r] * gateA[e];
          if (ie != icur) { atomicAdd(&accum[icur][f], vsum); vsum = 0.f; icur = ie; }
          vsum += v;
        }
        atomicAdd(&accum[icur][f], vsum);
      }
    }
  }
  __syncthreads();
  #pragma unroll
  for (int s2 = 0; s2 < 2; ++s2) {
    int u = s2*512 + t;
    int i = u >> 6, f = u & 63;
    float val = (accum[i][f] + mm_b2[lh*F_ + f]*sumat[i]) * (1.f/3.f);
    atomicAdd(&fea_nxt[(size_t)(g16 + i)*64 + f], val);
  }
}

// Crystal phase: per graph, all 3 heads. PQc bf16, b1 pre-folded.
__global__ __launch_bounds__(256) void cry_fused(
    const unsigned short* __restrict__ PQc, // [4096][1536] bf16
    const unsigned short* __restrict__ W2cT,// [3][64][256] bf16
    const float* __restrict__ cg_W2, const float* __restrict__ cg_b2,
    const float* __restrict__ cm_b2, const float* __restrict__ c_pow,
    const float* __restrict__ wts, float* __restrict__ out) {
  __shared__ float PQh[16][520];
  __shared__ float gred[16][18];
  __shared__ float attnL[16];
  __shared__ float sumatS;
  __shared__ __align__(16) unsigned short hidc[16][264];
  __shared__ float outg[64];
  int t = threadIdx.x;
  int g = blockIdx.x, g16 = g*16;
  if (t < 64) outg[t] = 0.f;
  for (int h = 0; h < H_; ++h) {
    __syncthreads();
    #pragma unroll
    for (int s = 0; s < 4; ++s) {
      int u = s*256 + t;
      int row = u >> 6, c8 = (u & 63) * 8;
      short8 raw = *(const short8*)(PQc + (size_t)(g16+row)*1536 + h*512 + c8);
      #pragma unroll
      for (int r = 0; r < 8; ++r) PQh[row][c8+r] = bf2f((unsigned short)raw[r]);
    }
    __syncthreads();
    {
      int i = t >> 4, c0 = (t & 15) * 16;
      float s = 0.f;
      #pragma unroll
      for (int c = c0; c < c0+16; ++c)
        s = fmaf(selu_f(PQh[i][c]), cg_W2[h*HID_ + c], s);
      gred[i][t & 15] = s;
    }
    __syncthreads();
    if (t < 16) {
      float sg = 0.f;
      #pragma unroll
      for (int u2 = 0; u2 < 16; ++u2) sg += gred[t][u2];
      gred[t][16] = sg + cg_b2[h];
    }
    __syncthreads();
    if (t == 0) {
      float pw = c_pow[h];
      float m = -1e30f;
      #pragma unroll
      for (int i = 0; i < 16; ++i) m = fmaxf(m, gred[i][16]);
      float den = 0.f; float v[16];
      #pragma unroll
      for (int i = 0; i < 16; ++i) {
        float x = __powf(wts[g16+i], pw) * __expf(gred[i][16] - m);
        v[i] = x; den += x;
      }
      den += 1e-10f;
      float sa = 0.f;
      #pragma unroll
      for (int i = 0; i < 16; ++i) { float a = v[i]/den; attnL[i] = a; sa += a; }
      sumatS = sa;
    }
    {
      int i = t >> 4, c0 = (t & 15) * 16;
      #pragma unroll
      for (int c = c0; c < c0+16; c += 2) {
        unsigned int pk = f2bf2(selu_f(PQh[i][256 + c]), selu_f(PQh[i][256 + c + 1]));
        *(unsigned int*)&hidc[i][c] = pk;
      }
    }
    __syncthreads();
    int w = t >> 6, lane = t & 63, mr = lane & 15, q = lane >> 4;
    f32x4 acc = {0.f, 0.f, 0.f, 0.f};
    #pragma unroll
    for (int kc = 0; kc < 8; ++kc) {
      short8 a = *(const short8*)&hidc[mr][kc*32 + q*8];
      short8 b = *(const short8*)&W2cT[((size_t)h*64 + w*16 + mr)*HID_ + kc*32 + q*8];
      acc = __builtin_amdgcn_mfma_f32_16x16x32_bf16(a, b, acc, 0, 0, 0);
    }
    float p = 0.f;
    #pragma unroll
    for (int r = 0; r < 4; ++r) p = fmaf(attnL[q*4+r], acc[r], p);
    atomicAdd(&outg[w*16+mr], p);
    if (q == 0) atomicAdd(&outg[w*16+mr], cm_b2[h*F_ + w*16 + mr]*sumatS);
  }
  __syncthreads();
  if (t < 64) out[(size_t)g*64 + t] = outg[t] * (1.f/(float)H_);
}

extern "C" void kernel_launch(void* const* d_in, const int* in_sizes, int n_in,
                              void* d_out, int out_size, void* d_ws, size_t ws_size,
                              hipStream_t stream) {
  const float* elem_weights = (const float*)d_in[0];
  const float* elem_fea_in  = (const float*)d_in[1];
  const float* W_init = (const float*)d_in[2];
  const float* b_init = (const float*)d_in[3];
  const float* mg_W1  = (const float*)d_in[4];
  const float* mg_b1  = (const float*)d_in[5];
  const float* mg_W2  = (const float*)d_in[6];
  const float* mg_b2  = (const float*)d_in[7];
  const float* mm_W1  = (const float*)d_in[8];
  const float* mm_b1  = (const float*)d_in[9];
  const float* mm_W2  = (const float*)d_in[10];
  const float* mm_b2  = (const float*)d_in[11];
  const float* m_pow  = (const float*)d_in[12];
  const float* cg_W1  = (const float*)d_in[13];
  const float* cg_b1  = (const float*)d_in[14];
  const float* cg_W2  = (const float*)d_in[15];
  const float* cg_b2  = (const float*)d_in[16];
  const float* cm_W1  = (const float*)d_in[17];
  const float* cm_b1  = (const float*)d_in[18];
  const float* cm_W2  = (const float*)d_in[19];
  const float* cm_b2  = (const float*)d_in[20];
  const float* c_pow  = (const float*)d_in[21];

  // workspace (~29 MB)
  float* ws = (float*)d_ws;
  unsigned short* PQ  = (unsigned short*)ws;     // union: edge [4096*3072] bf16
  unsigned short* PQc = (unsigned short*)ws;     //        crystal [4096*1536] bf16
  float* feaA  = ws   + (size_t)4096*3072/2;
  float* feaB  = feaA + (size_t)N_*F_;
  unsigned short* feaBF = (unsigned short*)(feaB + (size_t)N_*F_);
  unsigned short* WcatT = feaBF + (size_t)N_*F_;           // 9*1024*64
  unsigned short* W2mT  = WcatT + (size_t)9*1024*64;       // 9*64*256
  unsigned short* WcryT = W2mT  + (size_t)9*64*256;        // 1536*64
  unsigned short* W2cT  = WcryT + (size_t)1536*64;         // 3*64*256
  float* bias_e = (float*)(W2cT + (size_t)3*64*256);       // 3*3072
  float* bias_c = bias_e + 3*3072;                         // 1536

  prep_wcat<<<(9*1024*64)/256, 256, 0, stream>>>(mg_W1, mm_W1, WcatT);
  prep_w2mt<<<(9*64*256)/256, 256, 0, stream>>>(mm_W2, W2mT);
  prep_wcry<<<(1536*64)/256, 256, 0, stream>>>(cg_W1, cm_W1, WcryT);
  prep_w2c<<<(3*64*256)/256, 256, 0, stream>>>(cm_W2, W2cT);
  prep_bias<<<(9216+1536+255)/256, 256, 0, stream>>>(mg_b1, mm_b1, cg_b1, cm_b1, bias_e, bias_c);
  init_embed<<<N_, 64, 0, stream>>>(elem_fea_in, W_init, b_init, elem_weights, feaA);

  float* cur = feaA; float* nxt = feaB;
  for (int l = 0; l < L_; ++l) {
    conv_copy<<<(N_*F_)/256, 256, 0, stream>>>(cur, feaBF, nxt, N_*F_);
    gemm_pq<<<dim3(64, 24), 256, 0, stream>>>(
        feaBF, WcatT + (size_t)(3*l)*1024*64, bias_e + (size_t)l*3072, PQ, 3072);
    edge_fused<<<dim3(G_, H_), 512, 0, stream>>>(
        PQ, W2mT, mg_W2, mg_b2, m_pow, mm_b2, elem_weights, nxt, l);
    float* t = cur; cur = nxt; nxt = t;
  }

  // crystal phase
  conv_bf16<<<(N_*F_)/256, 256, 0, stream>>>(cur, feaBF, N_*F_);
  gemm_pq<<<dim3(64, 12), 256, 0, stream>>>(feaBF, WcryT, bias_c, PQc, 1536);
  cry_fused<<<G_, 256, 0, stream>>>(
      PQc, W2cT, cg_W2, cg_b2, cm_b2, c_pow, elem_weights, (float*)d_out);
}

// Round 12
// 354.795 us; speedup vs baseline: 7.8674x; 1.0652x over previous
//
#include <hip/hip_runtime.h>
#include <hip/hip_bf16.h>

#define G_ 256
#define K_ 16
#define L_ 3
#define H_ 3
#define F_ 64
#define EMB_ 200
#define HID_ 256
#define N_ (G_*K_)          // 4096 nodes
#define E_ (G_*K_*(K_-1))   // 61440 edges

typedef __attribute__((ext_vector_type(8))) short short8;
typedef __attribute__((ext_vector_type(4))) float f32x4;

#define SELU_S 1.0507009873554804934193349852946f
#define SELU_SA (1.0507009873554804934193349852946f*1.6732632423543772848170429916717f)

// 5-op selu
__device__ __forceinline__ float selu_f(float x) {
  float e = __expf(x);
  float neg = fmaf(SELU_SA, e, -SELU_SA);
  float pos = SELU_S * x;
  return x > 0.f ? pos : neg;
}

__device__ __forceinline__ unsigned short f2bf(float x) {
  __hip_bfloat16 h = __float2bfloat16(x);
  return *reinterpret_cast<unsigned short*>(&h);
}

__device__ __forceinline__ unsigned int f2bf2(float a, float b) {
  float2 t; t.x = a; t.y = b;
  __hip_bfloat162 h = __float22bfloat162_rn(t);
  return *reinterpret_cast<unsigned int*>(&h);
}

__device__ __forceinline__ float bf2f(unsigned short u) {
  union { unsigned int i; float f; } v;
  v.i = ((unsigned int)u) << 16;
  return v.f;
}

// fea[n, 0:63] = elem_fea_in[n,:] @ W_init + b_init ; fea[n,63] = w[n]
__global__ __launch_bounds__(64) void init_embed(
    const float* __restrict__ fea_in, const float* __restrict__ W,
    const float* __restrict__ b, const float* __restrict__ wts,
    float* __restrict__ fea) {
  __shared__ float row[EMB_];
  int n = blockIdx.x;
  int j = threadIdx.x;
  for (int k = j; k < EMB_; k += 64) row[k] = fea_in[(size_t)n*EMB_ + k];
  __syncthreads();
  if (j < F_-1) {
    float s = b[j];
    for (int k = 0; k < EMB_; ++k) s = fmaf(row[k], W[k*(F_-1) + j], s);
    fea[(size_t)n*F_ + j] = s;
  } else {
    fea[(size_t)n*F_ + (F_-1)] = wts[n];
  }
}

// WcatT[lh][n][k] (bf16, n-major)
__global__ __launch_bounds__(256) void prep_wcat(
    const float* __restrict__ mg_W1, const float* __restrict__ mm_W1,
    unsigned short* __restrict__ WcatT) {
  int idx = blockIdx.x*256 + threadIdx.x;   // 9*1024*64
  int lh = idx >> 16;
  int n  = (idx >> 6) & 1023;
  int k  = idx & 63;
  const float* W = (n < 512) ? mg_W1 : mm_W1;
  int nn = n & 511;
  int r  = (nn < 256) ? k : (64 + k);
  int c  = nn & 255;
  WcatT[idx] = f2bf(W[(size_t)lh*(2*F_*HID_) + r*HID_ + c]);
}

// W2mT[lh][f][k] = bf16(mm_W2[lh][k][f])
__global__ __launch_bounds__(256) void prep_w2mt(
    const float* __restrict__ mm_W2, unsigned short* __restrict__ W2mT) {
  int idx = blockIdx.x*256 + threadIdx.x;   // 9*64*256
  int lh = idx >> 14;
  int f  = (idx >> 8) & 63;
  int k  = idx & 255;
  W2mT[idx] = f2bf(mm_W2[(size_t)lh*(HID_*F_) + k*F_ + f]);
}

// WcryT[n][k] (bf16, n-major, 1536 x 64): n = h*512 + {gate 0..255 | msg 256..511}
__global__ __launch_bounds__(256) void prep_wcry(
    const float* __restrict__ cg_W1, const float* __restrict__ cm_W1,
    unsigned short* __restrict__ WcryT) {
  int idx = blockIdx.x*256 + threadIdx.x;   // 1536*64
  int n = idx >> 6, k = idx & 63;
  int h = n >> 9, r = n & 511;
  float v = (r < 256) ? cg_W1[(size_t)h*F_*HID_ + k*HID_ + r]
                      : cm_W1[(size_t)h*F_*HID_ + k*HID_ + (r - 256)];
  WcryT[idx] = f2bf(v);
}

// W2cT[h][f][k] = bf16(cm_W2[h][k][f])
__global__ __launch_bounds__(256) void prep_w2c(
    const float* __restrict__ cm_W2, unsigned short* __restrict__ W2cT) {
  int idx = blockIdx.x*256 + threadIdx.x;   // 3*64*256
  int h = idx >> 14;
  int f = (idx >> 8) & 63;
  int k = idx & 255;
  W2cT[idx] = f2bf(cm_W2[(size_t)h*HID_*F_ + k*F_ + f]);
}

// bias_e[l][3072]: h*1024 + [0,256)=mg_b1 ; [512,768)=mm_b1 ; else 0
// bias_c[1536]:    h*512  + [0,256)=cg_b1 ; [256,512)=cm_b1
__global__ __launch_bounds__(256) void prep_bias(
    const float* __restrict__ mg_b1, const float* __restrict__ mm_b1,
    const float* __restrict__ cg_b1, const float* __restrict__ cm_b1,
    float* __restrict__ bias_e, float* __restrict__ bias_c) {
  int idx = blockIdx.x*256 + threadIdx.x;
  if (idx < 9216) {
    int l = idx / 3072, c = idx - l*3072;
    int h = c >> 10, cc = c & 1023;
    int lh = l*H_ + h;
    float v = 0.f;
    if (cc < 256) v = mg_b1[lh*HID_ + cc];
    else if (cc >= 512 && cc < 768) v = mm_b1[lh*HID_ + (cc - 512)];
    bias_e[idx] = v;
  } else if (idx < 9216 + 1536) {
    int c = idx - 9216;
    int h = c >> 9, cc = c & 511;
    bias_c[c] = (cc < 256) ? cg_b1[h*HID_ + cc] : cm_b1[h*HID_ + (cc - 256)];
  }
}

// fea_nxt = cur (f32 copy, float4)
__global__ __launch_bounds__(256) void copy_fea(
    const float* __restrict__ in, float* __restrict__ out) {
  int i = blockIdx.x*256 + threadIdx.x;     // N_*F_/4 elements
  ((float4*)out)[i] = ((const float4*)in)[i];
}

// ---------------------------------------------------------------------------
// Fully fused edge phase, 512 threads, grid (G_, H_):
//   PQ-GEMM in-block (fea 16x64 @ Wcat 64x1024, bias folded) -> LDS bf16
//   -> gate (480 thr) -> softmax -> msg MFMA -> attn accum -> atomic residual.
// No PQ workspace in HBM at all.
// ---------------------------------------------------------------------------
__global__ __launch_bounds__(512, 4) void edge_fused(
    const float* __restrict__ fea, const unsigned short* __restrict__ WcatT,
    const float* __restrict__ bias_e, const unsigned short* __restrict__ W2T,
    const float* __restrict__ mg_W2, const float* __restrict__ mg_b2,
    const float* __restrict__ m_pow, const float* __restrict__ mm_b2,
    const float* __restrict__ wts, float* __restrict__ fea_nxt, int l) {
  __shared__ __align__(16) unsigned short feaS[16][72];
  __shared__ __align__(16) unsigned short PQs[16][1032];  // Pg|Qg|Pm|Qm x256, skew 8
  __shared__ float bs[1024];
  __shared__ float w2g[256];
  __shared__ float gred[240][2];
  __shared__ float gateA[240];
  __shared__ float accum[16][68];
  __shared__ float sumat[16];
  int t = threadIdx.x;
  int g = blockIdx.x, g16 = g * 16;
  int h = blockIdx.y, lh = l*H_ + h;
  const unsigned short* Wlh = WcatT + (size_t)lh*1024*64;
  const float* biaslh = bias_e + (size_t)l*3072 + h*1024;

  // stage fea (16x64 f32 -> bf16), bias, gate-W2, zero accum
  {
    int row = t >> 5, c2 = (t & 31) * 2;
    float2 fv = *(const float2*)&fea[(size_t)(g16 + row)*64 + c2];
    *(unsigned int*)&feaS[row][c2] = f2bf2(fv.x, fv.y);
  }
  bs[t] = biaslh[t];
  bs[512 + t] = biaslh[512 + t];
  if (t < 256) w2g[t] = mg_W2[lh*HID_ + t];
  #pragma unroll
  for (int s = 0; s < 3; ++s) {
    int idx = s*512 + t;
    if (idx < 16*68) ((float*)accum)[idx] = 0.f;
  }
  __syncthreads();

  int w = t >> 6, lane = t & 63, mr = lane & 15, q = lane >> 4;

  // PQ GEMM: wave w computes cols n0w..n0w+127 for all 16 nodes
  {
    int n0w = w * 128;
    short8 a0 = *(const short8*)&feaS[mr][q*8];
    short8 a1 = *(const short8*)&feaS[mr][32 + q*8];
    #pragma unroll
    for (int nt = 0; nt < 8; ++nt) {
      int n = n0w + nt*16 + mr;
      const unsigned short* bp = Wlh + (size_t)n*64 + q*8;
      short8 b0 = *(const short8*)bp;
      short8 b1 = *(const short8*)(bp + 32);
      f32x4 z = {0.f, 0.f, 0.f, 0.f};
      z = __builtin_amdgcn_mfma_f32_16x16x32_bf16(a0, b0, z, 0, 0, 0);
      z = __builtin_amdgcn_mfma_f32_16x16x32_bf16(a1, b1, z, 0, 0, 0);
      float bb = bs[n];
      #pragma unroll
      for (int r = 0; r < 4; ++r)
        PQs[q*4 + r][n] = f2bf(z[r] + bb);
    }
  }
  __syncthreads();

  // gate: 2 threads/edge, interleaved 8-col chunks
  if (t < 480) {
    int e = t >> 1, half = t & 1;
    int i = e / 15, jj = e - i*15;
    int j = (jj < i) ? jj : jj + 1;
    float s = 0.f;
    #pragma unroll
    for (int u = 0; u < 16; ++u) {
      int c = half*8 + u*16;
      short8 pv = *(const short8*)&PQs[i][c];
      short8 qv = *(const short8*)&PQs[j][256 + c];
      #pragma unroll
      for (int r = 0; r < 8; ++r) {
        float hv = selu_f(bf2f((unsigned short)pv[r]) + bf2f((unsigned short)qv[r]));
        s = fmaf(hv, w2g[c + r], s);
      }
    }
    gred[e][half] = s;
  }
  __syncthreads();

  // softmax attn (t<16)
  if (t < 16) {
    int i = t;
    float pw = m_pow[lh];
    float b2v = mg_b2[lh];
    float gl[15];
    float m = -1e30f;
    #pragma unroll
    for (int jj = 0; jj < 15; ++jj) {
      float v = gred[i*15 + jj][0] + gred[i*15 + jj][1] + b2v;
      gl[jj] = v; m = fmaxf(m, v);
    }
    float den = 0.f;
    #pragma unroll
    for (int jj = 0; jj < 15; ++jj) {
      int j = (jj < i) ? jj : jj + 1;
      float x = __powf(wts[g16 + j], pw) * __expf(gl[jj] - m);
      gl[jj] = x; den += x;
    }
    den += 1e-10f;
    float sa = 0.f;
    #pragma unroll
    for (int jj = 0; jj < 15; ++jj) {
      float a = gl[jj] / den; gateA[i*15 + jj] = a; sa += a;
    }
    sumat[i] = sa;
  }
  __syncthreads();

  // msg MFMA: 15 m-tiles over 8 waves (2 per wave, last masked)
  f32x4 acc[2][4];
  #pragma unroll
  for (int mi = 0; mi < 2; ++mi)
    #pragma unroll
    for (int nt = 0; nt < 4; ++nt) { f32x4 z = {0.f,0.f,0.f,0.f}; acc[mi][nt] = z; }
  int iL[2], jL[2];
  #pragma unroll
  for (int mi = 0; mi < 2; ++mi) {
    int mt = w*2 + mi; if (mt > 14) mt = 14;
    int e = mt*16 + mr;
    int i = e / 15, jj = e - i*15;
    iL[mi] = i; jL[mi] = (jj < i) ? jj : jj + 1;
  }
  const unsigned short* W2lh = W2T + (size_t)lh*64*256;

  for (int kc = 0; kc < 8; ++kc) {
    int k0 = kc*32 + q*8;
    short8 bfr[4];
    #pragma unroll
    for (int nt = 0; nt < 4; ++nt)
      bfr[nt] = *(const short8*)&W2lh[(size_t)(nt*16 + mr)*256 + k0];
    #pragma unroll
    for (int mi = 0; mi < 2; ++mi) {
      if (w*2 + mi < 15) {
        short8 pv = *(const short8*)&PQs[iL[mi]][512 + k0];
        short8 qv = *(const short8*)&PQs[jL[mi]][768 + k0];
        float hv[8];
        #pragma unroll
        for (int r = 0; r < 8; ++r)
          hv[r] = selu_f(bf2f((unsigned short)pv[r]) + bf2f((unsigned short)qv[r]));
        unsigned int apk[4];
        #pragma unroll
        for (int r2 = 0; r2 < 4; ++r2) apk[r2] = f2bf2(hv[2*r2], hv[2*r2+1]);
        short8 a = *reinterpret_cast<short8*>(apk);
        #pragma unroll
        for (int nt = 0; nt < 4; ++nt)
          acc[mi][nt] = __builtin_amdgcn_mfma_f32_16x16x32_bf16(a, bfr[nt], acc[mi][nt], 0, 0, 0);
      }
    }
  }
  // attn-weighted accumulate
  #pragma unroll
  for (int mi = 0; mi < 2; ++mi) {
    if (w*2 + mi < 15) {
      int ebase = (w*2 + mi)*16 + q*4;
      #pragma unroll
      for (int nt = 0; nt < 4; ++nt) {
        int f = nt*16 + mr;
        int icur = ebase / 15; float vsum = 0.f;
        #pragma unroll
        for (int r = 0; r < 4; ++r) {
          int e = ebase + r;
          int ie = e / 15;
          float v = acc[mi][nt][r] * gateA[e];
          if (ie != icur) { atomicAdd(&accum[icur][f], vsum); vsum = 0.f; icur = ie; }
          vsum += v;
        }
        atomicAdd(&accum[icur][f], vsum);
      }
    }
  }
  __syncthreads();
  #pragma unroll
  for (int s2 = 0; s2 < 2; ++s2) {
    int u = s2*512 + t;
    int i = u >> 6, f = u & 63;
    float val = (accum[i][f] + mm_b2[lh*F_ + f]*sumat[i]) * (1.f/3.f);
    atomicAdd(&fea_nxt[(size_t)(g16 + i)*64 + f], val);
  }
}

// ---------------------------------------------------------------------------
// Crystal phase, fully fused incl. PQ GEMM (f32 pre-acts, bias folded):
// per graph, loop over 3 heads. 256 threads, grid G_.
// ---------------------------------------------------------------------------
__global__ __launch_bounds__(256) void cry_fused(
    const float* __restrict__ fea, const unsigned short* __restrict__ WcryT,
    const float* __restrict__ bias_c, const unsigned short* __restrict__ W2cT,
    const float* __restrict__ cg_W2, const float* __restrict__ cg_b2,
    const float* __restrict__ cm_b2, const float* __restrict__ c_pow,
    const float* __restrict__ wts, float* __restrict__ out) {
  __shared__ __align__(16) unsigned short feaS[16][72];
  __shared__ float PQh[16][520];
  __shared__ float bsc[512];
  __shared__ float gred[16][18];
  __shared__ float attnL[16];
  __shared__ float sumatS;
  __shared__ __align__(16) unsigned short hidc[16][264];
  __shared__ float outg[64];
  int t = threadIdx.x;
  int g = blockIdx.x, g16 = g*16;
  // stage fea once
  {
    int row = t >> 4, c4 = (t & 15) * 4;
    float4 fv = *(const float4*)&fea[(size_t)(g16 + row)*64 + c4];
    *(unsigned int*)&feaS[row][c4]   = f2bf2(fv.x, fv.y);
    *(unsigned int*)&feaS[row][c4+2] = f2bf2(fv.z, fv.w);
  }
  if (t < 64) outg[t] = 0.f;
  int w = t >> 6, lane = t & 63, mr = lane & 15, q = lane >> 4;

  for (int h = 0; h < H_; ++h) {
    __syncthreads();                  // prior-iter PQh readers done; feaS ready
    bsc[t] = bias_c[h*512 + t];
    bsc[256 + t] = bias_c[h*512 + 256 + t];
    __syncthreads();
    // PQ GEMM: 4 waves x 128 cols = 512
    {
      int n0w = w * 128;
      short8 a0 = *(const short8*)&feaS[mr][q*8];
      short8 a1 = *(const short8*)&feaS[mr][32 + q*8];
      #pragma unroll
      for (int nt = 0; nt < 8; ++nt) {
        int n = n0w + nt*16 + mr;
        const unsigned short* bp = WcryT + (size_t)(h*512 + n)*64 + q*8;
        short8 b0 = *(const short8*)bp;
        short8 b1 = *(const short8*)(bp + 32);
        f32x4 z = {0.f, 0.f, 0.f, 0.f};
        z = __builtin_amdgcn_mfma_f32_16x16x32_bf16(a0, b0, z, 0, 0, 0);
        z = __builtin_amdgcn_mfma_f32_16x16x32_bf16(a1, b1, z, 0, 0, 0);
        float bb = bsc[n];
        #pragma unroll
        for (int r = 0; r < 4; ++r)
          PQh[q*4 + r][n] = z[r] + bb;
      }
    }
    __syncthreads();
    {
      int i = t >> 4, c0 = (t & 15) * 16;
      float s = 0.f;
      #pragma unroll
      for (int c = c0; c < c0+16; ++c)
        s = fmaf(selu_f(PQh[i][c]), cg_W2[h*HID_ + c], s);
      gred[i][t & 15] = s;
    }
    __syncthreads();
    if (t < 16) {
      float sg = 0.f;
      #pragma unroll
      for (int u2 = 0; u2 < 16; ++u2) sg += gred[t][u2];
      gred[t][16] = sg + cg_b2[h];
    }
    __syncthreads();
    if (t == 0) {
      float pw = c_pow[h];
      float m = -1e30f;
      #pragma unroll
      for (int i = 0; i < 16; ++i) m = fmaxf(m, gred[i][16]);
      float den = 0.f; float v[16];
      #pragma unroll
      for (int i = 0; i < 16; ++i) {
        float x = __powf(wts[g16+i], pw) * __expf(gred[i][16] - m);
        v[i] = x; den += x;
      }
      den += 1e-10f;
      float sa = 0.f;
      #pragma unroll
      for (int i = 0; i < 16; ++i) { float a = v[i]/den; attnL[i] = a; sa += a; }
      sumatS = sa;
    }
    {
      int i = t >> 4, c0 = (t & 15) * 16;
      #pragma unroll
      for (int c = c0; c < c0+16; c += 2) {
        unsigned int pk = f2bf2(selu_f(PQh[i][256 + c]), selu_f(PQh[i][256 + c + 1]));
        *(unsigned int*)&hidc[i][c] = pk;
      }
    }
    __syncthreads();
    f32x4 acc = {0.f, 0.f, 0.f, 0.f};
    #pragma unroll
    for (int kc = 0; kc < 8; ++kc) {
      short8 a = *(const short8*)&hidc[mr][kc*32 + q*8];
      short8 b = *(const short8*)&W2cT[((size_t)h*64 + w*16 + mr)*HID_ + kc*32 + q*8];
      acc = __builtin_amdgcn_mfma_f32_16x16x32_bf16(a, b, acc, 0, 0, 0);
    }
    float p = 0.f;
    #pragma unroll
    for (int r = 0; r < 4; ++r) p = fmaf(attnL[q*4+r], acc[r], p);
    atomicAdd(&outg[w*16+mr], p);
    if (q == 0) atomicAdd(&outg[w*16+mr], cm_b2[h*F_ + w*16 + mr]*sumatS);
  }
  __syncthreads();
  if (t < 64) out[(size_t)g*64 + t] = outg[t] * (1.f/(float)H_);
}

extern "C" void kernel_launch(void* const* d_in, const int* in_sizes, int n_in,
                              void* d_out, int out_size, void* d_ws, size_t ws_size,
                              hipStream_t stream) {
  const float* elem_weights = (const float*)d_in[0];
  const float* elem_fea_in  = (const float*)d_in[1];
  const float* W_init = (const float*)d_in[2];
  const float* b_init = (const float*)d_in[3];
  const float* mg_W1  = (const float*)d_in[4];
  const float* mg_b1  = (const float*)d_in[5];
  const float* mg_W2  = (const float*)d_in[6];
  const float* mg_b2  = (const float*)d_in[7];
  const float* mm_W1  = (const float*)d_in[8];
  const float* mm_b1  = (const float*)d_in[9];
  const float* mm_W2  = (const float*)d_in[10];
  const float* mm_b2  = (const float*)d_in[11];
  const float* m_pow  = (const float*)d_in[12];
  const float* cg_W1  = (const float*)d_in[13];
  const float* cg_b1  = (const float*)d_in[14];
  const float* cg_W2  = (const float*)d_in[15];
  const float* cg_b2  = (const float*)d_in[16];
  const float* cm_W1  = (const float*)d_in[17];
  const float* cm_b1  = (const float*)d_in[18];
  const float* cm_W2  = (const float*)d_in[19];
  const float* cm_b2  = (const float*)d_in[20];
  const float* c_pow  = (const float*)d_in[21];

  // workspace (~3.5 MB now): fea buffers + preconverted weights + biases
  float* ws = (float*)d_ws;
  float* feaA  = ws;
  float* feaB  = feaA + (size_t)N_*F_;
  unsigned short* WcatT = (unsigned short*)(feaB + (size_t)N_*F_);  // 9*1024*64
  unsigned short* W2mT  = WcatT + (size_t)9*1024*64;                // 9*64*256
  unsigned short* WcryT = W2mT  + (size_t)9*64*256;                 // 1536*64
  unsigned short* W2cT  = WcryT + (size_t)1536*64;                  // 3*64*256
  float* bias_e = (float*)(W2cT + (size_t)3*64*256);                // 3*3072
  float* bias_c = bias_e + 3*3072;                                  // 1536

  prep_wcat<<<(9*1024*64)/256, 256, 0, stream>>>(mg_W1, mm_W1, WcatT);
  prep_w2mt<<<(9*64*256)/256, 256, 0, stream>>>(mm_W2, W2mT);
  prep_wcry<<<(1536*64)/256, 256, 0, stream>>>(cg_W1, cm_W1, WcryT);
  prep_w2c<<<(3*64*256)/256, 256, 0, stream>>>(cm_W2, W2cT);
  prep_bias<<<(9216+1536+255)/256, 256, 0, stream>>>(mg_b1, mm_b1, cg_b1, cm_b1, bias_e, bias_c);
  init_embed<<<N_, 64, 0, stream>>>(elem_fea_in, W_init, b_init, elem_weights, feaA);

  float* cur = feaA; float* nxt = feaB;
  for (int l = 0; l < L_; ++l) {
    copy_fea<<<(N_*F_/4)/256, 256, 0, stream>>>(cur, nxt);
    edge_fused<<<dim3(G_, H_), 512, 0, stream>>>(
        cur, WcatT, bias_e, W2mT, mg_W2, mg_b2, m_pow, mm_b2,
        elem_weights, nxt, l);
    float* t = cur; cur = nxt; nxt = t;
  }

  cry_fused<<<G_, 256, 0, stream>>>(
      cur, WcryT, bias_c, W2cT, cg_W2, cg_b2, cm_b2, c_pow,
      elem_weights, (float*)d_out);
}